// Round 3
// baseline (1964.384 us; speedup 1.0000x reference)
//
#include <hip/hip_runtime.h>
#include <hip/hip_bf16.h>

// ---------------------------------------------------------------------------
// MDTA_FOR_VIDEO_Prompted — full-graph HIP implementation, fp32 in/out/compute.
// B=2, C=32, H=W=128. All intermediates fp32 in d_ws.
// R3: k_conv3 rewritten as 4-pixel-per-thread (64x16 tile, 8 couts/thread):
//     288 FMA per channel-iter vs 72 before; b128-aligned LDS reads (LW=68).
// ---------------------------------------------------------------------------

constexpr int B = 2, C = 32, H = 128, W = 128, N = H * W;

// ---------------- prep: CAT2=[x;y] NCHW, XT = x NHWC ------------------------
__global__ __launch_bounds__(256) void k_prep(const float* __restrict__ x,
                                              const float* __restrict__ y,
                                              float* __restrict__ cat2,
                                              float* __restrict__ xt) {
  __shared__ float tile[C][257];
  const int b = blockIdx.y, n0 = blockIdx.x * 256, tid = threadIdx.x;
  const int n = n0 + tid;
  for (int c = 0; c < C; c++) {
    float v = x[(size_t)(b * C + c) * N + n];
    tile[c][tid] = v;
    cat2[(size_t)(b * 64 + c) * N + n] = v;
  }
  for (int c = 0; c < C; c++)
    cat2[(size_t)(b * 64 + 32 + c) * N + n] = y[(size_t)(b * C + c) * N + n];
  __syncthreads();
  for (int i = tid; i < C * 256; i += 256) {
    int c = i & 31, nl = i >> 5;
    xt[((size_t)b * N + n0 + nl) * C + c] = tile[c][nl];
  }
}

// ---------------- layernorm over channels ----------------------------------
__global__ __launch_bounds__(256) void k_lnorm(const float* __restrict__ xt,
                                               const float* __restrict__ g,
                                               const float* __restrict__ bta,
                                               float* __restrict__ xn) {
  const int b = blockIdx.y;
  const int n = blockIdx.x * 256 + threadIdx.x;
  const float* p = xt + ((size_t)b * N + n) * C;
  float v[C], s = 0.f, ss = 0.f;
#pragma unroll
  for (int c = 0; c < C; c++) { v[c] = p[c]; s += v[c]; ss += v[c] * v[c]; }
  const float mu = s * (1.f / C);
  const float var = ss * (1.f / C) - mu * mu;
  const float inv = rsqrtf(var + 1e-5f);
#pragma unroll
  for (int c = 0; c < C; c++)
    xn[(size_t)(b * C + c) * N + n] = (v[c] - mu) * inv * g[c] + bta[c];
}

// ---------------- generic 1x1 conv (4 couts/thread) ------------------------
__global__ __launch_bounds__(256)
void k_conv1x1(const float* __restrict__ in, long in_bs, int cin,
               const float* __restrict__ wts, const float* __restrict__ bias,
               const float* __restrict__ resid, long res_bs,
               float* __restrict__ out, long out_bs, int out_coff) {
  const int n = blockIdx.x * 256 + threadIdx.x;
  const int co0 = blockIdx.y * 4, b = blockIdx.z;
  const float* ip = in + (size_t)b * in_bs + n;
  const float* w = wts + (size_t)co0 * cin;
  float a0 = 0, a1 = 0, a2 = 0, a3 = 0;
  for (int ci = 0; ci < cin; ci++) {
    float xv = ip[(size_t)ci * N];
    a0 += xv * w[ci]; a1 += xv * w[cin + ci];
    a2 += xv * w[2 * cin + ci]; a3 += xv * w[3 * cin + ci];
  }
  float acc[4] = {a0, a1, a2, a3};
#pragma unroll
  for (int o = 0; o < 4; o++) {
    const int co = co0 + o;
    float r = acc[o];
    if (bias) r += bias[co];
    if (resid) r += resid[(size_t)b * res_bs + (size_t)co * N + n];
    out[(size_t)b * out_bs + (size_t)(out_coff + co) * N + n] = r;
  }
}

// ---------------- generic 3x3 conv: 64x16 tile, 4 px/thread, TCO couts -----
template <int TCO>
__global__ __launch_bounds__(256)
void k_conv3(const float* __restrict__ in, long in_bs, int cin, int ih, int iw,
             const float* __restrict__ wts, int cout,
             float* __restrict__ out, long out_bs, int out_coff, int oh, int ow,
             int pad, int tiles_x) {
  constexpr int TW = 64, TH = 16;
  constexpr int LW = 68, LH = TH + 2;  // LW=68: keeps col tx*4 16B-aligned per row
  constexpr int CC = 4;                // channels per LDS chunk
  __shared__ float tile[CC][LH][LW];   // 4*18*68*4 = 19584 B
  const int tid = threadIdx.x;
  const int b = blockIdx.z;
  const int tx0 = (blockIdx.x % tiles_x) * TW, ty0 = (blockIdx.x / tiles_x) * TH;
  const int co0 = blockIdx.y * TCO;
  const int tx = tid & 15, ty = tid >> 4;
  const int tx4 = tx * 4;
  const int ox = tx0 + tx4, oy = ty0 + ty;
  float acc[TCO][4];
#pragma unroll
  for (int o = 0; o < TCO; o++)
#pragma unroll
    for (int p = 0; p < 4; p++) acc[o][p] = 0.f;
  const float* inb = in + (size_t)b * in_bs;
  const int isp = ih * iw;

  for (int c0 = 0; c0 < cin; c0 += CC) {
    const int cb = min(CC, cin - c0);
    __syncthreads();
    const int tot = cb * (LH * LW);
    for (int i = tid; i < tot; i += 256) {
      int c = i / (LH * LW), rem = i - c * (LH * LW);
      int r = rem / LW, col = rem - r * LW;
      int iy = ty0 - pad + r, ix = tx0 - pad + col;
      float v = 0.f;
      if (iy >= 0 && iy < ih && ix >= 0 && ix < iw)
        v = inb[(size_t)(c0 + c) * isp + (size_t)iy * iw + ix];
      tile[c][r][col] = v;
    }
    __syncthreads();
    for (int c = 0; c < cb; c++) {
      float v[3][6];
#pragma unroll
      for (int r = 0; r < 3; r++) {
        const float4 a4 = *(const float4*)&tile[c][ty + r][tx4];
        const float2 a2 = *(const float2*)&tile[c][ty + r][tx4 + 4];
        v[r][0] = a4.x; v[r][1] = a4.y; v[r][2] = a4.z; v[r][3] = a4.w;
        v[r][4] = a2.x; v[r][5] = a2.y;
      }
      const float* wp = wts + ((size_t)co0 * cin + (c0 + c)) * 9;
#pragma unroll
      for (int o = 0; o < TCO; o++) {
        if (co0 + o >= cout) break;
        const float* w = wp + (size_t)o * cin * 9;
#pragma unroll
        for (int r = 0; r < 3; r++) {
          const float w0 = w[r * 3 + 0], w1 = w[r * 3 + 1], w2 = w[r * 3 + 2];
#pragma unroll
          for (int p = 0; p < 4; p++)
            acc[o][p] += v[r][p] * w0 + v[r][p + 1] * w1 + v[r][p + 2] * w2;
        }
      }
    }
  }

  if (oy < oh && ox < ow) {
    const size_t sp = (size_t)oh * ow;
    float* ob = out + (size_t)b * out_bs + (size_t)oy * ow + ox;
#pragma unroll
    for (int o = 0; o < TCO; o++) {
      const int co = co0 + o;
      if (co >= cout) break;
      float* op = ob + (size_t)(out_coff + co) * sp;
      if (ox + 3 < ow) {
        *(float4*)op = make_float4(acc[o][0], acc[o][1], acc[o][2], acc[o][3]);
      } else {
#pragma unroll
        for (int p = 0; p < 4; p++)
          if (ox + p < ow) op[p] = acc[o][p];
      }
    }
  }
}

// ---------------- grouped 3x3 conv (groups=32, 3 in / 3 out per group) -----
__global__ __launch_bounds__(256) void k_dwconv(const float* __restrict__ in,
                                                const float* __restrict__ wts,
                                                float* __restrict__ out) {
  const int n = blockIdx.x * 256 + threadIdx.x;
  const int g = blockIdx.y, b = blockIdx.z;
  const int h0 = n >> 7, w0 = n & 127;
  float acc[3] = {0.f, 0.f, 0.f};
  for (int ci = 0; ci < 3; ci++) {
    const float* ip = in + ((size_t)b * 96 + g * 3 + ci) * N;
#pragma unroll
    for (int ky = 0; ky < 3; ky++) {
      const int iy = h0 - 1 + ky;
      if (iy < 0 || iy >= H) continue;
#pragma unroll
      for (int kx = 0; kx < 3; kx++) {
        const int ix = w0 - 1 + kx;
        if (ix < 0 || ix >= W) continue;
        const float v = ip[(size_t)iy * W + ix];
#pragma unroll
        for (int o = 0; o < 3; o++)
          acc[o] += v * wts[((size_t)(g * 3 + o) * 3 + ci) * 9 + ky * 3 + kx];
      }
    }
  }
#pragma unroll
  for (int o = 0; o < 3; o++)
    out[((size_t)b * 96 + g * 3 + o) * N + n] = acc[o];
}

// ---------------- channel-attn: norms + gram + softmax ---------------------
template <int DQ>
__global__ __launch_bounds__(256)
void k_attn_stats(const float* __restrict__ q1, long q1_bs,
                  const float* __restrict__ q2, long q2_bs,
                  const float* __restrict__ k, long k_bs,
                  const float* __restrict__ temp, float* __restrict__ stats) {
  const int h = blockIdx.x, b = blockIdx.y, tid = threadIdx.x;
  const float* qp[DQ];
#pragma unroll
  for (int d = 0; d < DQ; d++) {
    const int qc = h * DQ + d;
    qp[d] = (qc < 32) ? (q1 + (size_t)b * q1_bs + (size_t)qc * N)
                      : (q2 + (size_t)b * q2_bs + (size_t)(qc - 32) * N);
  }
  const float* kp[4];
#pragma unroll
  for (int e = 0; e < 4; e++) kp[e] = k + (size_t)b * k_bs + (size_t)(h * 4 + e) * N;

  constexpr int NV = DQ + 4 + DQ * 4;
  float ssq[DQ] = {}, ssk[4] = {}, gr[DQ][4] = {};
  for (int n = tid; n < N; n += 256) {
    float qv[DQ], kv[4];
#pragma unroll
    for (int d = 0; d < DQ; d++) { qv[d] = qp[d][n]; ssq[d] += qv[d] * qv[d]; }
#pragma unroll
    for (int e = 0; e < 4; e++) { kv[e] = kp[e][n]; ssk[e] += kv[e] * kv[e]; }
#pragma unroll
    for (int d = 0; d < DQ; d++)
#pragma unroll
      for (int e = 0; e < 4; e++) gr[d][e] += qv[d] * kv[e];
  }
  float vals[NV];
#pragma unroll
  for (int d = 0; d < DQ; d++) vals[d] = ssq[d];
#pragma unroll
  for (int e = 0; e < 4; e++) vals[DQ + e] = ssk[e];
#pragma unroll
  for (int d = 0; d < DQ; d++)
#pragma unroll
    for (int e = 0; e < 4; e++) vals[DQ + 4 + d * 4 + e] = gr[d][e];
#pragma unroll
  for (int j = 0; j < NV; j++) {
    float v = vals[j];
    for (int m = 32; m > 0; m >>= 1) v += __shfl_xor(v, m, 64);
    vals[j] = v;
  }
  __shared__ float red[4][NV];
  const int wid = tid >> 6, lane = tid & 63;
  if (lane == 0)
#pragma unroll
    for (int j = 0; j < NV; j++) red[wid][j] = vals[j];
  __syncthreads();
  if (tid == 0) {
    float tot[NV];
#pragma unroll
    for (int j = 0; j < NV; j++) tot[j] = red[0][j] + red[1][j] + red[2][j] + red[3][j];
    float invq[DQ], invk[4];
#pragma unroll
    for (int d = 0; d < DQ; d++) invq[d] = 1.f / fmaxf(sqrtf(tot[d]), 1e-12f);
#pragma unroll
    for (int e = 0; e < 4; e++) invk[e] = 1.f / fmaxf(sqrtf(tot[DQ + e]), 1e-12f);
    const float t = temp[h];
    float* sp = stats + (size_t)(b * 8 + h) * DQ * 4;
    for (int d = 0; d < DQ; d++) {
      float s[4], mx = -1e30f;
#pragma unroll
      for (int e = 0; e < 4; e++) {
        s[e] = tot[DQ + 4 + d * 4 + e] * invq[d] * invk[e] * t;
        mx = fmaxf(mx, s[e]);
      }
      float sum = 0.f;
#pragma unroll
      for (int e = 0; e < 4; e++) { s[e] = expf(s[e] - mx); sum += s[e]; }
#pragma unroll
      for (int e = 0; e < 4; e++) sp[d * 4 + e] = s[e] / sum;
    }
  }
}

// ---------------- channel-attn: apply attn to v ----------------------------
template <int DQ>
__global__ __launch_bounds__(256)
void k_attn_apply(const float* __restrict__ v, long v_bs,
                  const float* __restrict__ stats,
                  float* __restrict__ out, long out_bs) {
  const int n = blockIdx.x * 256 + threadIdx.x;
  const int h = blockIdx.y, b = blockIdx.z;
  float vv[4];
#pragma unroll
  for (int e = 0; e < 4; e++) vv[e] = v[(size_t)b * v_bs + (size_t)(h * 4 + e) * N + n];
  const float* A = stats + (size_t)(b * 8 + h) * DQ * 4;
#pragma unroll
  for (int d = 0; d < DQ; d++) {
    const float a = A[d * 4] * vv[0] + A[d * 4 + 1] * vv[1] + A[d * 4 + 2] * vv[2] + A[d * 4 + 3] * vv[3];
    out[(size_t)b * out_bs + (size_t)(h * DQ + d) * N + n] = a;
  }
}

// ---------------- avgpool 2x2 on CAT2 --------------------------------------
__global__ __launch_bounds__(256) void k_avgpool(const float* __restrict__ in,
                                                 float* __restrict__ out) {
  const int id = blockIdx.x * 256 + threadIdx.x;  // B*64*64*64
  const int ox = id & 63, oy = (id >> 6) & 63, c = (id >> 12) & 63, b = id >> 18;
  const float* p = in + ((size_t)b * 64 + c) * N + (size_t)(oy * 2) * W + ox * 2;
  out[id] = 0.25f * (p[0] + p[1] + p[W] + p[W + 1]);
}

// ---------------- t3 *= sigmoid(nearest_resize(asmall)) --------------------
__global__ __launch_bounds__(256) void k_sigmul(float* __restrict__ t3,
                                                const float* __restrict__ asmall) {
  const int id = blockIdx.x * 256 + threadIdx.x;  // B*166*N
  const int x = id & 127, yv = (id >> 7) & 127;
  const int bc = id >> 14;
  const int iy = (yv * 62) >> 7, ix = (x * 62) >> 7;
  const float a = asmall[(size_t)bc * 3844 + iy * 62 + ix];
  t3[id] *= 1.f / (1.f + expf(-a));
}

// ---------------- deformable conv (stride1, groups=8, bilinear) ------------
template <int K>
__global__ __launch_bounds__(256)
void k_deform(const float* __restrict__ xt, const float* __restrict__ offs, int off_c0,
              const float* __restrict__ wd, const float* __restrict__ bd,
              float* __restrict__ out, int out_c0) {
  constexpr int K2 = K * K, PAD = K / 2;
  const int n = blockIdx.x * 256 + threadIdx.x;
  const int g = blockIdx.y, b = blockIdx.z;
  const int hy = n >> 7, wx = n & 127;
  float acc[4] = {0.f, 0.f, 0.f, 0.f};
  const float* ob = offs + (size_t)b * (166 * N) + (size_t)off_c0 * N + n;
  const float* xb = xt + ((size_t)b * N) * 32 + g * 4;
  const float* wg = wd + (size_t)(g * 4) * (4 * K2);
  for (int tap = 0; tap < K2; tap++) {
    const int ky = tap / K, kx = tap % K;
    const float dy = ob[(size_t)(2 * tap) * N];
    const float dx = ob[(size_t)(2 * tap + 1) * N];
    const float py = (float)(hy - PAD + ky) + dy;
    const float px = (float)(wx - PAD + kx) + dx;
    const float y0f = floorf(py), x0f = floorf(px);
    const float fy = py - y0f, fx = px - x0f;
    const int y0 = (int)y0f, x0 = (int)x0f;
    const int y1 = y0 + 1, x1 = x0 + 1;
    float w00 = (1.f - fy) * (1.f - fx), w01 = (1.f - fy) * fx;
    float w10 = fy * (1.f - fx), w11 = fy * fx;
    const bool vy0 = (y0 >= 0) & (y0 < H), vy1 = (y1 >= 0) & (y1 < H);
    const bool vx0 = (x0 >= 0) & (x0 < W), vx1 = (x1 >= 0) & (x1 < W);
    w00 = (vy0 & vx0) ? w00 : 0.f;
    w01 = (vy0 & vx1) ? w01 : 0.f;
    w10 = (vy1 & vx0) ? w10 : 0.f;
    w11 = (vy1 & vx1) ? w11 : 0.f;
    const int cy0 = min(max(y0, 0), H - 1), cy1 = min(max(y1, 0), H - 1);
    const int cx0 = min(max(x0, 0), W - 1), cx1 = min(max(x1, 0), W - 1);
    const float4 g00 = *(const float4*)(xb + (size_t)(cy0 * W + cx0) * 32);
    const float4 g01 = *(const float4*)(xb + (size_t)(cy0 * W + cx1) * 32);
    const float4 g10 = *(const float4*)(xb + (size_t)(cy1 * W + cx0) * 32);
    const float4 g11 = *(const float4*)(xb + (size_t)(cy1 * W + cx1) * 32);
    const float s0 = w00 * g00.x + w01 * g01.x + w10 * g10.x + w11 * g11.x;
    const float s1 = w00 * g00.y + w01 * g01.y + w10 * g10.y + w11 * g11.y;
    const float s2 = w00 * g00.z + w01 * g01.z + w10 * g10.z + w11 * g11.z;
    const float s3 = w00 * g00.w + w01 * g01.w + w10 * g10.w + w11 * g11.w;
    const float* wt = wg + tap;
#pragma unroll
    for (int o = 0; o < 4; o++) {
      const float* wr = wt + (size_t)(o * 4) * K2;
      acc[o] += s0 * wr[0] + s1 * wr[K2] + s2 * wr[2 * K2] + s3 * wr[3 * K2];
    }
  }
#pragma unroll
  for (int o = 0; o < 4; o++) {
    const float r = fmaxf(acc[o] + bd[g * 4 + o], 0.f);
    out[((size_t)b * 96 + (out_c0 + g * 4 + o)) * N + n] = r;
  }
}

// ---------------------------------------------------------------------------
extern "C" void kernel_launch(void* const* d_in, const int* in_sizes, int n_in,
                              void* d_out, int out_size, void* d_ws, size_t ws_size,
                              hipStream_t stream) {
  // All reference dtypes are float32 — use inputs in place.
  const float* fx       = (const float*)d_in[0];
  const float* fy       = (const float*)d_in[1];
  const float* w_temp   = (const float*)d_in[2];
  const float* w_po     = (const float*)d_in[3];
  const float* w_lp1    = (const float*)d_in[4];
  const float* w_lp2    = (const float*)d_in[5];
  const float* ln_g     = (const float*)d_in[6];
  const float* ln_b     = (const float*)d_in[7];
  const float* w_tempin = (const float*)d_in[8];
  const float* w_qkv    = (const float*)d_in[9];
  const float* w_qkvd   = (const float*)d_in[10];
  const float* w_mproj  = (const float*)d_in[11];
  const float* w_c3     = (const float*)d_in[12];
  const float* w_k2     = (const float*)d_in[13];
  const float* w_k3     = (const float*)d_in[14];
  const float* w_k4     = (const float*)d_in[15];
  const float* w_d3     = (const float*)d_in[16];
  const float* b_d3     = (const float*)d_in[17];
  const float* w_d5     = (const float*)d_in[18];
  const float* b_d5     = (const float*)d_in[19];
  const float* w_d7     = (const float*)d_in[20];
  const float* b_d7     = (const float*)d_in[21];
  const float* w_pw     = (const float*)d_in[22];
  const float* b_pw     = (const float*)d_in[23];
  float* ws = (float*)d_ws;

  // ---- workspace layout (fp32 elements), time-multiplexed regions ----
  size_t off = 0;
  auto buf = [&](size_t nelem) { float* p = ws + off; off += nelem; return p; };
  float* CAT2   = buf(2097152);   // [B,64,N] [x;y], lives whole pass
  float* XT     = buf(1048576);   // [B,N,32] x NHWC (lnorm + deform gathers)
  float* R1     = buf(1048576);   // XN, then ATTN
  float* R2     = buf(3145728);   // QKV1, then CAT1, then ATTN2
  float* R3     = buf(3145728);   // QKV2, then POOL+ASMALL
  float* PROMPT = buf(1048576);
  float* R4     = buf(5439488);   // T3, then CAT3+KFEAT
  float* OFFS   = buf(5439488);
  float* STATS  = buf(1024);
  (void)ws_size; (void)out_size; (void)n_in; (void)in_sizes;

  float* XN = R1;     float* ATTN = R1;
  float* QKV1 = R2;   float* CAT1 = R2;   float* ATTN2 = R2;
  float* QKV2 = R3;   float* POOL = R3;   float* ASMALL = R3 + 524288;
  float* T3 = R4;     float* CAT3 = R4;   float* KFEAT = R4 + 3145728;
  float* ST_IN = STATS;        // inner attn: B*8*4*4 = 256
  float* ST_FI = STATS + 256;  // final attn: B*8*8*4 = 512

  const long bs64 = 64L * N, bs32 = 32L * N, bs96 = 96L * N, bs166 = 166L * N;

  // conv3 tiling: 64x16 output tile. 128x128 -> tiles_x=2, 16 tiles.
  //               62x62 (k2)        -> tiles_x=1, 4 tiles.

  // 1. prep CAT2 + XT
  k_prep<<<dim3(N / 256, B), 256, 0, stream>>>(fx, fy, CAT2, XT);
  // 2. layernorm
  k_lnorm<<<dim3(N / 256, B), 256, 0, stream>>>(XT, ln_g, ln_b, XN);
  // 3. qkv 1x1: XN(32) -> QKV1(96)
  k_conv1x1<<<dim3(N / 256, 24, B), 256, 0, stream>>>(
      XN, bs32, 32, w_qkv, nullptr, nullptr, 0, QKV1, bs96, 0);
  // 4. grouped 3x3: QKV1 -> QKV2
  k_dwconv<<<dim3(N / 256, 32, B), 256, 0, stream>>>(QKV1, w_qkvd, QKV2);
  // 5/6. inner channel attention (dq=4): qi,ki,vi slices of QKV2
  k_attn_stats<4><<<dim3(8, B), 256, 0, stream>>>(
      QKV2, bs96, nullptr, 0, QKV2 + bs32, bs96, w_tempin, ST_IN);
  k_attn_apply<4><<<dim3(N / 256, 8, B), 256, 0, stream>>>(
      QKV2 + 2 * bs32, bs96, ST_IN, ATTN, bs32);
  // 7. xg = x + mproj(ATTN) -> CAT1 ch 64..95
  k_conv1x1<<<dim3(N / 256, 8, B), 256, 0, stream>>>(
      ATTN, bs32, 32, w_mproj, nullptr, CAT2, bs64, CAT1, bs96, 64);
  // 8. l1 = lp1(x) -> CAT1 ch 0..31
  k_conv1x1<<<dim3(N / 256, 8, B), 256, 0, stream>>>(
      CAT2, bs64, 32, w_lp1, nullptr, nullptr, 0, CAT1, bs96, 0);
  // 9. l2 = lp2 3x3(x) -> CAT1 ch 32..63
  k_conv3<8><<<dim3(16, 4, B), 256, 0, stream>>>(
      CAT2, bs64, 32, H, W, w_lp2, 32, CAT1, bs96, 32, H, W, 1, 2);
  // 10. prompt = c3 3x3(CAT1)
  k_conv3<8><<<dim3(16, 4, B), 256, 0, stream>>>(
      CAT1, bs96, 96, H, W, w_c3, 32, PROMPT, bs32, 0, H, W, 1, 2);
  // 11. avgpool CAT2 -> POOL
  k_avgpool<<<dim3((B * 64 * 64 * 64) / 256), 256, 0, stream>>>(CAT2, POOL);
  // 12. k2 3x3 valid: POOL(64,64x64) -> ASMALL(166,62x62)
  k_conv3<8><<<dim3(4, 21, B), 256, 0, stream>>>(
      POOL, 64L * 4096, 64, 64, 64, w_k2, 166, ASMALL, 166L * 3844, 0, 62, 62, 0, 1);
  // 13. k3 3x3: CAT2(64) -> T3(166)
  k_conv3<8><<<dim3(16, 21, B), 256, 0, stream>>>(
      CAT2, bs64, 64, H, W, w_k3, 166, T3, bs166, 0, H, W, 1, 2);
  // 14. T3 *= sigmoid(resize(ASMALL))
  k_sigmul<<<dim3((B * 166 * N) / 256), 256, 0, stream>>>(T3, ASMALL);
  // 15. k4 3x3: T3(166) -> OFFS(166)
  k_conv3<8><<<dim3(16, 21, B), 256, 0, stream>>>(
      T3, bs166, 166, H, W, w_k4, 166, OFFS, bs166, 0, H, W, 1, 2);
  // 16-18. deformable convs -> CAT3
  k_deform<3><<<dim3(N / 256, 8, B), 256, 0, stream>>>(XT, OFFS, 0, w_d3, b_d3, CAT3, 0);
  k_deform<5><<<dim3(N / 256, 8, B), 256, 0, stream>>>(XT, OFFS, 18, w_d5, b_d5, CAT3, 32);
  k_deform<7><<<dim3(N / 256, 8, B), 256, 0, stream>>>(XT, OFFS, 68, w_d7, b_d7, CAT3, 64);
  // 19. k_feat = pw 1x1(CAT3) + bias
  k_conv1x1<<<dim3(N / 256, 8, B), 256, 0, stream>>>(
      CAT3, bs96, 96, w_pw, b_pw, nullptr, 0, KFEAT, bs32, 0);
  // 20/21. final channel attention (dq=8): q=[x;prompt], k=KFEAT, v=x
  k_attn_stats<8><<<dim3(8, B), 256, 0, stream>>>(
      CAT2, bs64, PROMPT, bs32, KFEAT, bs32, w_temp, ST_FI);
  k_attn_apply<8><<<dim3(N / 256, 8, B), 256, 0, stream>>>(
      CAT2, bs64, ST_FI, ATTN2, bs64);
  // 22. out = po 1x1(ATTN2) -> d_out (fp32)
  k_conv1x1<<<dim3(N / 256, 8, B), 256, 0, stream>>>(
      ATTN2, bs64, 64, w_po, nullptr, nullptr, 0, (float*)d_out, bs32, 0);
}

// Round 4
// 1415.346 us; speedup vs baseline: 1.3879x; 1.3879x over previous
//
#include <hip/hip_runtime.h>
#include <hip/hip_bf16.h>

// ---------------------------------------------------------------------------
// MDTA_FOR_VIDEO_Prompted — full-graph HIP implementation, fp32 in/out/compute.
// B=2, C=32, H=W=128. All intermediates fp32 in d_ws.
// R4 conv3: wave-per-row lane mapping (lane=x, 2 rows/thread). Every LDS read
//   has 64 lanes on consecutive cols of one row -> conflict-free (2 lanes/bank
//   is free, m136). 64x8 tile -> k4 grid 1344 blocks (~65% occupancy).
//   Weight addresses stay wave-uniform (SGPR loads, FMA with SGPR operand).
// ---------------------------------------------------------------------------

constexpr int B = 2, C = 32, H = 128, W = 128, N = H * W;

// ---------------- prep: CAT2=[x;y] NCHW, XT = x NHWC ------------------------
__global__ __launch_bounds__(256) void k_prep(const float* __restrict__ x,
                                              const float* __restrict__ y,
                                              float* __restrict__ cat2,
                                              float* __restrict__ xt) {
  __shared__ float tile[C][257];
  const int b = blockIdx.y, n0 = blockIdx.x * 256, tid = threadIdx.x;
  const int n = n0 + tid;
  for (int c = 0; c < C; c++) {
    float v = x[(size_t)(b * C + c) * N + n];
    tile[c][tid] = v;
    cat2[(size_t)(b * 64 + c) * N + n] = v;
  }
  for (int c = 0; c < C; c++)
    cat2[(size_t)(b * 64 + 32 + c) * N + n] = y[(size_t)(b * C + c) * N + n];
  __syncthreads();
  for (int i = tid; i < C * 256; i += 256) {
    int c = i & 31, nl = i >> 5;
    xt[((size_t)b * N + n0 + nl) * C + c] = tile[c][nl];
  }
}

// ---------------- layernorm over channels ----------------------------------
__global__ __launch_bounds__(256) void k_lnorm(const float* __restrict__ xt,
                                               const float* __restrict__ g,
                                               const float* __restrict__ bta,
                                               float* __restrict__ xn) {
  const int b = blockIdx.y;
  const int n = blockIdx.x * 256 + threadIdx.x;
  const float* p = xt + ((size_t)b * N + n) * C;
  float v[C], s = 0.f, ss = 0.f;
#pragma unroll
  for (int c = 0; c < C; c++) { v[c] = p[c]; s += v[c]; ss += v[c] * v[c]; }
  const float mu = s * (1.f / C);
  const float var = ss * (1.f / C) - mu * mu;
  const float inv = rsqrtf(var + 1e-5f);
#pragma unroll
  for (int c = 0; c < C; c++)
    xn[(size_t)(b * C + c) * N + n] = (v[c] - mu) * inv * g[c] + bta[c];
}

// ---------------- generic 1x1 conv (4 couts/thread) ------------------------
__global__ __launch_bounds__(256)
void k_conv1x1(const float* __restrict__ in, long in_bs, int cin,
               const float* __restrict__ wts, const float* __restrict__ bias,
               const float* __restrict__ resid, long res_bs,
               float* __restrict__ out, long out_bs, int out_coff) {
  const int n = blockIdx.x * 256 + threadIdx.x;
  const int co0 = blockIdx.y * 4, b = blockIdx.z;
  const float* ip = in + (size_t)b * in_bs + n;
  const float* w = wts + (size_t)co0 * cin;
  float a0 = 0, a1 = 0, a2 = 0, a3 = 0;
  for (int ci = 0; ci < cin; ci++) {
    float xv = ip[(size_t)ci * N];
    a0 += xv * w[ci]; a1 += xv * w[cin + ci];
    a2 += xv * w[2 * cin + ci]; a3 += xv * w[3 * cin + ci];
  }
  float acc[4] = {a0, a1, a2, a3};
#pragma unroll
  for (int o = 0; o < 4; o++) {
    const int co = co0 + o;
    float r = acc[o];
    if (bias) r += bias[co];
    if (resid) r += resid[(size_t)b * res_bs + (size_t)co * N + n];
    out[(size_t)b * out_bs + (size_t)(out_coff + co) * N + n] = r;
  }
}

// ---------------- generic 3x3 conv: 64x8 tile, lane=x, 2 rows/thread -------
template <int TCO>
__global__ __launch_bounds__(256)
void k_conv3(const float* __restrict__ in, long in_bs, int cin, int ih, int iw,
             const float* __restrict__ wts, int cout,
             float* __restrict__ out, long out_bs, int out_coff, int oh, int ow,
             int pad, int tiles_x) {
  constexpr int TW = 64, TH = 8;
  constexpr int LW = 68, LH = TH + 2;  // bank layout irrelevant: same-row reads
  constexpr int CC = 4;                // channels per LDS chunk
  __shared__ float tile[CC][LH][LW];   // 4*10*68*4 = 10880 B
  const int tid = threadIdx.x;
  const int b = blockIdx.z;
  const int tx0 = (blockIdx.x % tiles_x) * TW, ty0 = (blockIdx.x / tiles_x) * TH;
  const int co0 = blockIdx.y * TCO;
  const int x = tid & 63;          // lane = x: wave reads one row at a time
  const int ys = (tid >> 6) * 2;   // each thread computes rows ys, ys+1
  const int ox = tx0 + x;
  float acc[TCO][2];
#pragma unroll
  for (int o = 0; o < TCO; o++) { acc[o][0] = 0.f; acc[o][1] = 0.f; }
  const float* inb = in + (size_t)b * in_bs;
  const int isp = ih * iw;

  for (int c0 = 0; c0 < cin; c0 += CC) {
    const int cb = min(CC, cin - c0);
    __syncthreads();
    const int tot = cb * (LH * LW);
    for (int i = tid; i < tot; i += 256) {
      int c = i / (LH * LW), rem = i - c * (LH * LW);
      int r = rem / LW, col = rem - r * LW;
      int iy = ty0 - pad + r, ix = tx0 - pad + col;
      float v = 0.f;
      if (iy >= 0 && iy < ih && ix >= 0 && ix < iw)
        v = inb[(size_t)(c0 + c) * isp + (size_t)iy * iw + ix];
      tile[c][r][col] = v;
    }
    __syncthreads();
    for (int c = 0; c < cb; c++) {
      // 12 conflict-free LDS reads: rows ys..ys+3, cols x..x+2
      float v[4][3];
#pragma unroll
      for (int rr = 0; rr < 4; rr++)
#pragma unroll
        for (int d = 0; d < 3; d++)
          v[rr][d] = tile[c][ys + rr][x + d];
#pragma unroll
      for (int o = 0; o < TCO; o++) {
        // clamp keeps weight addr in-bounds & wave-uniform; tail rows discarded at store
        const int co = min(co0 + o, cout - 1);
        const float* w = wts + ((size_t)co * cin + (c0 + c)) * 9;
        const float w0 = w[0], w1 = w[1], w2 = w[2];
        const float w3 = w[3], w4 = w[4], w5 = w[5];
        const float w6 = w[6], w7 = w[7], w8 = w[8];
        acc[o][0] += v[0][0] * w0 + v[0][1] * w1 + v[0][2] * w2
                   + v[1][0] * w3 + v[1][1] * w4 + v[1][2] * w5
                   + v[2][0] * w6 + v[2][1] * w7 + v[2][2] * w8;
        acc[o][1] += v[1][0] * w0 + v[1][1] * w1 + v[1][2] * w2
                   + v[2][0] * w3 + v[2][1] * w4 + v[2][2] * w5
                   + v[3][0] * w6 + v[3][1] * w7 + v[3][2] * w8;
      }
    }
  }

  if (ox < ow) {
    const size_t sp = (size_t)oh * ow;
#pragma unroll
    for (int j = 0; j < 2; j++) {
      const int oy = ty0 + ys + j;
      if (oy >= oh) continue;
      float* ob = out + (size_t)b * out_bs + (size_t)oy * ow + ox;
#pragma unroll
      for (int o = 0; o < TCO; o++) {
        const int co = co0 + o;
        if (co < cout) ob[(size_t)(out_coff + co) * sp] = acc[o][j];
      }
    }
  }
}

// ---------------- grouped 3x3 conv (groups=32, 3 in / 3 out per group) -----
__global__ __launch_bounds__(256) void k_dwconv(const float* __restrict__ in,
                                                const float* __restrict__ wts,
                                                float* __restrict__ out) {
  const int n = blockIdx.x * 256 + threadIdx.x;
  const int g = blockIdx.y, b = blockIdx.z;
  const int h0 = n >> 7, w0 = n & 127;
  float acc[3] = {0.f, 0.f, 0.f};
  for (int ci = 0; ci < 3; ci++) {
    const float* ip = in + ((size_t)b * 96 + g * 3 + ci) * N;
#pragma unroll
    for (int ky = 0; ky < 3; ky++) {
      const int iy = h0 - 1 + ky;
      if (iy < 0 || iy >= H) continue;
#pragma unroll
      for (int kx = 0; kx < 3; kx++) {
        const int ix = w0 - 1 + kx;
        if (ix < 0 || ix >= W) continue;
        const float v = ip[(size_t)iy * W + ix];
#pragma unroll
        for (int o = 0; o < 3; o++)
          acc[o] += v * wts[((size_t)(g * 3 + o) * 3 + ci) * 9 + ky * 3 + kx];
      }
    }
  }
#pragma unroll
  for (int o = 0; o < 3; o++)
    out[((size_t)b * 96 + g * 3 + o) * N + n] = acc[o];
}

// ---------------- channel-attn: norms + gram + softmax ---------------------
template <int DQ>
__global__ __launch_bounds__(256)
void k_attn_stats(const float* __restrict__ q1, long q1_bs,
                  const float* __restrict__ q2, long q2_bs,
                  const float* __restrict__ k, long k_bs,
                  const float* __restrict__ temp, float* __restrict__ stats) {
  const int h = blockIdx.x, b = blockIdx.y, tid = threadIdx.x;
  const float* qp[DQ];
#pragma unroll
  for (int d = 0; d < DQ; d++) {
    const int qc = h * DQ + d;
    qp[d] = (qc < 32) ? (q1 + (size_t)b * q1_bs + (size_t)qc * N)
                      : (q2 + (size_t)b * q2_bs + (size_t)(qc - 32) * N);
  }
  const float* kp[4];
#pragma unroll
  for (int e = 0; e < 4; e++) kp[e] = k + (size_t)b * k_bs + (size_t)(h * 4 + e) * N;

  constexpr int NV = DQ + 4 + DQ * 4;
  float ssq[DQ] = {}, ssk[4] = {}, gr[DQ][4] = {};
  for (int n = tid; n < N; n += 256) {
    float qv[DQ], kv[4];
#pragma unroll
    for (int d = 0; d < DQ; d++) { qv[d] = qp[d][n]; ssq[d] += qv[d] * qv[d]; }
#pragma unroll
    for (int e = 0; e < 4; e++) { kv[e] = kp[e][n]; ssk[e] += kv[e] * kv[e]; }
#pragma unroll
    for (int d = 0; d < DQ; d++)
#pragma unroll
      for (int e = 0; e < 4; e++) gr[d][e] += qv[d] * kv[e];
  }
  float vals[NV];
#pragma unroll
  for (int d = 0; d < DQ; d++) vals[d] = ssq[d];
#pragma unroll
  for (int e = 0; e < 4; e++) vals[DQ + e] = ssk[e];
#pragma unroll
  for (int d = 0; d < DQ; d++)
#pragma unroll
    for (int e = 0; e < 4; e++) vals[DQ + 4 + d * 4 + e] = gr[d][e];
#pragma unroll
  for (int j = 0; j < NV; j++) {
    float v = vals[j];
    for (int m = 32; m > 0; m >>= 1) v += __shfl_xor(v, m, 64);
    vals[j] = v;
  }
  __shared__ float red[4][NV];
  const int wid = tid >> 6, lane = tid & 63;
  if (lane == 0)
#pragma unroll
    for (int j = 0; j < NV; j++) red[wid][j] = vals[j];
  __syncthreads();
  if (tid == 0) {
    float tot[NV];
#pragma unroll
    for (int j = 0; j < NV; j++) tot[j] = red[0][j] + red[1][j] + red[2][j] + red[3][j];
    float invq[DQ], invk[4];
#pragma unroll
    for (int d = 0; d < DQ; d++) invq[d] = 1.f / fmaxf(sqrtf(tot[d]), 1e-12f);
#pragma unroll
    for (int e = 0; e < 4; e++) invk[e] = 1.f / fmaxf(sqrtf(tot[DQ + e]), 1e-12f);
    const float t = temp[h];
    float* sp = stats + (size_t)(b * 8 + h) * DQ * 4;
    for (int d = 0; d < DQ; d++) {
      float s[4], mx = -1e30f;
#pragma unroll
      for (int e = 0; e < 4; e++) {
        s[e] = tot[DQ + 4 + d * 4 + e] * invq[d] * invk[e] * t;
        mx = fmaxf(mx, s[e]);
      }
      float sum = 0.f;
#pragma unroll
      for (int e = 0; e < 4; e++) { s[e] = expf(s[e] - mx); sum += s[e]; }
#pragma unroll
      for (int e = 0; e < 4; e++) sp[d * 4 + e] = s[e] / sum;
    }
  }
}

// ---------------- channel-attn: apply attn to v ----------------------------
template <int DQ>
__global__ __launch_bounds__(256)
void k_attn_apply(const float* __restrict__ v, long v_bs,
                  const float* __restrict__ stats,
                  float* __restrict__ out, long out_bs) {
  const int n = blockIdx.x * 256 + threadIdx.x;
  const int h = blockIdx.y, b = blockIdx.z;
  float vv[4];
#pragma unroll
  for (int e = 0; e < 4; e++) vv[e] = v[(size_t)b * v_bs + (size_t)(h * 4 + e) * N + n];
  const float* A = stats + (size_t)(b * 8 + h) * DQ * 4;
#pragma unroll
  for (int d = 0; d < DQ; d++) {
    const float a = A[d * 4] * vv[0] + A[d * 4 + 1] * vv[1] + A[d * 4 + 2] * vv[2] + A[d * 4 + 3] * vv[3];
    out[(size_t)b * out_bs + (size_t)(h * DQ + d) * N + n] = a;
  }
}

// ---------------- avgpool 2x2 on CAT2 --------------------------------------
__global__ __launch_bounds__(256) void k_avgpool(const float* __restrict__ in,
                                                 float* __restrict__ out) {
  const int id = blockIdx.x * 256 + threadIdx.x;  // B*64*64*64
  const int ox = id & 63, oy = (id >> 6) & 63, c = (id >> 12) & 63, b = id >> 18;
  const float* p = in + ((size_t)b * 64 + c) * N + (size_t)(oy * 2) * W + ox * 2;
  out[id] = 0.25f * (p[0] + p[1] + p[W] + p[W + 1]);
}

// ---------------- t3 *= sigmoid(nearest_resize(asmall)) --------------------
__global__ __launch_bounds__(256) void k_sigmul(float* __restrict__ t3,
                                                const float* __restrict__ asmall) {
  const int id = blockIdx.x * 256 + threadIdx.x;  // B*166*N
  const int x = id & 127, yv = (id >> 7) & 127;
  const int bc = id >> 14;
  const int iy = (yv * 62) >> 7, ix = (x * 62) >> 7;
  const float a = asmall[(size_t)bc * 3844 + iy * 62 + ix];
  t3[id] *= 1.f / (1.f + expf(-a));
}

// ---------------- deformable conv (stride1, groups=8, bilinear) ------------
template <int K>
__global__ __launch_bounds__(256)
void k_deform(const float* __restrict__ xt, const float* __restrict__ offs, int off_c0,
              const float* __restrict__ wd, const float* __restrict__ bd,
              float* __restrict__ out, int out_c0) {
  constexpr int K2 = K * K, PAD = K / 2;
  const int n = blockIdx.x * 256 + threadIdx.x;
  const int g = blockIdx.y, b = blockIdx.z;
  const int hy = n >> 7, wx = n & 127;
  float acc[4] = {0.f, 0.f, 0.f, 0.f};
  const float* ob = offs + (size_t)b * (166 * N) + (size_t)off_c0 * N + n;
  const float* xb = xt + ((size_t)b * N) * 32 + g * 4;
  const float* wg = wd + (size_t)(g * 4) * (4 * K2);
  for (int tap = 0; tap < K2; tap++) {
    const int ky = tap / K, kx = tap % K;
    const float dy = ob[(size_t)(2 * tap) * N];
    const float dx = ob[(size_t)(2 * tap + 1) * N];
    const float py = (float)(hy - PAD + ky) + dy;
    const float px = (float)(wx - PAD + kx) + dx;
    const float y0f = floorf(py), x0f = floorf(px);
    const float fy = py - y0f, fx = px - x0f;
    const int y0 = (int)y0f, x0 = (int)x0f;
    const int y1 = y0 + 1, x1 = x0 + 1;
    float w00 = (1.f - fy) * (1.f - fx), w01 = (1.f - fy) * fx;
    float w10 = fy * (1.f - fx), w11 = fy * fx;
    const bool vy0 = (y0 >= 0) & (y0 < H), vy1 = (y1 >= 0) & (y1 < H);
    const bool vx0 = (x0 >= 0) & (x0 < W), vx1 = (x1 >= 0) & (x1 < W);
    w00 = (vy0 & vx0) ? w00 : 0.f;
    w01 = (vy0 & vx1) ? w01 : 0.f;
    w10 = (vy1 & vx0) ? w10 : 0.f;
    w11 = (vy1 & vx1) ? w11 : 0.f;
    const int cy0 = min(max(y0, 0), H - 1), cy1 = min(max(y1, 0), H - 1);
    const int cx0 = min(max(x0, 0), W - 1), cx1 = min(max(x1, 0), W - 1);
    const float4 g00 = *(const float4*)(xb + (size_t)(cy0 * W + cx0) * 32);
    const float4 g01 = *(const float4*)(xb + (size_t)(cy0 * W + cx1) * 32);
    const float4 g10 = *(const float4*)(xb + (size_t)(cy1 * W + cx0) * 32);
    const float4 g11 = *(const float4*)(xb + (size_t)(cy1 * W + cx1) * 32);
    const float s0 = w00 * g00.x + w01 * g01.x + w10 * g10.x + w11 * g11.x;
    const float s1 = w00 * g00.y + w01 * g01.y + w10 * g10.y + w11 * g11.y;
    const float s2 = w00 * g00.z + w01 * g01.z + w10 * g10.z + w11 * g11.z;
    const float s3 = w00 * g00.w + w01 * g01.w + w10 * g10.w + w11 * g11.w;
    const float* wt = wg + tap;
#pragma unroll
    for (int o = 0; o < 4; o++) {
      const float* wr = wt + (size_t)(o * 4) * K2;
      acc[o] += s0 * wr[0] + s1 * wr[K2] + s2 * wr[2 * K2] + s3 * wr[3 * K2];
    }
  }
#pragma unroll
  for (int o = 0; o < 4; o++) {
    const float r = fmaxf(acc[o] + bd[g * 4 + o], 0.f);
    out[((size_t)b * 96 + (out_c0 + g * 4 + o)) * N + n] = r;
  }
}

// ---------------------------------------------------------------------------
extern "C" void kernel_launch(void* const* d_in, const int* in_sizes, int n_in,
                              void* d_out, int out_size, void* d_ws, size_t ws_size,
                              hipStream_t stream) {
  // All reference dtypes are float32 — use inputs in place.
  const float* fx       = (const float*)d_in[0];
  const float* fy       = (const float*)d_in[1];
  const float* w_temp   = (const float*)d_in[2];
  const float* w_po     = (const float*)d_in[3];
  const float* w_lp1    = (const float*)d_in[4];
  const float* w_lp2    = (const float*)d_in[5];
  const float* ln_g     = (const float*)d_in[6];
  const float* ln_b     = (const float*)d_in[7];
  const float* w_tempin = (const float*)d_in[8];
  const float* w_qkv    = (const float*)d_in[9];
  const float* w_qkvd   = (const float*)d_in[10];
  const float* w_mproj  = (const float*)d_in[11];
  const float* w_c3     = (const float*)d_in[12];
  const float* w_k2     = (const float*)d_in[13];
  const float* w_k3     = (const float*)d_in[14];
  const float* w_k4     = (const float*)d_in[15];
  const float* w_d3     = (const float*)d_in[16];
  const float* b_d3     = (const float*)d_in[17];
  const float* w_d5     = (const float*)d_in[18];
  const float* b_d5     = (const float*)d_in[19];
  const float* w_d7     = (const float*)d_in[20];
  const float* b_d7     = (const float*)d_in[21];
  const float* w_pw     = (const float*)d_in[22];
  const float* b_pw     = (const float*)d_in[23];
  float* ws = (float*)d_ws;

  // ---- workspace layout (fp32 elements), time-multiplexed regions ----
  size_t off = 0;
  auto buf = [&](size_t nelem) { float* p = ws + off; off += nelem; return p; };
  float* CAT2   = buf(2097152);   // [B,64,N] [x;y], lives whole pass
  float* XT     = buf(1048576);   // [B,N,32] x NHWC (lnorm + deform gathers)
  float* R1     = buf(1048576);   // XN, then ATTN
  float* R2     = buf(3145728);   // QKV1, then CAT1, then ATTN2
  float* R3     = buf(3145728);   // QKV2, then POOL+ASMALL
  float* PROMPT = buf(1048576);
  float* R4     = buf(5439488);   // T3, then CAT3+KFEAT
  float* OFFS   = buf(5439488);
  float* STATS  = buf(1024);
  (void)ws_size; (void)out_size; (void)n_in; (void)in_sizes;

  float* XN = R1;     float* ATTN = R1;
  float* QKV1 = R2;   float* CAT1 = R2;   float* ATTN2 = R2;
  float* QKV2 = R3;   float* POOL = R3;   float* ASMALL = R3 + 524288;
  float* T3 = R4;     float* CAT3 = R4;   float* KFEAT = R4 + 3145728;
  float* ST_IN = STATS;        // inner attn: B*8*4*4 = 256
  float* ST_FI = STATS + 256;  // final attn: B*8*8*4 = 512

  const long bs64 = 64L * N, bs32 = 32L * N, bs96 = 96L * N, bs166 = 166L * N;

  // conv3 tiling: 64x8 output tile. 128x128 -> tiles_x=2, 32 tiles.
  //               62x62 (k2)        -> tiles_x=1, 8 tiles.

  // 1. prep CAT2 + XT
  k_prep<<<dim3(N / 256, B), 256, 0, stream>>>(fx, fy, CAT2, XT);
  // 2. layernorm
  k_lnorm<<<dim3(N / 256, B), 256, 0, stream>>>(XT, ln_g, ln_b, XN);
  // 3. qkv 1x1: XN(32) -> QKV1(96)
  k_conv1x1<<<dim3(N / 256, 24, B), 256, 0, stream>>>(
      XN, bs32, 32, w_qkv, nullptr, nullptr, 0, QKV1, bs96, 0);
  // 4. grouped 3x3: QKV1 -> QKV2
  k_dwconv<<<dim3(N / 256, 32, B), 256, 0, stream>>>(QKV1, w_qkvd, QKV2);
  // 5/6. inner channel attention (dq=4): qi,ki,vi slices of QKV2
  k_attn_stats<4><<<dim3(8, B), 256, 0, stream>>>(
      QKV2, bs96, nullptr, 0, QKV2 + bs32, bs96, w_tempin, ST_IN);
  k_attn_apply<4><<<dim3(N / 256, 8, B), 256, 0, stream>>>(
      QKV2 + 2 * bs32, bs96, ST_IN, ATTN, bs32);
  // 7. xg = x + mproj(ATTN) -> CAT1 ch 64..95
  k_conv1x1<<<dim3(N / 256, 8, B), 256, 0, stream>>>(
      ATTN, bs32, 32, w_mproj, nullptr, CAT2, bs64, CAT1, bs96, 64);
  // 8. l1 = lp1(x) -> CAT1 ch 0..31
  k_conv1x1<<<dim3(N / 256, 8, B), 256, 0, stream>>>(
      CAT2, bs64, 32, w_lp1, nullptr, nullptr, 0, CAT1, bs96, 0);
  // 9. l2 = lp2 3x3(x) -> CAT1 ch 32..63
  k_conv3<8><<<dim3(32, 4, B), 256, 0, stream>>>(
      CAT2, bs64, 32, H, W, w_lp2, 32, CAT1, bs96, 32, H, W, 1, 2);
  // 10. prompt = c3 3x3(CAT1)
  k_conv3<8><<<dim3(32, 4, B), 256, 0, stream>>>(
      CAT1, bs96, 96, H, W, w_c3, 32, PROMPT, bs32, 0, H, W, 1, 2);
  // 11. avgpool CAT2 -> POOL
  k_avgpool<<<dim3((B * 64 * 64 * 64) / 256), 256, 0, stream>>>(CAT2, POOL);
  // 12. k2 3x3 valid: POOL(64,64x64) -> ASMALL(166,62x62)
  k_conv3<8><<<dim3(8, 21, B), 256, 0, stream>>>(
      POOL, 64L * 4096, 64, 64, 64, w_k2, 166, ASMALL, 166L * 3844, 0, 62, 62, 0, 1);
  // 13. k3 3x3: CAT2(64) -> T3(166)
  k_conv3<8><<<dim3(32, 21, B), 256, 0, stream>>>(
      CAT2, bs64, 64, H, W, w_k3, 166, T3, bs166, 0, H, W, 1, 2);
  // 14. T3 *= sigmoid(resize(ASMALL))
  k_sigmul<<<dim3((B * 166 * N) / 256), 256, 0, stream>>>(T3, ASMALL);
  // 15. k4 3x3: T3(166) -> OFFS(166)
  k_conv3<8><<<dim3(32, 21, B), 256, 0, stream>>>(
      T3, bs166, 166, H, W, w_k4, 166, OFFS, bs166, 0, H, W, 1, 2);
  // 16-18. deformable convs -> CAT3
  k_deform<3><<<dim3(N / 256, 8, B), 256, 0, stream>>>(XT, OFFS, 0, w_d3, b_d3, CAT3, 0);
  k_deform<5><<<dim3(N / 256, 8, B), 256, 0, stream>>>(XT, OFFS, 18, w_d5, b_d5, CAT3, 32);
  k_deform<7><<<dim3(N / 256, 8, B), 256, 0, stream>>>(XT, OFFS, 68, w_d7, b_d7, CAT3, 64);
  // 19. k_feat = pw 1x1(CAT3) + bias
  k_conv1x1<<<dim3(N / 256, 8, B), 256, 0, stream>>>(
      CAT3, bs96, 96, w_pw, b_pw, nullptr, 0, KFEAT, bs32, 0);
  // 20/21. final channel attention (dq=8): q=[x;prompt], k=KFEAT, v=x
  k_attn_stats<8><<<dim3(8, B), 256, 0, stream>>>(
      CAT2, bs64, PROMPT, bs32, KFEAT, bs32, w_temp, ST_FI);
  k_attn_apply<8><<<dim3(N / 256, 8, B), 256, 0, stream>>>(
      CAT2, bs64, ST_FI, ATTN2, bs64);
  // 22. out = po 1x1(ATTN2) -> d_out (fp32)
  k_conv1x1<<<dim3(N / 256, 8, B), 256, 0, stream>>>(
      ATTN2, bs64, 64, w_po, nullptr, nullptr, 0, (float*)d_out, bs32, 0);
}

// Round 5
// 635.258 us; speedup vs baseline: 3.0923x; 2.2280x over previous
//
#include <hip/hip_runtime.h>
#include <hip/hip_bf16.h>

// ---------------------------------------------------------------------------
// MDTA_FOR_VIDEO_Prompted — full-graph HIP implementation.
// B=2, C=32, H=W=128. fp32 in/out; 3x3 convs via bf16 MFMA implicit GEMM.
// R5: k_conv3m (mfma_f32_16x16x32_bf16): tap-major K, NHWC bf16 inputs,
//     64co x 256px block, 4x4 frag blocking/wave (16 mfma : 8 b128 reads).
// ---------------------------------------------------------------------------

constexpr int B = 2, C = 32, H = 128, W = 128, N = H * W;

using bh8   = __attribute__((ext_vector_type(8))) short;  // 8 bf16 = 4 VGPRs
using f32x4 = __attribute__((ext_vector_type(4))) float;

__device__ __forceinline__ ushort f2bf(float v) {
  __hip_bfloat16 h = __float2bfloat16(v);
  return *(ushort*)&h;
}

// ---------------- prep: CAT2=[x;y] NCHW fp32, XT = x NHWC fp32,
//                  CAT2b = [x;y] NHWC bf16 ----------------------------------
__global__ __launch_bounds__(256) void k_prep(const float* __restrict__ x,
                                              const float* __restrict__ y,
                                              float* __restrict__ cat2,
                                              float* __restrict__ xt,
                                              ushort* __restrict__ cat2b) {
  __shared__ float tile[C][257];
  const int b = blockIdx.y, n0 = blockIdx.x * 256, tid = threadIdx.x;
  const int n = n0 + tid;
  for (int c = 0; c < C; c++) {
    float v = x[(size_t)(b * C + c) * N + n];
    tile[c][tid] = v;
    cat2[(size_t)(b * 64 + c) * N + n] = v;
  }
  __syncthreads();
  for (int i = tid; i < C * 256; i += 256) {
    int c = i & 31, nl = i >> 5;
    const float v = tile[c][nl];
    xt[((size_t)b * N + n0 + nl) * C + c] = v;
    cat2b[((size_t)b * N + n0 + nl) * 64 + c] = f2bf(v);
  }
  __syncthreads();
  for (int c = 0; c < C; c++) {
    float v = y[(size_t)(b * C + c) * N + n];
    tile[c][tid] = v;
    cat2[(size_t)(b * 64 + 32 + c) * N + n] = v;
  }
  __syncthreads();
  for (int i = tid; i < C * 256; i += 256) {
    int c = i & 31, nl = i >> 5;
    cat2b[((size_t)b * N + n0 + nl) * 64 + 32 + c] = f2bf(tile[c][nl]);
  }
}

// ---------------- NCHW fp32 -> NHWC bf16 cast (32-ch chunk per block) ------
__global__ __launch_bounds__(256)
void k_castn(const float* __restrict__ src, ushort* __restrict__ dst,
             int isp, int cin_real, int cin_pad) {
  const int p = blockIdx.x * 256 + threadIdx.x;
  const int ci0 = blockIdx.y * 32, b = blockIdx.z;
  const float* sp = src + (size_t)b * cin_real * isp + p;
  ushort tmp[32];
#pragma unroll
  for (int j = 0; j < 32; j++) {
    const int ci = ci0 + j;
    const float v = (ci < cin_real) ? sp[(size_t)ci * isp] : 0.f;
    tmp[j] = f2bf(v);
  }
  ushort* dp = dst + ((size_t)b * isp + p) * cin_pad + ci0;
#pragma unroll
  for (int k = 0; k < 4; k++) *(bh8*)(dp + k * 8) = *(const bh8*)&tmp[k * 8];
}

// ---------------- weight pack: OIHW fp32 -> [co][t][ci] bf16 (padded) ------
struct WEnt { const float* src; ushort* dst; int cout_real, cin_real, kc32, total; };
struct WArgs { WEnt e[5]; };

__global__ __launch_bounds__(256) void k_wpack(WArgs a) {
  const WEnt en = a.e[blockIdx.y];
  const int tk = 9 * en.kc32;
  for (int i = blockIdx.x * 256 + threadIdx.x; i < en.total; i += gridDim.x * 256) {
    const int co = i / tk, rem = i - co * tk;
    const int t = rem / en.kc32, ci = rem - t * en.kc32;
    float v = 0.f;
    if (co < en.cout_real && ci < en.cin_real)
      v = en.src[((size_t)co * en.cin_real + ci) * 9 + t];
    en.dst[i] = f2bf(v);
  }
}

// ---------------- 3x3 conv as bf16 MFMA implicit GEMM ----------------------
// block: 4 waves, 64 couts x (2 rows x 128 cols) px. K = 9 * kchunks*32.
// LDS x-tile: [4 rows][130 cols][32 ci] bf16. A-frags from global wp (L2).
__global__ __launch_bounds__(256)
void k_conv3m(const ushort* __restrict__ xin, long in_bs, int in_cs, int ih, int iw,
              const ushort* __restrict__ wp, int kchunks, int cout_real,
              float* __restrict__ out, long out_bs, int out_coff,
              int oh, int ow, int pad) {
  __shared__ ushort xt[4 * 130 * 32];
  const int tid = threadIdx.x, b = blockIdx.z;
  const int y0 = blockIdx.x * 2, co0 = blockIdx.y * 64;
  const int wv = tid >> 6, lane = tid & 63;
  const int row_sel = wv >> 1, col0 = (wv & 1) * 64;
  const int q = lane >> 4, n = lane & 15, q8 = q * 8;
  const int kc32 = kchunks * 32;
  const ushort* xb = xin + (size_t)b * in_bs;

  f32x4 acc[4][4];
#pragma unroll
  for (int mt = 0; mt < 4; mt++)
#pragma unroll
    for (int nb = 0; nb < 4; nb++) acc[mt][nb] = (f32x4){0.f, 0.f, 0.f, 0.f};

  for (int cc = 0; cc < kchunks; cc++) {
    __syncthreads();
    for (int i = tid; i < 2080; i += 256) {
      const int qq = i & 3, rc = i >> 2;
      const int r = rc / 130, c = rc - r * 130;
      const int yy = y0 - pad + r, xx = c - pad;
      bh8 v = {0, 0, 0, 0, 0, 0, 0, 0};
      if (yy >= 0 && yy < ih && xx >= 0 && xx < iw)
        v = *(const bh8*)(xb + ((size_t)yy * iw + xx) * in_cs + cc * 32 + qq * 8);
      *(bh8*)&xt[rc * 32 + qq * 8] = v;
    }
    __syncthreads();
#pragma unroll
    for (int t = 0; t < 9; t++) {
      const int dy = t / 3, dx = t - dy * 3;
      bh8 a[4], bb[4];
#pragma unroll
      for (int mt = 0; mt < 4; mt++)
        a[mt] = *(const bh8*)(wp + (size_t)((co0 + mt * 16 + n) * 9 + t) * kc32 + cc * 32 + q8);
#pragma unroll
      for (int nb = 0; nb < 4; nb++)
        bb[nb] = *(const bh8*)&xt[((row_sel + dy) * 130 + col0 + nb * 16 + n + dx) * 32 + q8];
#pragma unroll
      for (int mt = 0; mt < 4; mt++)
#pragma unroll
        for (int nb = 0; nb < 4; nb++)
          acc[mt][nb] = __builtin_amdgcn_mfma_f32_16x16x32_bf16(a[mt], bb[nb], acc[mt][nb], 0, 0, 0);
    }
  }

  const int oy = y0 + row_sel;
  const size_t osp = (size_t)oh * ow;
  float* ob = out + (size_t)b * out_bs + (size_t)out_coff * osp + (size_t)oy * ow;
#pragma unroll
  for (int mt = 0; mt < 4; mt++)
#pragma unroll
    for (int r = 0; r < 4; r++) {
      const int co = co0 + mt * 16 + q * 4 + r;
      if (co < cout_real) {
#pragma unroll
        for (int nb = 0; nb < 4; nb++) {
          const int px = col0 + nb * 16 + n;
          if (px < ow) ob[(size_t)co * osp + px] = acc[mt][nb][r];
        }
      }
    }
}

// ---------------- layernorm over channels ----------------------------------
__global__ __launch_bounds__(256) void k_lnorm(const float* __restrict__ xt,
                                               const float* __restrict__ g,
                                               const float* __restrict__ bta,
                                               float* __restrict__ xn) {
  const int b = blockIdx.y;
  const int n = blockIdx.x * 256 + threadIdx.x;
  const float* p = xt + ((size_t)b * N + n) * C;
  float v[C], s = 0.f, ss = 0.f;
#pragma unroll
  for (int c = 0; c < C; c++) { v[c] = p[c]; s += v[c]; ss += v[c] * v[c]; }
  const float mu = s * (1.f / C);
  const float var = ss * (1.f / C) - mu * mu;
  const float inv = rsqrtf(var + 1e-5f);
#pragma unroll
  for (int c = 0; c < C; c++)
    xn[(size_t)(b * C + c) * N + n] = (v[c] - mu) * inv * g[c] + bta[c];
}

// ---------------- generic 1x1 conv (4 couts/thread) ------------------------
__global__ __launch_bounds__(256)
void k_conv1x1(const float* __restrict__ in, long in_bs, int cin,
               const float* __restrict__ wts, const float* __restrict__ bias,
               const float* __restrict__ resid, long res_bs,
               float* __restrict__ out, long out_bs, int out_coff) {
  const int n = blockIdx.x * 256 + threadIdx.x;
  const int co0 = blockIdx.y * 4, b = blockIdx.z;
  const float* ip = in + (size_t)b * in_bs + n;
  const float* w = wts + (size_t)co0 * cin;
  float a0 = 0, a1 = 0, a2 = 0, a3 = 0;
  for (int ci = 0; ci < cin; ci++) {
    float xv = ip[(size_t)ci * N];
    a0 += xv * w[ci]; a1 += xv * w[cin + ci];
    a2 += xv * w[2 * cin + ci]; a3 += xv * w[3 * cin + ci];
  }
  float acc[4] = {a0, a1, a2, a3};
#pragma unroll
  for (int o = 0; o < 4; o++) {
    const int co = co0 + o;
    float r = acc[o];
    if (bias) r += bias[co];
    if (resid) r += resid[(size_t)b * res_bs + (size_t)co * N + n];
    out[(size_t)b * out_bs + (size_t)(out_coff + co) * N + n] = r;
  }
}

// ---------------- grouped 3x3 conv (groups=32, 3 in / 3 out per group) -----
__global__ __launch_bounds__(256) void k_dwconv(const float* __restrict__ in,
                                                const float* __restrict__ wts,
                                                float* __restrict__ out) {
  const int n = blockIdx.x * 256 + threadIdx.x;
  const int g = blockIdx.y, b = blockIdx.z;
  const int h0 = n >> 7, w0 = n & 127;
  float acc[3] = {0.f, 0.f, 0.f};
  for (int ci = 0; ci < 3; ci++) {
    const float* ip = in + ((size_t)b * 96 + g * 3 + ci) * N;
#pragma unroll
    for (int ky = 0; ky < 3; ky++) {
      const int iy = h0 - 1 + ky;
      if (iy < 0 || iy >= H) continue;
#pragma unroll
      for (int kx = 0; kx < 3; kx++) {
        const int ix = w0 - 1 + kx;
        if (ix < 0 || ix >= W) continue;
        const float v = ip[(size_t)iy * W + ix];
#pragma unroll
        for (int o = 0; o < 3; o++)
          acc[o] += v * wts[((size_t)(g * 3 + o) * 3 + ci) * 9 + ky * 3 + kx];
      }
    }
  }
#pragma unroll
  for (int o = 0; o < 3; o++)
    out[((size_t)b * 96 + g * 3 + o) * N + n] = acc[o];
}

// ---------------- channel-attn: norms + gram + softmax ---------------------
template <int DQ>
__global__ __launch_bounds__(256)
void k_attn_stats(const float* __restrict__ q1, long q1_bs,
                  const float* __restrict__ q2, long q2_bs,
                  const float* __restrict__ k, long k_bs,
                  const float* __restrict__ temp, float* __restrict__ stats) {
  const int h = blockIdx.x, b = blockIdx.y, tid = threadIdx.x;
  const float* qp[DQ];
#pragma unroll
  for (int d = 0; d < DQ; d++) {
    const int qc = h * DQ + d;
    qp[d] = (qc < 32) ? (q1 + (size_t)b * q1_bs + (size_t)qc * N)
                      : (q2 + (size_t)b * q2_bs + (size_t)(qc - 32) * N);
  }
  const float* kp[4];
#pragma unroll
  for (int e = 0; e < 4; e++) kp[e] = k + (size_t)b * k_bs + (size_t)(h * 4 + e) * N;

  constexpr int NV = DQ + 4 + DQ * 4;
  float ssq[DQ] = {}, ssk[4] = {}, gr[DQ][4] = {};
  for (int n = tid; n < N; n += 256) {
    float qv[DQ], kv[4];
#pragma unroll
    for (int d = 0; d < DQ; d++) { qv[d] = qp[d][n]; ssq[d] += qv[d] * qv[d]; }
#pragma unroll
    for (int e = 0; e < 4; e++) { kv[e] = kp[e][n]; ssk[e] += kv[e] * kv[e]; }
#pragma unroll
    for (int d = 0; d < DQ; d++)
#pragma unroll
      for (int e = 0; e < 4; e++) gr[d][e] += qv[d] * kv[e];
  }
  float vals[NV];
#pragma unroll
  for (int d = 0; d < DQ; d++) vals[d] = ssq[d];
#pragma unroll
  for (int e = 0; e < 4; e++) vals[DQ + e] = ssk[e];
#pragma unroll
  for (int d = 0; d < DQ; d++)
#pragma unroll
    for (int e = 0; e < 4; e++) vals[DQ + 4 + d * 4 + e] = gr[d][e];
#pragma unroll
  for (int j = 0; j < NV; j++) {
    float v = vals[j];
    for (int m = 32; m > 0; m >>= 1) v += __shfl_xor(v, m, 64);
    vals[j] = v;
  }
  __shared__ float red[4][NV];
  const int wid = tid >> 6, lane = tid & 63;
  if (lane == 0)
#pragma unroll
    for (int j = 0; j < NV; j++) red[wid][j] = vals[j];
  __syncthreads();
  if (tid == 0) {
    float tot[NV];
#pragma unroll
    for (int j = 0; j < NV; j++) tot[j] = red[0][j] + red[1][j] + red[2][j] + red[3][j];
    float invq[DQ], invk[4];
#pragma unroll
    for (int d = 0; d < DQ; d++) invq[d] = 1.f / fmaxf(sqrtf(tot[d]), 1e-12f);
#pragma unroll
    for (int e = 0; e < 4; e++) invk[e] = 1.f / fmaxf(sqrtf(tot[DQ + e]), 1e-12f);
    const float t = temp[h];
    float* sp = stats + (size_t)(b * 8 + h) * DQ * 4;
    for (int d = 0; d < DQ; d++) {
      float s[4], mx = -1e30f;
#pragma unroll
      for (int e = 0; e < 4; e++) {
        s[e] = tot[DQ + 4 + d * 4 + e] * invq[d] * invk[e] * t;
        mx = fmaxf(mx, s[e]);
      }
      float sum = 0.f;
#pragma unroll
      for (int e = 0; e < 4; e++) { s[e] = expf(s[e] - mx); sum += s[e]; }
#pragma unroll
      for (int e = 0; e < 4; e++) sp[d * 4 + e] = s[e] / sum;
    }
  }
}

// ---------------- channel-attn: apply attn to v ----------------------------
template <int DQ>
__global__ __launch_bounds__(256)
void k_attn_apply(const float* __restrict__ v, long v_bs,
                  const float* __restrict__ stats,
                  float* __restrict__ out, long out_bs) {
  const int n = blockIdx.x * 256 + threadIdx.x;
  const int h = blockIdx.y, b = blockIdx.z;
  float vv[4];
#pragma unroll
  for (int e = 0; e < 4; e++) vv[e] = v[(size_t)b * v_bs + (size_t)(h * 4 + e) * N + n];
  const float* A = stats + (size_t)(b * 8 + h) * DQ * 4;
#pragma unroll
  for (int d = 0; d < DQ; d++) {
    const float a = A[d * 4] * vv[0] + A[d * 4 + 1] * vv[1] + A[d * 4 + 2] * vv[2] + A[d * 4 + 3] * vv[3];
    out[(size_t)b * out_bs + (size_t)(h * DQ + d) * N + n] = a;
  }
}

// ---------------- avgpool 2x2 on CAT2 --------------------------------------
__global__ __launch_bounds__(256) void k_avgpool(const float* __restrict__ in,
                                                 float* __restrict__ out) {
  const int id = blockIdx.x * 256 + threadIdx.x;  // B*64*64*64
  const int ox = id & 63, oy = (id >> 6) & 63, c = (id >> 12) & 63, b = id >> 18;
  const float* p = in + ((size_t)b * 64 + c) * N + (size_t)(oy * 2) * W + ox * 2;
  out[id] = 0.25f * (p[0] + p[1] + p[W] + p[W + 1]);
}

// ---------------- t3 *= sigmoid(nearest_resize(asmall)) --------------------
__global__ __launch_bounds__(256) void k_sigmul(float* __restrict__ t3,
                                                const float* __restrict__ asmall) {
  const int id = blockIdx.x * 256 + threadIdx.x;  // B*166*N
  const int x = id & 127, yv = (id >> 7) & 127;
  const int bc = id >> 14;
  const int iy = (yv * 62) >> 7, ix = (x * 62) >> 7;
  const float a = asmall[(size_t)bc * 3844 + iy * 62 + ix];
  t3[id] *= 1.f / (1.f + expf(-a));
}

// ---------------- deformable conv (stride1, groups=8, bilinear) ------------
template <int K>
__global__ __launch_bounds__(256)
void k_deform(const float* __restrict__ xt, const float* __restrict__ offs, int off_c0,
              const float* __restrict__ wd, const float* __restrict__ bd,
              float* __restrict__ out, int out_c0) {
  constexpr int K2 = K * K, PAD = K / 2;
  const int n = blockIdx.x * 256 + threadIdx.x;
  const int g = blockIdx.y, b = blockIdx.z;
  const int hy = n >> 7, wx = n & 127;
  float acc[4] = {0.f, 0.f, 0.f, 0.f};
  const float* ob = offs + (size_t)b * (166 * N) + (size_t)off_c0 * N + n;
  const float* xb = xt + ((size_t)b * N) * 32 + g * 4;
  const float* wg = wd + (size_t)(g * 4) * (4 * K2);
  for (int tap = 0; tap < K2; tap++) {
    const int ky = tap / K, kx = tap % K;
    const float dy = ob[(size_t)(2 * tap) * N];
    const float dx = ob[(size_t)(2 * tap + 1) * N];
    const float py = (float)(hy - PAD + ky) + dy;
    const float px = (float)(wx - PAD + kx) + dx;
    const float y0f = floorf(py), x0f = floorf(px);
    const float fy = py - y0f, fx = px - x0f;
    const int y0 = (int)y0f, x0 = (int)x0f;
    const int y1 = y0 + 1, x1 = x0 + 1;
    float w00 = (1.f - fy) * (1.f - fx), w01 = (1.f - fy) * fx;
    float w10 = fy * (1.f - fx), w11 = fy * fx;
    const bool vy0 = (y0 >= 0) & (y0 < H), vy1 = (y1 >= 0) & (y1 < H);
    const bool vx0 = (x0 >= 0) & (x0 < W), vx1 = (x1 >= 0) & (x1 < W);
    w00 = (vy0 & vx0) ? w00 : 0.f;
    w01 = (vy0 & vx1) ? w01 : 0.f;
    w10 = (vy1 & vx0) ? w10 : 0.f;
    w11 = (vy1 & vx1) ? w11 : 0.f;
    const int cy0 = min(max(y0, 0), H - 1), cy1 = min(max(y1, 0), H - 1);
    const int cx0 = min(max(x0, 0), W - 1), cx1 = min(max(x1, 0), W - 1);
    const float4 g00 = *(const float4*)(xb + (size_t)(cy0 * W + cx0) * 32);
    const float4 g01 = *(const float4*)(xb + (size_t)(cy0 * W + cx1) * 32);
    const float4 g10 = *(const float4*)(xb + (size_t)(cy1 * W + cx0) * 32);
    const float4 g11 = *(const float4*)(xb + (size_t)(cy1 * W + cx1) * 32);
    const float s0 = w00 * g00.x + w01 * g01.x + w10 * g10.x + w11 * g11.x;
    const float s1 = w00 * g00.y + w01 * g01.y + w10 * g10.y + w11 * g11.y;
    const float s2 = w00 * g00.z + w01 * g01.z + w10 * g10.z + w11 * g11.z;
    const float s3 = w00 * g00.w + w01 * g01.w + w10 * g10.w + w11 * g11.w;
    const float* wt = wg + tap;
#pragma unroll
    for (int o = 0; o < 4; o++) {
      const float* wr = wt + (size_t)(o * 4) * K2;
      acc[o] += s0 * wr[0] + s1 * wr[K2] + s2 * wr[2 * K2] + s3 * wr[3 * K2];
    }
  }
#pragma unroll
  for (int o = 0; o < 4; o++) {
    const float r = fmaxf(acc[o] + bd[g * 4 + o], 0.f);
    out[((size_t)b * 96 + (out_c0 + g * 4 + o)) * N + n] = r;
  }
}

// ---------------------------------------------------------------------------
extern "C" void kernel_launch(void* const* d_in, const int* in_sizes, int n_in,
                              void* d_out, int out_size, void* d_ws, size_t ws_size,
                              hipStream_t stream) {
  const float* fx       = (const float*)d_in[0];
  const float* fy       = (const float*)d_in[1];
  const float* w_temp   = (const float*)d_in[2];
  const float* w_po     = (const float*)d_in[3];
  const float* w_lp1    = (const float*)d_in[4];
  const float* w_lp2    = (const float*)d_in[5];
  const float* ln_g     = (const float*)d_in[6];
  const float* ln_b     = (const float*)d_in[7];
  const float* w_tempin = (const float*)d_in[8];
  const float* w_qkv    = (const float*)d_in[9];
  const float* w_qkvd   = (const float*)d_in[10];
  const float* w_mproj  = (const float*)d_in[11];
  const float* w_c3     = (const float*)d_in[12];
  const float* w_k2     = (const float*)d_in[13];
  const float* w_k3     = (const float*)d_in[14];
  const float* w_k4     = (const float*)d_in[15];
  const float* w_d3     = (const float*)d_in[16];
  const float* b_d3     = (const float*)d_in[17];
  const float* w_d5     = (const float*)d_in[18];
  const float* b_d5     = (const float*)d_in[19];
  const float* w_d7     = (const float*)d_in[20];
  const float* b_d7     = (const float*)d_in[21];
  const float* w_pw     = (const float*)d_in[22];
  const float* b_pw     = (const float*)d_in[23];
  float* ws = (float*)d_ws;

  // ---- workspace layout (fp32 elements), time-multiplexed regions ----
  size_t off = 0;
  auto buf = [&](size_t nelem) { float* p = ws + off; off += nelem; return p; };
  float* CAT2   = buf(2097152);   // [B,64,N] fp32, whole pass
  float* XT     = buf(1048576);   // [B,N,32] fp32 NHWC (lnorm + deform)
  float* R1     = buf(1048576);   // XN, then ATTN
  float* R2     = buf(3145728);   // QKV1 -> CAT1 -> T3b(bf16) -> ATTN2
  float* R3     = buf(3145728);   // QKV2 -> POOL+ASMALL+POOLb
  float* PROMPT = buf(1048576);
  float* R4     = buf(5439488);   // T3, then CAT3+KFEAT
  float* OFFS   = buf(5439488);   // CAT1b(bf16) until k4 writes OFFS
  float* STATS  = buf(1024);
  float* CAT2Bf = buf(524288);    // CAT2b bf16 NHWC [B,N,64]
  float* WPf    = buf(327680);    // packed bf16 weights
  (void)ws_size; (void)out_size; (void)n_in; (void)in_sizes;

  float* XN = R1;     float* ATTN = R1;
  float* QKV1 = R2;   float* CAT1 = R2;   float* ATTN2 = R2;
  float* QKV2 = R3;   float* POOL = R3;   float* ASMALL = R3 + 524288;
  float* T3 = R4;     float* CAT3 = R4;   float* KFEAT = R4 + 3145728;
  float* ST_IN = STATS;        // inner attn stats
  float* ST_FI = STATS + 256;  // final attn stats

  ushort* CAT2b = (ushort*)CAT2Bf;          // [B*N][64]
  ushort* POOLb = (ushort*)(R3 + 1835008);  // [B*4096][64]
  ushort* CAT1b = (ushort*)OFFS;            // [B*N][96] (dead once k4 runs)
  ushort* T3b   = (ushort*)R2;              // [B*N][192] (CAT1 dead by then)

  // packed weights (ushort offsets in WPf region)
  ushort* WPu = (ushort*)WPf;
  ushort* wp_lp2 = WPu;                    // 64*9*32   = 18432
  ushort* wp_c3  = wp_lp2 + 18432;         // 64*9*96   = 55296
  ushort* wp_k2  = wp_c3 + 55296;          // 192*9*64  = 110592
  ushort* wp_k3  = wp_k2 + 110592;         // 192*9*64  = 110592
  ushort* wp_k4  = wp_k3 + 110592;         // 192*9*192 = 331776

  const long bs64 = 64L * N, bs32 = 32L * N, bs96 = 96L * N, bs166 = 166L * N;

  // 0. pack conv weights to bf16 [co][t][ci]
  WArgs wa;
  wa.e[0] = { w_lp2, wp_lp2, 32, 32, 32, 64 * 9 * 32 };
  wa.e[1] = { w_c3,  wp_c3,  32, 96, 96, 64 * 9 * 96 };
  wa.e[2] = { w_k2,  wp_k2, 166, 64, 64, 192 * 9 * 64 };
  wa.e[3] = { w_k3,  wp_k3, 166, 64, 64, 192 * 9 * 64 };
  wa.e[4] = { w_k4,  wp_k4, 166, 166, 192, 192 * 9 * 192 };
  k_wpack<<<dim3(64, 5), 256, 0, stream>>>(wa);
  // 1. prep CAT2 + XT + CAT2b
  k_prep<<<dim3(N / 256, B), 256, 0, stream>>>(fx, fy, CAT2, XT, CAT2b);
  // 2. layernorm
  k_lnorm<<<dim3(N / 256, B), 256, 0, stream>>>(XT, ln_g, ln_b, XN);
  // 3. qkv 1x1: XN(32) -> QKV1(96)
  k_conv1x1<<<dim3(N / 256, 24, B), 256, 0, stream>>>(
      XN, bs32, 32, w_qkv, nullptr, nullptr, 0, QKV1, bs96, 0);
  // 4. grouped 3x3: QKV1 -> QKV2
  k_dwconv<<<dim3(N / 256, 32, B), 256, 0, stream>>>(QKV1, w_qkvd, QKV2);
  // 5/6. inner channel attention (dq=4)
  k_attn_stats<4><<<dim3(8, B), 256, 0, stream>>>(
      QKV2, bs96, nullptr, 0, QKV2 + bs32, bs96, w_tempin, ST_IN);
  k_attn_apply<4><<<dim3(N / 256, 8, B), 256, 0, stream>>>(
      QKV2 + 2 * bs32, bs96, ST_IN, ATTN, bs32);
  // 7. xg = x + mproj(ATTN) -> CAT1 ch 64..95
  k_conv1x1<<<dim3(N / 256, 8, B), 256, 0, stream>>>(
      ATTN, bs32, 32, w_mproj, nullptr, CAT2, bs64, CAT1, bs96, 64);
  // 8. l1 = lp1(x) -> CAT1 ch 0..31
  k_conv1x1<<<dim3(N / 256, 8, B), 256, 0, stream>>>(
      CAT2, bs64, 32, w_lp1, nullptr, nullptr, 0, CAT1, bs96, 0);
  // 9. l2 = lp2 3x3(x via CAT2b ci 0..31) -> CAT1 ch 32..63
  k_conv3m<<<dim3(64, 1, B), 256, 0, stream>>>(
      CAT2b, (long)N * 64, 64, H, W, wp_lp2, 1, 32, CAT1, bs96, 32, H, W, 1);
  // 9b. cast CAT1 -> CAT1b (NHWC bf16, 96ch)
  k_castn<<<dim3(64, 3, B), 256, 0, stream>>>(CAT1, CAT1b, N, 96, 96);
  // 10. prompt = c3 3x3(CAT1b)
  k_conv3m<<<dim3(64, 1, B), 256, 0, stream>>>(
      CAT1b, (long)N * 96, 96, H, W, wp_c3, 3, 32, PROMPT, bs32, 0, H, W, 1);
  // 11. avgpool CAT2 -> POOL; cast -> POOLb
  k_avgpool<<<dim3((B * 64 * 64 * 64) / 256), 256, 0, stream>>>(CAT2, POOL);
  k_castn<<<dim3(16, 2, B), 256, 0, stream>>>(POOL, POOLb, 4096, 64, 64);
  // 12. k2 3x3 valid: POOLb -> ASMALL(166, 62x62)
  k_conv3m<<<dim3(31, 3, B), 256, 0, stream>>>(
      POOLb, 4096L * 64, 64, 64, 64, wp_k2, 2, 166, ASMALL, 166L * 3844, 0, 62, 62, 0);
  // 13. k3 3x3: CAT2b -> T3(166)
  k_conv3m<<<dim3(64, 3, B), 256, 0, stream>>>(
      CAT2b, (long)N * 64, 64, H, W, wp_k3, 2, 166, T3, bs166, 0, H, W, 1);
  // 14. T3 *= sigmoid(resize(ASMALL)); cast T3 -> T3b
  k_sigmul<<<dim3((B * 166 * N) / 256), 256, 0, stream>>>(T3, ASMALL);
  k_castn<<<dim3(64, 6, B), 256, 0, stream>>>(T3, T3b, N, 166, 192);
  // 15. k4 3x3: T3b -> OFFS(166)
  k_conv3m<<<dim3(64, 3, B), 256, 0, stream>>>(
      T3b, (long)N * 192, 192, H, W, wp_k4, 6, 166, OFFS, bs166, 0, H, W, 1);
  // 16-18. deformable convs -> CAT3
  k_deform<3><<<dim3(N / 256, 8, B), 256, 0, stream>>>(XT, OFFS, 0, w_d3, b_d3, CAT3, 0);
  k_deform<5><<<dim3(N / 256, 8, B), 256, 0, stream>>>(XT, OFFS, 18, w_d5, b_d5, CAT3, 32);
  k_deform<7><<<dim3(N / 256, 8, B), 256, 0, stream>>>(XT, OFFS, 68, w_d7, b_d7, CAT3, 64);
  // 19. k_feat = pw 1x1(CAT3) + bias
  k_conv1x1<<<dim3(N / 256, 8, B), 256, 0, stream>>>(
      CAT3, bs96, 96, w_pw, b_pw, nullptr, 0, KFEAT, bs32, 0);
  // 20/21. final channel attention (dq=8): q=[x;prompt], k=KFEAT, v=x
  k_attn_stats<8><<<dim3(8, B), 256, 0, stream>>>(
      CAT2, bs64, PROMPT, bs32, KFEAT, bs32, w_temp, ST_FI);
  k_attn_apply<8><<<dim3(N / 256, 8, B), 256, 0, stream>>>(
      CAT2, bs64, ST_FI, ATTN2, bs64);
  // 22. out = po 1x1(ATTN2) -> d_out (fp32)
  k_conv1x1<<<dim3(N / 256, 8, B), 256, 0, stream>>>(
      ATTN2, bs64, 64, w_po, nullptr, nullptr, 0, (float*)d_out, bs32, 0);
}

// Round 6
// 627.422 us; speedup vs baseline: 3.1309x; 1.0125x over previous
//
#include <hip/hip_runtime.h>
#include <hip/hip_bf16.h>

// ---------------------------------------------------------------------------
// MDTA_FOR_VIDEO_Prompted — full-graph HIP implementation.
// B=2, C=32, H=W=128. fp32 in/out; 3x3 convs via bf16 MFMA implicit GEMM.
// R6: deform = lane-per-channel coalesced gathers + quad bpermute contraction;
//     attn stats two-phase; lnorm/avgpool/sigmul/apply+proj fusions.
// ---------------------------------------------------------------------------

constexpr int B = 2, C = 32, H = 128, W = 128, N = H * W;

using bh8   = __attribute__((ext_vector_type(8))) short;  // 8 bf16 = 4 VGPRs
using f32x4 = __attribute__((ext_vector_type(4))) float;

__device__ __forceinline__ ushort f2bf(float v) {
  __hip_bfloat16 h = __float2bfloat16(v);
  return *(ushort*)&h;
}

// ---------------- prep: CAT2=[x;y] NCHW fp32, XT = x NHWC fp32,
//                  CAT2b = [x;y] NHWC bf16, XN = layernorm(x) NCHW ----------
__global__ __launch_bounds__(256) void k_prep(const float* __restrict__ x,
                                              const float* __restrict__ y,
                                              const float* __restrict__ ln_g,
                                              const float* __restrict__ ln_b,
                                              float* __restrict__ cat2,
                                              float* __restrict__ xt,
                                              ushort* __restrict__ cat2b,
                                              float* __restrict__ xn) {
  __shared__ float tile[C][257];
  const int b = blockIdx.y, n0 = blockIdx.x * 256, tid = threadIdx.x;
  const int n = n0 + tid;
  for (int c = 0; c < C; c++) {
    float v = x[(size_t)(b * C + c) * N + n];
    tile[c][tid] = v;
    cat2[(size_t)(b * 64 + c) * N + n] = v;
  }
  __syncthreads();
  // fused layernorm over channels (each thread owns pixel tid)
  {
    float s = 0.f, ss = 0.f;
#pragma unroll
    for (int c = 0; c < C; c++) { const float v = tile[c][tid]; s += v; ss += v * v; }
    const float mu = s * (1.f / C);
    const float var = ss * (1.f / C) - mu * mu;
    const float inv = rsqrtf(var + 1e-5f);
#pragma unroll
    for (int c = 0; c < C; c++)
      xn[(size_t)(b * C + c) * N + n] = (tile[c][tid] - mu) * inv * ln_g[c] + ln_b[c];
  }
  for (int i = tid; i < C * 256; i += 256) {
    int c = i & 31, nl = i >> 5;
    const float v = tile[c][nl];
    xt[((size_t)b * N + n0 + nl) * C + c] = v;
    cat2b[((size_t)b * N + n0 + nl) * 64 + c] = f2bf(v);
  }
  __syncthreads();
  for (int c = 0; c < C; c++) {
    float v = y[(size_t)(b * C + c) * N + n];
    tile[c][tid] = v;
    cat2[(size_t)(b * 64 + 32 + c) * N + n] = v;
  }
  __syncthreads();
  for (int i = tid; i < C * 256; i += 256) {
    int c = i & 31, nl = i >> 5;
    cat2b[((size_t)b * N + n0 + nl) * 64 + 32 + c] = f2bf(tile[c][nl]);
  }
}

// ---------------- NCHW fp32 -> NHWC bf16 cast (32-ch chunk per block) ------
__global__ __launch_bounds__(256)
void k_castn(const float* __restrict__ src, ushort* __restrict__ dst,
             int isp, int cin_real, int cin_pad) {
  const int p = blockIdx.x * 256 + threadIdx.x;
  const int ci0 = blockIdx.y * 32, b = blockIdx.z;
  const float* sp = src + (size_t)b * cin_real * isp + p;
  ushort tmp[32];
#pragma unroll
  for (int j = 0; j < 32; j++) {
    const int ci = ci0 + j;
    const float v = (ci < cin_real) ? sp[(size_t)ci * isp] : 0.f;
    tmp[j] = f2bf(v);
  }
  ushort* dp = dst + ((size_t)b * isp + p) * cin_pad + ci0;
#pragma unroll
  for (int k = 0; k < 4; k++) *(bh8*)(dp + k * 8) = *(const bh8*)&tmp[k * 8];
}

// ---------------- weight pack: OIHW fp32 -> [co][t][ci] bf16 (padded) ------
struct WEnt { const float* src; ushort* dst; int cout_real, cin_real, kc32, total; };
struct WArgs { WEnt e[5]; };

__global__ __launch_bounds__(256) void k_wpack(WArgs a) {
  const WEnt en = a.e[blockIdx.y];
  const int tk = 9 * en.kc32;
  for (int i = blockIdx.x * 256 + threadIdx.x; i < en.total; i += gridDim.x * 256) {
    const int co = i / tk, rem = i - co * tk;
    const int t = rem / en.kc32, ci = rem - t * en.kc32;
    float v = 0.f;
    if (co < en.cout_real && ci < en.cin_real)
      v = en.src[((size_t)co * en.cin_real + ci) * 9 + t];
    en.dst[i] = f2bf(v);
  }
}

// ---------------- 3x3 conv as bf16 MFMA implicit GEMM ----------------------
__global__ __launch_bounds__(256)
void k_conv3m(const ushort* __restrict__ xin, long in_bs, int in_cs, int ih, int iw,
              const ushort* __restrict__ wp, int kchunks, int cout_real,
              float* __restrict__ out, long out_bs, int out_coff,
              int oh, int ow, int pad) {
  __shared__ ushort xt[4 * 130 * 32];
  const int tid = threadIdx.x, b = blockIdx.z;
  const int y0 = blockIdx.x * 2, co0 = blockIdx.y * 64;
  const int wv = tid >> 6, lane = tid & 63;
  const int row_sel = wv >> 1, col0 = (wv & 1) * 64;
  const int q = lane >> 4, n = lane & 15, q8 = q * 8;
  const int kc32 = kchunks * 32;
  const ushort* xb = xin + (size_t)b * in_bs;

  f32x4 acc[4][4];
#pragma unroll
  for (int mt = 0; mt < 4; mt++)
#pragma unroll
    for (int nb = 0; nb < 4; nb++) acc[mt][nb] = (f32x4){0.f, 0.f, 0.f, 0.f};

  for (int cc = 0; cc < kchunks; cc++) {
    __syncthreads();
    for (int i = tid; i < 2080; i += 256) {
      const int qq = i & 3, rc = i >> 2;
      const int r = rc / 130, c = rc - r * 130;
      const int yy = y0 - pad + r, xx = c - pad;
      bh8 v = {0, 0, 0, 0, 0, 0, 0, 0};
      if (yy >= 0 && yy < ih && xx >= 0 && xx < iw)
        v = *(const bh8*)(xb + ((size_t)yy * iw + xx) * in_cs + cc * 32 + qq * 8);
      *(bh8*)&xt[rc * 32 + qq * 8] = v;
    }
    __syncthreads();
#pragma unroll
    for (int t = 0; t < 9; t++) {
      const int dy = t / 3, dx = t - dy * 3;
      bh8 a[4], bb[4];
#pragma unroll
      for (int mt = 0; mt < 4; mt++)
        a[mt] = *(const bh8*)(wp + (size_t)((co0 + mt * 16 + n) * 9 + t) * kc32 + cc * 32 + q8);
#pragma unroll
      for (int nb = 0; nb < 4; nb++)
        bb[nb] = *(const bh8*)&xt[((row_sel + dy) * 130 + col0 + nb * 16 + n + dx) * 32 + q8];
#pragma unroll
      for (int mt = 0; mt < 4; mt++)
#pragma unroll
        for (int nb = 0; nb < 4; nb++)
          acc[mt][nb] = __builtin_amdgcn_mfma_f32_16x16x32_bf16(a[mt], bb[nb], acc[mt][nb], 0, 0, 0);
    }
  }

  const int oy = y0 + row_sel;
  const size_t osp = (size_t)oh * ow;
  float* ob = out + (size_t)b * out_bs + (size_t)out_coff * osp + (size_t)oy * ow;
#pragma unroll
  for (int mt = 0; mt < 4; mt++)
#pragma unroll
    for (int r = 0; r < 4; r++) {
      const int co = co0 + mt * 16 + q * 4 + r;
      if (co < cout_real) {
#pragma unroll
        for (int nb = 0; nb < 4; nb++) {
          const int px = col0 + nb * 16 + n;
          if (px < ow) ob[(size_t)co * osp + px] = acc[mt][nb][r];
        }
      }
    }
}

// ---------------- generic 1x1 conv (4 couts/thread) ------------------------
__global__ __launch_bounds__(256)
void k_conv1x1(const float* __restrict__ in, long in_bs, int cin,
               const float* __restrict__ wts, const float* __restrict__ bias,
               const float* __restrict__ resid, long res_bs,
               float* __restrict__ out, long out_bs, int out_coff) {
  const int n = blockIdx.x * 256 + threadIdx.x;
  const int co0 = blockIdx.y * 4, b = blockIdx.z;
  const float* ip = in + (size_t)b * in_bs + n;
  const float* w = wts + (size_t)co0 * cin;
  float a0 = 0, a1 = 0, a2 = 0, a3 = 0;
  for (int ci = 0; ci < cin; ci++) {
    float xv = ip[(size_t)ci * N];
    a0 += xv * w[ci]; a1 += xv * w[cin + ci];
    a2 += xv * w[2 * cin + ci]; a3 += xv * w[3 * cin + ci];
  }
  float acc[4] = {a0, a1, a2, a3};
#pragma unroll
  for (int o = 0; o < 4; o++) {
    const int co = co0 + o;
    float r = acc[o];
    if (bias) r += bias[co];
    if (resid) r += resid[(size_t)b * res_bs + (size_t)co * N + n];
    out[(size_t)b * out_bs + (size_t)(out_coff + co) * N + n] = r;
  }
}

// ---------------- grouped 3x3 conv (groups=32, 3 in / 3 out per group) -----
__global__ __launch_bounds__(256) void k_dwconv(const float* __restrict__ in,
                                                const float* __restrict__ wts,
                                                float* __restrict__ out) {
  const int n = blockIdx.x * 256 + threadIdx.x;
  const int g = blockIdx.y, b = blockIdx.z;
  const int h0 = n >> 7, w0 = n & 127;
  float acc[3] = {0.f, 0.f, 0.f};
  for (int ci = 0; ci < 3; ci++) {
    const float* ip = in + ((size_t)b * 96 + g * 3 + ci) * N;
#pragma unroll
    for (int ky = 0; ky < 3; ky++) {
      const int iy = h0 - 1 + ky;
      if (iy < 0 || iy >= H) continue;
#pragma unroll
      for (int kx = 0; kx < 3; kx++) {
        const int ix = w0 - 1 + kx;
        if (ix < 0 || ix >= W) continue;
        const float v = ip[(size_t)iy * W + ix];
#pragma unroll
        for (int o = 0; o < 3; o++)
          acc[o] += v * wts[((size_t)(g * 3 + o) * 3 + ci) * 9 + ky * 3 + kx];
      }
    }
  }
#pragma unroll
  for (int o = 0; o < 3; o++)
    out[((size_t)b * 96 + g * 3 + o) * N + n] = acc[o];
}

// ---------------- channel-attn phase 1: partial sums over N chunk ----------
template <int DQ>
__global__ __launch_bounds__(256)
void k_attn_part(const float* __restrict__ q1, long q1_bs,
                 const float* __restrict__ q2, long q2_bs,
                 const float* __restrict__ k, long k_bs,
                 float* __restrict__ partial) {
  const int h = blockIdx.x, b = blockIdx.y, ch = blockIdx.z, tid = threadIdx.x;
  const float* qp[DQ];
#pragma unroll
  for (int d = 0; d < DQ; d++) {
    const int qc = h * DQ + d;
    qp[d] = (qc < 32) ? (q1 + (size_t)b * q1_bs + (size_t)qc * N)
                      : (q2 + (size_t)b * q2_bs + (size_t)(qc - 32) * N);
  }
  const float* kp[4];
#pragma unroll
  for (int e = 0; e < 4; e++) kp[e] = k + (size_t)b * k_bs + (size_t)(h * 4 + e) * N;

  constexpr int NV = DQ + 4 + DQ * 4;
  float ssq[DQ] = {}, ssk[4] = {}, gr[DQ][4] = {};
  const int n1 = (ch + 1) * (N / 8);
  for (int n = ch * (N / 8) + tid; n < n1; n += 256) {
    float qv[DQ], kv[4];
#pragma unroll
    for (int d = 0; d < DQ; d++) { qv[d] = qp[d][n]; ssq[d] += qv[d] * qv[d]; }
#pragma unroll
    for (int e = 0; e < 4; e++) { kv[e] = kp[e][n]; ssk[e] += kv[e] * kv[e]; }
#pragma unroll
    for (int d = 0; d < DQ; d++)
#pragma unroll
      for (int e = 0; e < 4; e++) gr[d][e] += qv[d] * kv[e];
  }
  float vals[NV];
#pragma unroll
  for (int d = 0; d < DQ; d++) vals[d] = ssq[d];
#pragma unroll
  for (int e = 0; e < 4; e++) vals[DQ + e] = ssk[e];
#pragma unroll
  for (int d = 0; d < DQ; d++)
#pragma unroll
    for (int e = 0; e < 4; e++) vals[DQ + 4 + d * 4 + e] = gr[d][e];
#pragma unroll
  for (int j = 0; j < NV; j++) {
    float v = vals[j];
    for (int m = 32; m > 0; m >>= 1) v += __shfl_xor(v, m, 64);
    vals[j] = v;
  }
  __shared__ float red[4][NV];
  const int wid = tid >> 6, lane = tid & 63;
  if (lane == 0)
#pragma unroll
    for (int j = 0; j < NV; j++) red[wid][j] = vals[j];
  __syncthreads();
  if (tid < NV)
    partial[(size_t)(((b * 8 + h) * 8) + ch) * NV + tid] =
        red[0][tid] + red[1][tid] + red[2][tid] + red[3][tid];
}

// ---------------- channel-attn phase 2: reduce + softmax -------------------
template <int DQ>
__global__ __launch_bounds__(128)
void k_attn_soft(const float* __restrict__ partial,
                 const float* __restrict__ temp, float* __restrict__ stats) {
  constexpr int NV = DQ + 4 + DQ * 4;
  const int h = blockIdx.x, b = blockIdx.y, tid = threadIdx.x;
  __shared__ float tot[NV];
  if (tid < NV) {
    float s = 0.f;
#pragma unroll
    for (int ch = 0; ch < 8; ch++)
      s += partial[(size_t)(((b * 8 + h) * 8) + ch) * NV + tid];
    tot[tid] = s;
  }
  __syncthreads();
  if (tid == 0) {
    float invq[DQ], invk[4];
#pragma unroll
    for (int d = 0; d < DQ; d++) invq[d] = 1.f / fmaxf(sqrtf(tot[d]), 1e-12f);
#pragma unroll
    for (int e = 0; e < 4; e++) invk[e] = 1.f / fmaxf(sqrtf(tot[DQ + e]), 1e-12f);
    const float t = temp[h];
    float* sp = stats + (size_t)(b * 8 + h) * DQ * 4;
    for (int d = 0; d < DQ; d++) {
      float s[4], mx = -1e30f;
#pragma unroll
      for (int e = 0; e < 4; e++) {
        s[e] = tot[DQ + 4 + d * 4 + e] * invq[d] * invk[e] * t;
        mx = fmaxf(mx, s[e]);
      }
      float sum = 0.f;
#pragma unroll
      for (int e = 0; e < 4; e++) { s[e] = expf(s[e] - mx); sum += s[e]; }
#pragma unroll
      for (int e = 0; e < 4; e++) sp[d * 4 + e] = s[e] / sum;
    }
  }
}

// ---------------- fused inner attn-apply + mproj + residual ----------------
// attnout[h*4+d] = sum_e A[h][d][e]*vi[h*4+e]; CAT1[64+co] = x[co] + Wm.attnout
__global__ __launch_bounds__(256)
void k_attn_mproj(const float* __restrict__ qkv2, const float* __restrict__ stats,
                  const float* __restrict__ wm, const float* __restrict__ x,
                  float* __restrict__ cat1) {
  __shared__ float als[128], wls[1024];
  const int tid = threadIdx.x, b = blockIdx.y;
  const int n = blockIdx.x * 256 + tid;
  if (tid < 128) als[tid] = stats[(size_t)b * 128 + tid];
  for (int i = tid; i < 1024; i += 256) wls[i] = wm[i];
  __syncthreads();
  const float* vi = qkv2 + (size_t)b * (96L * N) + 64L * N;
  float t[32];
#pragma unroll
  for (int h = 0; h < 8; h++) {
    float vv[4];
#pragma unroll
    for (int e = 0; e < 4; e++) vv[e] = vi[(size_t)(h * 4 + e) * N + n];
#pragma unroll
    for (int d = 0; d < 4; d++) {
      const float* A = &als[h * 16 + d * 4];
      t[h * 4 + d] = A[0] * vv[0] + A[1] * vv[1] + A[2] * vv[2] + A[3] * vv[3];
    }
  }
  for (int co = 0; co < 32; co++) {
    const float* w = &wls[co * 32];
    float r = 0.f;
#pragma unroll
    for (int ci = 0; ci < 32; ci++) r += w[ci] * t[ci];
    r += x[(size_t)(b * 64 + co) * N + n];
    cat1[((size_t)b * 96 + 64 + co) * N + n] = r;
  }
}

// ---------------- fused final attn-apply + po -> d_out ---------------------
__global__ __launch_bounds__(256)
void k_attn_po(const float* __restrict__ cat2, const float* __restrict__ stats,
               const float* __restrict__ wpo, float* __restrict__ outp) {
  __shared__ float als[256], wls[2048];
  const int tid = threadIdx.x, b = blockIdx.y;
  const int n = blockIdx.x * 256 + tid;
  if (tid < 256) als[tid] = stats[(size_t)b * 256 + tid];
  for (int i = tid; i < 2048; i += 256) wls[i] = wpo[i];
  __syncthreads();
  const float* v = cat2 + (size_t)b * (64L * N);
  float t[64];
#pragma unroll
  for (int h = 0; h < 8; h++) {
    float vv[4];
#pragma unroll
    for (int e = 0; e < 4; e++) vv[e] = v[(size_t)(h * 4 + e) * N + n];
#pragma unroll
    for (int d = 0; d < 8; d++) {
      const float* A = &als[h * 32 + d * 4];
      t[h * 8 + d] = A[0] * vv[0] + A[1] * vv[1] + A[2] * vv[2] + A[3] * vv[3];
    }
  }
  for (int co = 0; co < 32; co++) {
    const float* w = &wls[co * 64];
    float r = 0.f;
#pragma unroll
    for (int ci = 0; ci < 64; ci++) r += w[ci] * t[ci];
    outp[(size_t)(b * 32 + co) * N + n] = r;
  }
}

// ---------------- avgpool 2x2 -> NHWC bf16 directly ------------------------
__global__ __launch_bounds__(256) void k_avgpoolb(const float* __restrict__ in,
                                                  ushort* __restrict__ outb) {
  const int opx = blockIdx.x * 256 + threadIdx.x;  // 4096 per b
  const int b = blockIdx.y;
  const int ox = opx & 63, oy = opx >> 6;
  const float* p0 = in + (size_t)b * 64 * N + (size_t)(oy * 2) * W + ox * 2;
  ushort tmp[64];
#pragma unroll
  for (int c = 0; c < 64; c++) {
    const float* p = p0 + (size_t)c * N;
    tmp[c] = f2bf(0.25f * (p[0] + p[1] + p[W] + p[W + 1]));
  }
  ushort* dp = outb + ((size_t)b * 4096 + opx) * 64;
#pragma unroll
  for (int k = 0; k < 8; k++) *(bh8*)(dp + k * 8) = *(const bh8*)&tmp[k * 8];
}

// ---------------- fused T3 * sigmoid(resize(asmall)) -> NHWC bf16 ----------
__global__ __launch_bounds__(256)
void k_sigcast(const float* __restrict__ t3, const float* __restrict__ asmall,
               ushort* __restrict__ t3b) {
  const int n = blockIdx.x * 256 + threadIdx.x;
  const int cy = blockIdx.y, b = blockIdx.z;
  const int x = n & 127, yv = n >> 7;
  const int iy = (yv * 62) >> 7, ix = (x * 62) >> 7;
  ushort tmp[32];
#pragma unroll
  for (int j = 0; j < 32; j++) {
    const int c = cy * 32 + j;
    float v = 0.f;
    if (c < 166) {
      const float a = asmall[((size_t)b * 166 + c) * 3844 + iy * 62 + ix];
      v = t3[((size_t)b * 166 + c) * N + n] * (1.f / (1.f + expf(-a)));
    }
    tmp[j] = f2bf(v);
  }
  ushort* dp = t3b + ((size_t)b * N + n) * 192 + cy * 32;
#pragma unroll
  for (int k = 0; k < 4; k++) *(bh8*)(dp + k * 8) = *(const bh8*)&tmp[k * 8];
}

// ---------------- deformable conv v2: lane=channel, coalesced gathers ------
// block: 256 = 8 px x 32 lanes. Lane c: gathers corner value of channel c
// (coalesced 128B per pixel-corner), computes s_c; quad bpermute gives the
// 4 group-channel s values; lane reinterpreted as cout applies LDS weights.
template <int K>
__global__ __launch_bounds__(256)
void k_deform2(const float* __restrict__ xt, const float* __restrict__ offs, int off_c0,
               const float* __restrict__ wd, const float* __restrict__ bd,
               float* __restrict__ out, int out_c0) {
  constexpr int K2 = K * K, PAD = K / 2;
  __shared__ float wlds[K2 * 128];  // [t][cout(32)][j(4)]
  const int tid = threadIdx.x, b = blockIdx.y;
  for (int i = tid; i < K2 * 128; i += 256) {
    const int t = i >> 7, r = i & 127, o = r >> 2, j = r & 3;
    wlds[i] = wd[(size_t)(o * 4 + j) * K2 + t];
  }
  __syncthreads();
  const int pxl = tid >> 5, c = tid & 31;
  const int px = blockIdx.x * 8 + pxl;
  const int hy = px >> 7, wx = px & 127;
  const float* ob = offs + (size_t)b * (166 * N) + (size_t)off_c0 * N + px;
  const float* xb = xt + (size_t)b * N * 32;
  const int permb = (tid & 32) * 4;      // byte base of this pixel-half's lanes
  const int g4 = (c >> 2) * 4;           // quad base (group of cout c)
  float acc = 0.f;
  float dy = ob[0], dx = ob[(size_t)N];  // tap 0 offsets (prefetched)
  int ky = 0, kx = 0;
  for (int t = 0; t < K2; t++) {
    float ndy = 0.f, ndx = 0.f;
    if (t + 1 < K2) { ndy = ob[(size_t)(2 * t + 2) * N]; ndx = ob[(size_t)(2 * t + 3) * N]; }
    const float py = (float)(hy - PAD + ky) + dy;
    const float pxf = (float)(wx - PAD + kx) + dx;
    const float y0f = floorf(py), x0f = floorf(pxf);
    const float fy = py - y0f, fx = pxf - x0f;
    const int y0 = (int)y0f, x0 = (int)x0f;
    const int y1 = y0 + 1, x1 = x0 + 1;
    float w00 = (1.f - fy) * (1.f - fx), w01 = (1.f - fy) * fx;
    float w10 = fy * (1.f - fx), w11 = fy * fx;
    const bool vy0 = (y0 >= 0) & (y0 < H), vy1 = (y1 >= 0) & (y1 < H);
    const bool vx0 = (x0 >= 0) & (x0 < W), vx1 = (x1 >= 0) & (x1 < W);
    w00 = (vy0 & vx0) ? w00 : 0.f;
    w01 = (vy0 & vx1) ? w01 : 0.f;
    w10 = (vy1 & vx0) ? w10 : 0.f;
    w11 = (vy1 & vx1) ? w11 : 0.f;
    const int cy0 = min(max(y0, 0), H - 1), cy1 = min(max(y1, 0), H - 1);
    const int cx0 = min(max(x0, 0), W - 1), cx1 = min(max(x1, 0), W - 1);
    const float v00 = xb[(size_t)(cy0 * W + cx0) * 32 + c];
    const float v01 = xb[(size_t)(cy0 * W + cx1) * 32 + c];
    const float v10 = xb[(size_t)(cy1 * W + cx0) * 32 + c];
    const float v11 = xb[(size_t)(cy1 * W + cx1) * 32 + c];
    const float s = w00 * v00 + w01 * v01 + w10 * v10 + w11 * v11;
    // quad broadcast: s values of input channels g4..g4+3 of this pixel
    const int si = __float_as_int(s);
    const float s0 = __int_as_float(__builtin_amdgcn_ds_bpermute(permb + (g4 + 0) * 4, si));
    const float s1 = __int_as_float(__builtin_amdgcn_ds_bpermute(permb + (g4 + 1) * 4, si));
    const float s2 = __int_as_float(__builtin_amdgcn_ds_bpermute(permb + (g4 + 2) * 4, si));
    const float s3 = __int_as_float(__builtin_amdgcn_ds_bpermute(permb + (g4 + 3) * 4, si));
    const float4 w4 = *(const float4*)&wlds[t * 128 + c * 4];
    acc += s0 * w4.x + s1 * w4.y + s2 * w4.z + s3 * w4.w;
    dy = ndy; dx = ndx;
    kx++; if (kx == K) { kx = 0; ky++; }
  }
  const float r = fmaxf(acc + bd[c], 0.f);
  out[((size_t)b * 96 + out_c0 + c) * N + px] = r;
}

// ---------------------------------------------------------------------------
extern "C" void kernel_launch(void* const* d_in, const int* in_sizes, int n_in,
                              void* d_out, int out_size, void* d_ws, size_t ws_size,
                              hipStream_t stream) {
  const float* fx       = (const float*)d_in[0];
  const float* fy       = (const float*)d_in[1];
  const float* w_temp   = (const float*)d_in[2];
  const float* w_po     = (const float*)d_in[3];
  const float* w_lp1    = (const float*)d_in[4];
  const float* w_lp2    = (const float*)d_in[5];
  const float* ln_g     = (const float*)d_in[6];
  const float* ln_b     = (const float*)d_in[7];
  const float* w_tempin = (const float*)d_in[8];
  const float* w_qkv    = (const float*)d_in[9];
  const float* w_qkvd   = (const float*)d_in[10];
  const float* w_mproj  = (const float*)d_in[11];
  const float* w_c3     = (const float*)d_in[12];
  const float* w_k2     = (const float*)d_in[13];
  const float* w_k3     = (const float*)d_in[14];
  const float* w_k4     = (const float*)d_in[15];
  const float* w_d3     = (const float*)d_in[16];
  const float* b_d3     = (const float*)d_in[17];
  const float* w_d5     = (const float*)d_in[18];
  const float* b_d5     = (const float*)d_in[19];
  const float* w_d7     = (const float*)d_in[20];
  const float* b_d7     = (const float*)d_in[21];
  const float* w_pw     = (const float*)d_in[22];
  const float* b_pw     = (const float*)d_in[23];
  float* ws = (float*)d_ws;

  // ---- workspace layout (fp32 elements), time-multiplexed regions ----
  size_t off = 0;
  auto buf = [&](size_t nelem) { float* p = ws + off; off += nelem; return p; };
  float* CAT2   = buf(2097152);   // [B,64,N] fp32, whole pass
  float* XT     = buf(1048576);   // [B,N,32] fp32 NHWC (deform gathers)
  float* R1     = buf(1048576);   // XN
  float* R2     = buf(3145728);   // QKV1 -> CAT1 -> T3b(bf16)
  float* R3     = buf(3145728);   // QKV2 -> POOLb + ASMALL
  float* PROMPT = buf(1048576);
  float* R4     = buf(5439488);   // T3, then CAT3+KFEAT
  float* OFFS   = buf(5439488);   // CAT1b(bf16) until k4 writes OFFS
  float* STATS  = buf(32768);
  float* CAT2Bf = buf(524288);    // CAT2b bf16 NHWC [B,N,64]
  float* WPf    = buf(327680);    // packed bf16 weights
  (void)ws_size; (void)out_size; (void)n_in; (void)in_sizes;

  float* XN = R1;
  float* QKV1 = R2;   float* CAT1 = R2;
  float* QKV2 = R3;   float* ASMALL = R3 + 524288;
  float* T3 = R4;     float* CAT3 = R4;   float* KFEAT = R4 + 3145728;
  float* ST_IN = STATS;          // inner attn A: B*8*16 = 256
  float* ST_FI = STATS + 256;    // final attn A: B*8*32 = 512
  float* P_IN  = STATS + 1024;   // partials dq4: 2*8*8*36 = 4608
  float* P_FI  = STATS + 8192;   // partials dq8: 2*8*8*76 = 9728

  ushort* CAT2b = (ushort*)CAT2Bf;   // [B*N][64]
  ushort* POOLb = (ushort*)R3;       // [B*4096][64] (QKV2 dead by then)
  ushort* CAT1b = (ushort*)OFFS;     // [B*N][96] (dead once k4 runs)
  ushort* T3b   = (ushort*)R2;       // [B*N][192] (CAT1 dead by then)

  ushort* WPu = (ushort*)WPf;
  ushort* wp_lp2 = WPu;
  ushort* wp_c3  = wp_lp2 + 18432;
  ushort* wp_k2  = wp_c3 + 55296;
  ushort* wp_k3  = wp_k2 + 110592;
  ushort* wp_k4  = wp_k3 + 110592;

  const long bs64 = 64L * N, bs32 = 32L * N, bs96 = 96L * N, bs166 = 166L * N;

  // 0. pack conv weights to bf16 [co][t][ci]
  WArgs wa;
  wa.e[0] = { w_lp2, wp_lp2, 32, 32, 32, 64 * 9 * 32 };
  wa.e[1] = { w_c3,  wp_c3,  32, 96, 96, 64 * 9 * 96 };
  wa.e[2] = { w_k2,  wp_k2, 166, 64, 64, 192 * 9 * 64 };
  wa.e[3] = { w_k3,  wp_k3, 166, 64, 64, 192 * 9 * 64 };
  wa.e[4] = { w_k4,  wp_k4, 166, 166, 192, 192 * 9 * 192 };
  k_wpack<<<dim3(64, 5), 256, 0, stream>>>(wa);
  // 1. prep CAT2 + XT + CAT2b + fused layernorm -> XN
  k_prep<<<dim3(N / 256, B), 256, 0, stream>>>(fx, fy, ln_g, ln_b, CAT2, XT, CAT2b, XN);
  // 2. qkv 1x1: XN(32) -> QKV1(96)
  k_conv1x1<<<dim3(N / 256, 24, B), 256, 0, stream>>>(
      XN, bs32, 32, w_qkv, nullptr, nullptr, 0, QKV1, bs96, 0);
  // 3. grouped 3x3: QKV1 -> QKV2
  k_dwconv<<<dim3(N / 256, 32, B), 256, 0, stream>>>(QKV1, w_qkvd, QKV2);
  // 4. inner channel attention stats (dq=4), two-phase
  k_attn_part<4><<<dim3(8, B, 8), 256, 0, stream>>>(
      QKV2, bs96, nullptr, 0, QKV2 + bs32, bs96, P_IN);
  k_attn_soft<4><<<dim3(8, B), 128, 0, stream>>>(P_IN, w_tempin, ST_IN);
  // 5. fused apply+mproj+residual -> CAT1 ch 64..95
  k_attn_mproj<<<dim3(N / 256, B), 256, 0, stream>>>(QKV2, ST_IN, w_mproj, CAT2, CAT1);
  // 6. l1 = lp1(x) -> CAT1 ch 0..31
  k_conv1x1<<<dim3(N / 256, 8, B), 256, 0, stream>>>(
      CAT2, bs64, 32, w_lp1, nullptr, nullptr, 0, CAT1, bs96, 0);
  // 7. l2 = lp2 3x3(x via CAT2b) -> CAT1 ch 32..63
  k_conv3m<<<dim3(64, 1, B), 256, 0, stream>>>(
      CAT2b, (long)N * 64, 64, H, W, wp_lp2, 1, 32, CAT1, bs96, 32, H, W, 1);
  // 8. cast CAT1 -> CAT1b (NHWC bf16, 96ch)
  k_castn<<<dim3(64, 3, B), 256, 0, stream>>>(CAT1, CAT1b, N, 96, 96);
  // 9. prompt = c3 3x3(CAT1b)
  k_conv3m<<<dim3(64, 1, B), 256, 0, stream>>>(
      CAT1b, (long)N * 96, 96, H, W, wp_c3, 3, 32, PROMPT, bs32, 0, H, W, 1);
  // 10. avgpool CAT2 -> POOLb (bf16 NHWC direct)
  k_avgpoolb<<<dim3(16, B), 256, 0, stream>>>(CAT2, POOLb);
  // 11. k2 3x3 valid: POOLb -> ASMALL(166, 62x62)
  k_conv3m<<<dim3(31, 3, B), 256, 0, stream>>>(
      POOLb, 4096L * 64, 64, 64, 64, wp_k2, 2, 166, ASMALL, 166L * 3844, 0, 62, 62, 0);
  // 12. k3 3x3: CAT2b -> T3(166)
  k_conv3m<<<dim3(64, 3, B), 256, 0, stream>>>(
      CAT2b, (long)N * 64, 64, H, W, wp_k3, 2, 166, T3, bs166, 0, H, W, 1);
  // 13. fused T3 * sigmoid(resize(ASMALL)) -> T3b (bf16 NHWC, 192-pad)
  k_sigcast<<<dim3(64, 6, B), 256, 0, stream>>>(T3, ASMALL, T3b);
  // 14. k4 3x3: T3b -> OFFS(166)
  k_conv3m<<<dim3(64, 3, B), 256, 0, stream>>>(
      T3b, (long)N * 192, 192, H, W, wp_k4, 6, 166, OFFS, bs166, 0, H, W, 1);
  // 15-17. deformable convs -> CAT3
  k_deform2<3><<<dim3(N / 8, B), 256, 0, stream>>>(XT, OFFS, 0, w_d3, b_d3, CAT3, 0);
  k_deform2<5><<<dim3(N / 8, B), 256, 0, stream>>>(XT, OFFS, 18, w_d5, b_d5, CAT3, 32);
  k_deform2<7><<<dim3(N / 8, B), 256, 0, stream>>>(XT, OFFS, 68, w_d7, b_d7, CAT3, 64);
  // 18. k_feat = pw 1x1(CAT3) + bias
  k_conv1x1<<<dim3(N / 256, 8, B), 256, 0, stream>>>(
      CAT3, bs96, 96, w_pw, b_pw, nullptr, 0, KFEAT, bs32, 0);
  // 19. final channel attention stats (dq=8), two-phase
  k_attn_part<8><<<dim3(8, B, 8), 256, 0, stream>>>(
      CAT2, bs64, PROMPT, bs32, KFEAT, bs32, P_FI);
  k_attn_soft<8><<<dim3(8, B), 128, 0, stream>>>(P_FI, w_temp, ST_FI);
  // 20. fused apply+po -> d_out
  k_attn_po<<<dim3(N / 256, B), 256, 0, stream>>>(CAT2, ST_FI, w_po, (float*)d_out);
}

// Round 7
// 578.865 us; speedup vs baseline: 3.3935x; 1.0839x over previous
//
#include <hip/hip_runtime.h>
#include <hip/hip_bf16.h>

// ---------------------------------------------------------------------------
// MDTA_FOR_VIDEO_Prompted — full-graph HIP implementation.
// B=2, C=32, H=W=128. fp32 in/out; 3x3 convs via bf16 MFMA implicit GEMM.
// R7: deform v3 = phase-A per-(px,tap) bilinear precompute in LDS (kills the
//     32x-duplicated offset math of v2), phase-B quad DPP broadcast (VALU)
//     instead of ds_bpermute. Everything else as R6.
// ---------------------------------------------------------------------------

constexpr int B = 2, C = 32, H = 128, W = 128, N = H * W;

using bh8   = __attribute__((ext_vector_type(8))) short;  // 8 bf16 = 4 VGPRs
using f32x4 = __attribute__((ext_vector_type(4))) float;

__device__ __forceinline__ ushort f2bf(float v) {
  __hip_bfloat16 h = __float2bfloat16(v);
  return *(ushort*)&h;
}

// ---------------- prep: CAT2=[x;y] NCHW fp32, XT = x NHWC fp32,
//                  CAT2b = [x;y] NHWC bf16, XN = layernorm(x) NCHW ----------
__global__ __launch_bounds__(256) void k_prep(const float* __restrict__ x,
                                              const float* __restrict__ y,
                                              const float* __restrict__ ln_g,
                                              const float* __restrict__ ln_b,
                                              float* __restrict__ cat2,
                                              float* __restrict__ xt,
                                              ushort* __restrict__ cat2b,
                                              float* __restrict__ xn) {
  __shared__ float tile[C][257];
  const int b = blockIdx.y, n0 = blockIdx.x * 256, tid = threadIdx.x;
  const int n = n0 + tid;
  for (int c = 0; c < C; c++) {
    float v = x[(size_t)(b * C + c) * N + n];
    tile[c][tid] = v;
    cat2[(size_t)(b * 64 + c) * N + n] = v;
  }
  __syncthreads();
  {
    float s = 0.f, ss = 0.f;
#pragma unroll
    for (int c = 0; c < C; c++) { const float v = tile[c][tid]; s += v; ss += v * v; }
    const float mu = s * (1.f / C);
    const float var = ss * (1.f / C) - mu * mu;
    const float inv = rsqrtf(var + 1e-5f);
#pragma unroll
    for (int c = 0; c < C; c++)
      xn[(size_t)(b * C + c) * N + n] = (tile[c][tid] - mu) * inv * ln_g[c] + ln_b[c];
  }
  for (int i = tid; i < C * 256; i += 256) {
    int c = i & 31, nl = i >> 5;
    const float v = tile[c][nl];
    xt[((size_t)b * N + n0 + nl) * C + c] = v;
    cat2b[((size_t)b * N + n0 + nl) * 64 + c] = f2bf(v);
  }
  __syncthreads();
  for (int c = 0; c < C; c++) {
    float v = y[(size_t)(b * C + c) * N + n];
    tile[c][tid] = v;
    cat2[(size_t)(b * 64 + 32 + c) * N + n] = v;
  }
  __syncthreads();
  for (int i = tid; i < C * 256; i += 256) {
    int c = i & 31, nl = i >> 5;
    cat2b[((size_t)b * N + n0 + nl) * 64 + 32 + c] = f2bf(tile[c][nl]);
  }
}

// ---------------- NCHW fp32 -> NHWC bf16 cast (32-ch chunk per block) ------
__global__ __launch_bounds__(256)
void k_castn(const float* __restrict__ src, ushort* __restrict__ dst,
             int isp, int cin_real, int cin_pad) {
  const int p = blockIdx.x * 256 + threadIdx.x;
  const int ci0 = blockIdx.y * 32, b = blockIdx.z;
  const float* sp = src + (size_t)b * cin_real * isp + p;
  ushort tmp[32];
#pragma unroll
  for (int j = 0; j < 32; j++) {
    const int ci = ci0 + j;
    const float v = (ci < cin_real) ? sp[(size_t)ci * isp] : 0.f;
    tmp[j] = f2bf(v);
  }
  ushort* dp = dst + ((size_t)b * isp + p) * cin_pad + ci0;
#pragma unroll
  for (int k = 0; k < 4; k++) *(bh8*)(dp + k * 8) = *(const bh8*)&tmp[k * 8];
}

// ---------------- weight pack: OIHW fp32 -> [co][t][ci] bf16 (padded) ------
struct WEnt { const float* src; ushort* dst; int cout_real, cin_real, kc32, total; };
struct WArgs { WEnt e[5]; };

__global__ __launch_bounds__(256) void k_wpack(WArgs a) {
  const WEnt en = a.e[blockIdx.y];
  const int tk = 9 * en.kc32;
  for (int i = blockIdx.x * 256 + threadIdx.x; i < en.total; i += gridDim.x * 256) {
    const int co = i / tk, rem = i - co * tk;
    const int t = rem / en.kc32, ci = rem - t * en.kc32;
    float v = 0.f;
    if (co < en.cout_real && ci < en.cin_real)
      v = en.src[((size_t)co * en.cin_real + ci) * 9 + t];
    en.dst[i] = f2bf(v);
  }
}

// ---------------- 3x3 conv as bf16 MFMA implicit GEMM ----------------------
__global__ __launch_bounds__(256)
void k_conv3m(const ushort* __restrict__ xin, long in_bs, int in_cs, int ih, int iw,
              const ushort* __restrict__ wp, int kchunks, int cout_real,
              float* __restrict__ out, long out_bs, int out_coff,
              int oh, int ow, int pad) {
  __shared__ ushort xt[4 * 130 * 32];
  const int tid = threadIdx.x, b = blockIdx.z;
  const int y0 = blockIdx.x * 2, co0 = blockIdx.y * 64;
  const int wv = tid >> 6, lane = tid & 63;
  const int row_sel = wv >> 1, col0 = (wv & 1) * 64;
  const int q = lane >> 4, n = lane & 15, q8 = q * 8;
  const int kc32 = kchunks * 32;
  const ushort* xb = xin + (size_t)b * in_bs;

  f32x4 acc[4][4];
#pragma unroll
  for (int mt = 0; mt < 4; mt++)
#pragma unroll
    for (int nb = 0; nb < 4; nb++) acc[mt][nb] = (f32x4){0.f, 0.f, 0.f, 0.f};

  for (int cc = 0; cc < kchunks; cc++) {
    __syncthreads();
    for (int i = tid; i < 2080; i += 256) {
      const int qq = i & 3, rc = i >> 2;
      const int r = rc / 130, c = rc - r * 130;
      const int yy = y0 - pad + r, xx = c - pad;
      bh8 v = {0, 0, 0, 0, 0, 0, 0, 0};
      if (yy >= 0 && yy < ih && xx >= 0 && xx < iw)
        v = *(const bh8*)(xb + ((size_t)yy * iw + xx) * in_cs + cc * 32 + qq * 8);
      *(bh8*)&xt[rc * 32 + qq * 8] = v;
    }
    __syncthreads();
#pragma unroll
    for (int t = 0; t < 9; t++) {
      const int dy = t / 3, dx = t - dy * 3;
      bh8 a[4], bb[4];
#pragma unroll
      for (int mt = 0; mt < 4; mt++)
        a[mt] = *(const bh8*)(wp + (size_t)((co0 + mt * 16 + n) * 9 + t) * kc32 + cc * 32 + q8);
#pragma unroll
      for (int nb = 0; nb < 4; nb++)
        bb[nb] = *(const bh8*)&xt[((row_sel + dy) * 130 + col0 + nb * 16 + n + dx) * 32 + q8];
#pragma unroll
      for (int mt = 0; mt < 4; mt++)
#pragma unroll
        for (int nb = 0; nb < 4; nb++)
          acc[mt][nb] = __builtin_amdgcn_mfma_f32_16x16x32_bf16(a[mt], bb[nb], acc[mt][nb], 0, 0, 0);
    }
  }

  const int oy = y0 + row_sel;
  const size_t osp = (size_t)oh * ow;
  float* ob = out + (size_t)b * out_bs + (size_t)out_coff * osp + (size_t)oy * ow;
#pragma unroll
  for (int mt = 0; mt < 4; mt++)
#pragma unroll
    for (int r = 0; r < 4; r++) {
      const int co = co0 + mt * 16 + q * 4 + r;
      if (co < cout_real) {
#pragma unroll
        for (int nb = 0; nb < 4; nb++) {
          const int px = col0 + nb * 16 + n;
          if (px < ow) ob[(size_t)co * osp + px] = acc[mt][nb][r];
        }
      }
    }
}

// ---------------- generic 1x1 conv (4 couts/thread) ------------------------
__global__ __launch_bounds__(256)
void k_conv1x1(const float* __restrict__ in, long in_bs, int cin,
               const float* __restrict__ wts, const float* __restrict__ bias,
               const float* __restrict__ resid, long res_bs,
               float* __restrict__ out, long out_bs, int out_coff) {
  const int n = blockIdx.x * 256 + threadIdx.x;
  const int co0 = blockIdx.y * 4, b = blockIdx.z;
  const float* ip = in + (size_t)b * in_bs + n;
  const float* w = wts + (size_t)co0 * cin;
  float a0 = 0, a1 = 0, a2 = 0, a3 = 0;
  for (int ci = 0; ci < cin; ci++) {
    float xv = ip[(size_t)ci * N];
    a0 += xv * w[ci]; a1 += xv * w[cin + ci];
    a2 += xv * w[2 * cin + ci]; a3 += xv * w[3 * cin + ci];
  }
  float acc[4] = {a0, a1, a2, a3};
#pragma unroll
  for (int o = 0; o < 4; o++) {
    const int co = co0 + o;
    float r = acc[o];
    if (bias) r += bias[co];
    if (resid) r += resid[(size_t)b * res_bs + (size_t)co * N + n];
    out[(size_t)b * out_bs + (size_t)(out_coff + co) * N + n] = r;
  }
}

// ---------------- grouped 3x3 conv (groups=32, 3 in / 3 out per group) -----
__global__ __launch_bounds__(256) void k_dwconv(const float* __restrict__ in,
                                                const float* __restrict__ wts,
                                                float* __restrict__ out) {
  const int n = blockIdx.x * 256 + threadIdx.x;
  const int g = blockIdx.y, b = blockIdx.z;
  const int h0 = n >> 7, w0 = n & 127;
  float acc[3] = {0.f, 0.f, 0.f};
  for (int ci = 0; ci < 3; ci++) {
    const float* ip = in + ((size_t)b * 96 + g * 3 + ci) * N;
#pragma unroll
    for (int ky = 0; ky < 3; ky++) {
      const int iy = h0 - 1 + ky;
      if (iy < 0 || iy >= H) continue;
#pragma unroll
      for (int kx = 0; kx < 3; kx++) {
        const int ix = w0 - 1 + kx;
        if (ix < 0 || ix >= W) continue;
        const float v = ip[(size_t)iy * W + ix];
#pragma unroll
        for (int o = 0; o < 3; o++)
          acc[o] += v * wts[((size_t)(g * 3 + o) * 3 + ci) * 9 + ky * 3 + kx];
      }
    }
  }
#pragma unroll
  for (int o = 0; o < 3; o++)
    out[((size_t)b * 96 + g * 3 + o) * N + n] = acc[o];
}

// ---------------- channel-attn phase 1: partial sums over N chunk ----------
template <int DQ>
__global__ __launch_bounds__(256)
void k_attn_part(const float* __restrict__ q1, long q1_bs,
                 const float* __restrict__ q2, long q2_bs,
                 const float* __restrict__ k, long k_bs,
                 float* __restrict__ partial) {
  const int h = blockIdx.x, b = blockIdx.y, ch = blockIdx.z, tid = threadIdx.x;
  const float* qp[DQ];
#pragma unroll
  for (int d = 0; d < DQ; d++) {
    const int qc = h * DQ + d;
    qp[d] = (qc < 32) ? (q1 + (size_t)b * q1_bs + (size_t)qc * N)
                      : (q2 + (size_t)b * q2_bs + (size_t)(qc - 32) * N);
  }
  const float* kp[4];
#pragma unroll
  for (int e = 0; e < 4; e++) kp[e] = k + (size_t)b * k_bs + (size_t)(h * 4 + e) * N;

  constexpr int NV = DQ + 4 + DQ * 4;
  float ssq[DQ] = {}, ssk[4] = {}, gr[DQ][4] = {};
  const int n1 = (ch + 1) * (N / 8);
  for (int n = ch * (N / 8) + tid; n < n1; n += 256) {
    float qv[DQ], kv[4];
#pragma unroll
    for (int d = 0; d < DQ; d++) { qv[d] = qp[d][n]; ssq[d] += qv[d] * qv[d]; }
#pragma unroll
    for (int e = 0; e < 4; e++) { kv[e] = kp[e][n]; ssk[e] += kv[e] * kv[e]; }
#pragma unroll
    for (int d = 0; d < DQ; d++)
#pragma unroll
      for (int e = 0; e < 4; e++) gr[d][e] += qv[d] * kv[e];
  }
  float vals[NV];
#pragma unroll
  for (int d = 0; d < DQ; d++) vals[d] = ssq[d];
#pragma unroll
  for (int e = 0; e < 4; e++) vals[DQ + e] = ssk[e];
#pragma unroll
  for (int d = 0; d < DQ; d++)
#pragma unroll
    for (int e = 0; e < 4; e++) vals[DQ + 4 + d * 4 + e] = gr[d][e];
#pragma unroll
  for (int j = 0; j < NV; j++) {
    float v = vals[j];
    for (int m = 32; m > 0; m >>= 1) v += __shfl_xor(v, m, 64);
    vals[j] = v;
  }
  __shared__ float red[4][NV];
  const int wid = tid >> 6, lane = tid & 63;
  if (lane == 0)
#pragma unroll
    for (int j = 0; j < NV; j++) red[wid][j] = vals[j];
  __syncthreads();
  if (tid < NV)
    partial[(size_t)(((b * 8 + h) * 8) + ch) * NV + tid] =
        red[0][tid] + red[1][tid] + red[2][tid] + red[3][tid];
}

// ---------------- channel-attn phase 2: reduce + softmax -------------------
template <int DQ>
__global__ __launch_bounds__(128)
void k_attn_soft(const float* __restrict__ partial,
                 const float* __restrict__ temp, float* __restrict__ stats) {
  constexpr int NV = DQ + 4 + DQ * 4;
  const int h = blockIdx.x, b = blockIdx.y, tid = threadIdx.x;
  __shared__ float tot[NV];
  if (tid < NV) {
    float s = 0.f;
#pragma unroll
    for (int ch = 0; ch < 8; ch++)
      s += partial[(size_t)(((b * 8 + h) * 8) + ch) * NV + tid];
    tot[tid] = s;
  }
  __syncthreads();
  if (tid == 0) {
    float invq[DQ], invk[4];
#pragma unroll
    for (int d = 0; d < DQ; d++) invq[d] = 1.f / fmaxf(sqrtf(tot[d]), 1e-12f);
#pragma unroll
    for (int e = 0; e < 4; e++) invk[e] = 1.f / fmaxf(sqrtf(tot[DQ + e]), 1e-12f);
    const float t = temp[h];
    float* sp = stats + (size_t)(b * 8 + h) * DQ * 4;
    for (int d = 0; d < DQ; d++) {
      float s[4], mx = -1e30f;
#pragma unroll
      for (int e = 0; e < 4; e++) {
        s[e] = tot[DQ + 4 + d * 4 + e] * invq[d] * invk[e] * t;
        mx = fmaxf(mx, s[e]);
      }
      float sum = 0.f;
#pragma unroll
      for (int e = 0; e < 4; e++) { s[e] = expf(s[e] - mx); sum += s[e]; }
#pragma unroll
      for (int e = 0; e < 4; e++) sp[d * 4 + e] = s[e] / sum;
    }
  }
}

// ---------------- fused inner attn-apply + mproj + residual ----------------
__global__ __launch_bounds__(256)
void k_attn_mproj(const float* __restrict__ qkv2, const float* __restrict__ stats,
                  const float* __restrict__ wm, const float* __restrict__ x,
                  float* __restrict__ cat1) {
  __shared__ float als[128], wls[1024];
  const int tid = threadIdx.x, b = blockIdx.y;
  const int n = blockIdx.x * 256 + tid;
  if (tid < 128) als[tid] = stats[(size_t)b * 128 + tid];
  for (int i = tid; i < 1024; i += 256) wls[i] = wm[i];
  __syncthreads();
  const float* vi = qkv2 + (size_t)b * (96L * N) + 64L * N;
  float t[32];
#pragma unroll
  for (int h = 0; h < 8; h++) {
    float vv[4];
#pragma unroll
    for (int e = 0; e < 4; e++) vv[e] = vi[(size_t)(h * 4 + e) * N + n];
#pragma unroll
    for (int d = 0; d < 4; d++) {
      const float* A = &als[h * 16 + d * 4];
      t[h * 4 + d] = A[0] * vv[0] + A[1] * vv[1] + A[2] * vv[2] + A[3] * vv[3];
    }
  }
  for (int co = 0; co < 32; co++) {
    const float* w = &wls[co * 32];
    float r = 0.f;
#pragma unroll
    for (int ci = 0; ci < 32; ci++) r += w[ci] * t[ci];
    r += x[(size_t)(b * 64 + co) * N + n];
    cat1[((size_t)b * 96 + 64 + co) * N + n] = r;
  }
}

// ---------------- fused final attn-apply + po -> d_out ---------------------
__global__ __launch_bounds__(256)
void k_attn_po(const float* __restrict__ cat2, const float* __restrict__ stats,
               const float* __restrict__ wpo, float* __restrict__ outp) {
  __shared__ float als[256], wls[2048];
  const int tid = threadIdx.x, b = blockIdx.y;
  const int n = blockIdx.x * 256 + tid;
  if (tid < 256) als[tid] = stats[(size_t)b * 256 + tid];
  for (int i = tid; i < 2048; i += 256) wls[i] = wpo[i];
  __syncthreads();
  const float* v = cat2 + (size_t)b * (64L * N);
  float t[64];
#pragma unroll
  for (int h = 0; h < 8; h++) {
    float vv[4];
#pragma unroll
    for (int e = 0; e < 4; e++) vv[e] = v[(size_t)(h * 4 + e) * N + n];
#pragma unroll
    for (int d = 0; d < 8; d++) {
      const float* A = &als[h * 32 + d * 4];
      t[h * 8 + d] = A[0] * vv[0] + A[1] * vv[1] + A[2] * vv[2] + A[3] * vv[3];
    }
  }
  for (int co = 0; co < 32; co++) {
    const float* w = &wls[co * 64];
    float r = 0.f;
#pragma unroll
    for (int ci = 0; ci < 64; ci++) r += w[ci] * t[ci];
    outp[(size_t)(b * 32 + co) * N + n] = r;
  }
}

// ---------------- avgpool 2x2 -> NHWC bf16 directly ------------------------
__global__ __launch_bounds__(256) void k_avgpoolb(const float* __restrict__ in,
                                                  ushort* __restrict__ outb) {
  const int opx = blockIdx.x * 256 + threadIdx.x;  // 4096 per b
  const int b = blockIdx.y;
  const int ox = opx & 63, oy = opx >> 6;
  const float* p0 = in + (size_t)b * 64 * N + (size_t)(oy * 2) * W + ox * 2;
  ushort tmp[64];
#pragma unroll
  for (int c = 0; c < 64; c++) {
    const float* p = p0 + (size_t)c * N;
    tmp[c] = f2bf(0.25f * (p[0] + p[1] + p[W] + p[W + 1]));
  }
  ushort* dp = outb + ((size_t)b * 4096 + opx) * 64;
#pragma unroll
  for (int k = 0; k < 8; k++) *(bh8*)(dp + k * 8) = *(const bh8*)&tmp[k * 8];
}

// ---------------- fused T3 * sigmoid(resize(asmall)) -> NHWC bf16 ----------
__global__ __launch_bounds__(256)
void k_sigcast(const float* __restrict__ t3, const float* __restrict__ asmall,
               ushort* __restrict__ t3b) {
  const int n = blockIdx.x * 256 + threadIdx.x;
  const int cy = blockIdx.y, b = blockIdx.z;
  const int x = n & 127, yv = n >> 7;
  const int iy = (yv * 62) >> 7, ix = (x * 62) >> 7;
  ushort tmp[32];
#pragma unroll
  for (int j = 0; j < 32; j++) {
    const int c = cy * 32 + j;
    float v = 0.f;
    if (c < 166) {
      const float a = asmall[((size_t)b * 166 + c) * 3844 + iy * 62 + ix];
      v = t3[((size_t)b * 166 + c) * N + n] * (1.f / (1.f + expf(-a)));
    }
    tmp[j] = f2bf(v);
  }
  ushort* dp = t3b + ((size_t)b * N + n) * 192 + cy * 32;
#pragma unroll
  for (int k = 0; k < 4; k++) *(bh8*)(dp + k * 8) = *(const bh8*)&tmp[k * 8];
}

// ---------------- deformable conv v3 ---------------------------------------
// Phase A: per-(pixel,tap) bilinear weights + clamped addrs -> LDS (once).
// Phase B: lane=channel; 4 coalesced gathers + 4 FMA; quad DPP broadcast
//          (channels g*4..g*4+3 ARE lane c's quad) + 4 FMA contraction.
template <int K>
__global__ __launch_bounds__(256)
void k_deform3(const float* __restrict__ xt, const float* __restrict__ offs, int off_c0,
               const float* __restrict__ wd, const float* __restrict__ bd,
               float* __restrict__ out, int out_c0) {
  constexpr int K2 = K * K, PAD = K / 2;
  __shared__ float wlds[K2 * 128];   // [t][cout(32)][j(4)]
  __shared__ float wbl[8][K2][4];    // bilinear weights per (px,tap)
  __shared__ int   abl[8][K2][4];    // clamped flat addrs (elements/32) per (px,tap)
  const int tid = threadIdx.x, b = blockIdx.y;
  const int px0 = blockIdx.x * 8;
  for (int i = tid; i < K2 * 128; i += 256) {
    const int t = i >> 7, r = i & 127, o = r >> 2, j = r & 3;
    wlds[i] = wd[(size_t)(o * 4 + j) * K2 + t];
  }
  // phase A
  const float* obb = offs + (size_t)b * (166 * N) + (size_t)off_c0 * N;
  for (int i = tid; i < 8 * K2; i += 256) {
    const int p = i / K2, t = i - p * K2;
    const int px = px0 + p;
    const int hy = px >> 7, wx = px & 127;
    const int ky = t / K, kx = t - ky * K;
    const float dy = obb[(size_t)(2 * t) * N + px];
    const float dx = obb[(size_t)(2 * t + 1) * N + px];
    const float py = (float)(hy - PAD + ky) + dy;
    const float pxf = (float)(wx - PAD + kx) + dx;
    const float y0f = floorf(py), x0f = floorf(pxf);
    const float fy = py - y0f, fx = pxf - x0f;
    const int y0 = (int)y0f, x0 = (int)x0f;
    const int y1 = y0 + 1, x1 = x0 + 1;
    float w00 = (1.f - fy) * (1.f - fx), w01 = (1.f - fy) * fx;
    float w10 = fy * (1.f - fx), w11 = fy * fx;
    const bool vy0 = (y0 >= 0) & (y0 < H), vy1 = (y1 >= 0) & (y1 < H);
    const bool vx0 = (x0 >= 0) & (x0 < W), vx1 = (x1 >= 0) & (x1 < W);
    w00 = (vy0 & vx0) ? w00 : 0.f;
    w01 = (vy0 & vx1) ? w01 : 0.f;
    w10 = (vy1 & vx0) ? w10 : 0.f;
    w11 = (vy1 & vx1) ? w11 : 0.f;
    const int cy0 = min(max(y0, 0), H - 1), cy1 = min(max(y1, 0), H - 1);
    const int cx0 = min(max(x0, 0), W - 1), cx1 = min(max(x1, 0), W - 1);
    wbl[p][t][0] = w00; wbl[p][t][1] = w01; wbl[p][t][2] = w10; wbl[p][t][3] = w11;
    abl[p][t][0] = (cy0 * W + cx0) * 32;
    abl[p][t][1] = (cy0 * W + cx1) * 32;
    abl[p][t][2] = (cy1 * W + cx0) * 32;
    abl[p][t][3] = (cy1 * W + cx1) * 32;
  }
  __syncthreads();
  // phase B
  const int pxl = tid >> 5, c = tid & 31;
  const int px = px0 + pxl;
  const float* xb = xt + (size_t)b * N * 32 + c;
  float acc = 0.f;
  for (int t = 0; t < K2; t++) {
    const float4 w4 = *(const float4*)&wbl[pxl][t][0];
    const int4 a4 = *(const int4*)&abl[pxl][t][0];
    const float v00 = xb[a4.x], v01 = xb[a4.y], v10 = xb[a4.z], v11 = xb[a4.w];
    const float s = w4.x * v00 + w4.y * v01 + w4.z * v10 + w4.w * v11;
    const int si = __float_as_int(s);
    // quad broadcast: lane c's quad holds channels (c&~3)..(c|3) == group cins
    const float s0 = __int_as_float(__builtin_amdgcn_mov_dpp(si, 0x00, 0xf, 0xf, false));
    const float s1 = __int_as_float(__builtin_amdgcn_mov_dpp(si, 0x55, 0xf, 0xf, false));
    const float s2 = __int_as_float(__builtin_amdgcn_mov_dpp(si, 0xAA, 0xf, 0xf, false));
    const float s3 = __int_as_float(__builtin_amdgcn_mov_dpp(si, 0xFF, 0xf, 0xf, false));
    const float4 wc = *(const float4*)&wlds[t * 128 + c * 4];
    acc += s0 * wc.x + s1 * wc.y + s2 * wc.z + s3 * wc.w;
  }
  const float r = fmaxf(acc + bd[c], 0.f);
  out[((size_t)b * 96 + out_c0 + c) * N + px] = r;
}

// ---------------------------------------------------------------------------
extern "C" void kernel_launch(void* const* d_in, const int* in_sizes, int n_in,
                              void* d_out, int out_size, void* d_ws, size_t ws_size,
                              hipStream_t stream) {
  const float* fx       = (const float*)d_in[0];
  const float* fy       = (const float*)d_in[1];
  const float* w_temp   = (const float*)d_in[2];
  const float* w_po     = (const float*)d_in[3];
  const float* w_lp1    = (const float*)d_in[4];
  const float* w_lp2    = (const float*)d_in[5];
  const float* ln_g     = (const float*)d_in[6];
  const float* ln_b     = (const float*)d_in[7];
  const float* w_tempin = (const float*)d_in[8];
  const float* w_qkv    = (const float*)d_in[9];
  const float* w_qkvd   = (const float*)d_in[10];
  const float* w_mproj  = (const float*)d_in[11];
  const float* w_c3     = (const float*)d_in[12];
  const float* w_k2     = (const float*)d_in[13];
  const float* w_k3     = (const float*)d_in[14];
  const float* w_k4     = (const float*)d_in[15];
  const float* w_d3     = (const float*)d_in[16];
  const float* b_d3     = (const float*)d_in[17];
  const float* w_d5     = (const float*)d_in[18];
  const float* b_d5     = (const float*)d_in[19];
  const float* w_d7     = (const float*)d_in[20];
  const float* b_d7     = (const float*)d_in[21];
  const float* w_pw     = (const float*)d_in[22];
  const float* b_pw     = (const float*)d_in[23];
  float* ws = (float*)d_ws;

  size_t off = 0;
  auto buf = [&](size_t nelem) { float* p = ws + off; off += nelem; return p; };
  float* CAT2   = buf(2097152);
  float* XT     = buf(1048576);
  float* R1     = buf(1048576);
  float* R2     = buf(3145728);
  float* R3     = buf(3145728);
  float* PROMPT = buf(1048576);
  float* R4     = buf(5439488);
  float* OFFS   = buf(5439488);
  float* STATS  = buf(32768);
  float* CAT2Bf = buf(524288);
  float* WPf    = buf(327680);
  (void)ws_size; (void)out_size; (void)n_in; (void)in_sizes;

  float* XN = R1;
  float* QKV1 = R2;   float* CAT1 = R2;
  float* QKV2 = R3;   float* ASMALL = R3 + 524288;
  float* T3 = R4;     float* CAT3 = R4;   float* KFEAT = R4 + 3145728;
  float* ST_IN = STATS;
  float* ST_FI = STATS + 256;
  float* P_IN  = STATS + 1024;
  float* P_FI  = STATS + 8192;

  ushort* CAT2b = (ushort*)CAT2Bf;
  ushort* POOLb = (ushort*)R3;
  ushort* CAT1b = (ushort*)OFFS;
  ushort* T3b   = (ushort*)R2;

  ushort* WPu = (ushort*)WPf;
  ushort* wp_lp2 = WPu;
  ushort* wp_c3  = wp_lp2 + 18432;
  ushort* wp_k2  = wp_c3 + 55296;
  ushort* wp_k3  = wp_k2 + 110592;
  ushort* wp_k4  = wp_k3 + 110592;

  const long bs64 = 64L * N, bs32 = 32L * N, bs96 = 96L * N, bs166 = 166L * N;

  WArgs wa;
  wa.e[0] = { w_lp2, wp_lp2, 32, 32, 32, 64 * 9 * 32 };
  wa.e[1] = { w_c3,  wp_c3,  32, 96, 96, 64 * 9 * 96 };
  wa.e[2] = { w_k2,  wp_k2, 166, 64, 64, 192 * 9 * 64 };
  wa.e[3] = { w_k3,  wp_k3, 166, 64, 64, 192 * 9 * 64 };
  wa.e[4] = { w_k4,  wp_k4, 166, 166, 192, 192 * 9 * 192 };
  k_wpack<<<dim3(64, 5), 256, 0, stream>>>(wa);
  k_prep<<<dim3(N / 256, B), 256, 0, stream>>>(fx, fy, ln_g, ln_b, CAT2, XT, CAT2b, XN);
  k_conv1x1<<<dim3(N / 256, 24, B), 256, 0, stream>>>(
      XN, bs32, 32, w_qkv, nullptr, nullptr, 0, QKV1, bs96, 0);
  k_dwconv<<<dim3(N / 256, 32, B), 256, 0, stream>>>(QKV1, w_qkvd, QKV2);
  k_attn_part<4><<<dim3(8, B, 8), 256, 0, stream>>>(
      QKV2, bs96, nullptr, 0, QKV2 + bs32, bs96, P_IN);
  k_attn_soft<4><<<dim3(8, B), 128, 0, stream>>>(P_IN, w_tempin, ST_IN);
  k_attn_mproj<<<dim3(N / 256, B), 256, 0, stream>>>(QKV2, ST_IN, w_mproj, CAT2, CAT1);
  k_conv1x1<<<dim3(N / 256, 8, B), 256, 0, stream>>>(
      CAT2, bs64, 32, w_lp1, nullptr, nullptr, 0, CAT1, bs96, 0);
  k_conv3m<<<dim3(64, 1, B), 256, 0, stream>>>(
      CAT2b, (long)N * 64, 64, H, W, wp_lp2, 1, 32, CAT1, bs96, 32, H, W, 1);
  k_castn<<<dim3(64, 3, B), 256, 0, stream>>>(CAT1, CAT1b, N, 96, 96);
  k_conv3m<<<dim3(64, 1, B), 256, 0, stream>>>(
      CAT1b, (long)N * 96, 96, H, W, wp_c3, 3, 32, PROMPT, bs32, 0, H, W, 1);
  k_avgpoolb<<<dim3(16, B), 256, 0, stream>>>(CAT2, POOLb);
  k_conv3m<<<dim3(31, 3, B), 256, 0, stream>>>(
      POOLb, 4096L * 64, 64, 64, 64, wp_k2, 2, 166, ASMALL, 166L * 3844, 0, 62, 62, 0);
  k_conv3m<<<dim3(64, 3, B), 256, 0, stream>>>(
      CAT2b, (long)N * 64, 64, H, W, wp_k3, 2, 166, T3, bs166, 0, H, W, 1);
  k_sigcast<<<dim3(64, 6, B), 256, 0, stream>>>(T3, ASMALL, T3b);
  k_conv3m<<<dim3(64, 3, B), 256, 0, stream>>>(
      T3b, (long)N * 192, 192, H, W, wp_k4, 6, 166, OFFS, bs166, 0, H, W, 1);
  k_deform3<3><<<dim3(N / 8, B), 256, 0, stream>>>(XT, OFFS, 0, w_d3, b_d3, CAT3, 0);
  k_deform3<5><<<dim3(N / 8, B), 256, 0, stream>>>(XT, OFFS, 18, w_d5, b_d5, CAT3, 32);
  k_deform3<7><<<dim3(N / 8, B), 256, 0, stream>>>(XT, OFFS, 68, w_d7, b_d7, CAT3, 64);
  k_conv1x1<<<dim3(N / 256, 8, B), 256, 0, stream>>>(
      CAT3, bs96, 96, w_pw, b_pw, nullptr, 0, KFEAT, bs32, 0);
  k_attn_part<8><<<dim3(8, B, 8), 256, 0, stream>>>(
      CAT2, bs64, PROMPT, bs32, KFEAT, bs32, P_FI);
  k_attn_soft<8><<<dim3(8, B), 128, 0, stream>>>(P_FI, w_temp, ST_FI);
  k_attn_po<<<dim3(N / 256, B), 256, 0, stream>>>(CAT2, ST_FI, w_po, (float*)d_out);
}

// Round 8
// 564.324 us; speedup vs baseline: 3.4809x; 1.0258x over previous
//
#include <hip/hip_runtime.h>
#include <hip/hip_bf16.h>

// ---------------------------------------------------------------------------
// MDTA_FOR_VIDEO_Prompted — full-graph HIP implementation.
// B=2, C=32, H=W=128. fp32 in/out; 3x3 convs via bf16 MFMA implicit GEMM.
// R8: deform v4 = bf16 gather source XTb (x row = 64B -> x0/x1 corners share
//     one cache line), 2 px/thread for 2x gather ILP. Rest as R7.
// ---------------------------------------------------------------------------

constexpr int B = 2, C = 32, H = 128, W = 128, N = H * W;

using bh8   = __attribute__((ext_vector_type(8))) short;  // 8 bf16 = 4 VGPRs
using f32x4 = __attribute__((ext_vector_type(4))) float;

__device__ __forceinline__ ushort f2bf(float v) {
  __hip_bfloat16 h = __float2bfloat16(v);
  return *(ushort*)&h;
}
__device__ __forceinline__ float bf2f(ushort u) {
  union { unsigned int i; float f; } w; w.i = ((unsigned int)u) << 16; return w.f;
}

// ---------------- prep: CAT2=[x;y] NCHW fp32, XTb = x NHWC bf16,
//                  CAT2b = [x;y] NHWC bf16, XN = layernorm(x) NCHW ----------
__global__ __launch_bounds__(256) void k_prep(const float* __restrict__ x,
                                              const float* __restrict__ y,
                                              const float* __restrict__ ln_g,
                                              const float* __restrict__ ln_b,
                                              float* __restrict__ cat2,
                                              ushort* __restrict__ xtb,
                                              ushort* __restrict__ cat2b,
                                              float* __restrict__ xn) {
  __shared__ float tile[C][257];
  const int b = blockIdx.y, n0 = blockIdx.x * 256, tid = threadIdx.x;
  const int n = n0 + tid;
  for (int c = 0; c < C; c++) {
    float v = x[(size_t)(b * C + c) * N + n];
    tile[c][tid] = v;
    cat2[(size_t)(b * 64 + c) * N + n] = v;
  }
  __syncthreads();
  {
    float s = 0.f, ss = 0.f;
#pragma unroll
    for (int c = 0; c < C; c++) { const float v = tile[c][tid]; s += v; ss += v * v; }
    const float mu = s * (1.f / C);
    const float var = ss * (1.f / C) - mu * mu;
    const float inv = rsqrtf(var + 1e-5f);
#pragma unroll
    for (int c = 0; c < C; c++)
      xn[(size_t)(b * C + c) * N + n] = (tile[c][tid] - mu) * inv * ln_g[c] + ln_b[c];
  }
  for (int i = tid; i < C * 256; i += 256) {
    int c = i & 31, nl = i >> 5;
    const ushort bv = f2bf(tile[c][nl]);
    xtb[((size_t)b * N + n0 + nl) * 32 + c] = bv;
    cat2b[((size_t)b * N + n0 + nl) * 64 + c] = bv;
  }
  __syncthreads();
  for (int c = 0; c < C; c++) {
    float v = y[(size_t)(b * C + c) * N + n];
    tile[c][tid] = v;
    cat2[(size_t)(b * 64 + 32 + c) * N + n] = v;
  }
  __syncthreads();
  for (int i = tid; i < C * 256; i += 256) {
    int c = i & 31, nl = i >> 5;
    cat2b[((size_t)b * N + n0 + nl) * 64 + 32 + c] = f2bf(tile[c][nl]);
  }
}

// ---------------- NCHW fp32 -> NHWC bf16 cast (32-ch chunk per block) ------
__global__ __launch_bounds__(256)
void k_castn(const float* __restrict__ src, ushort* __restrict__ dst,
             int isp, int cin_real, int cin_pad) {
  const int p = blockIdx.x * 256 + threadIdx.x;
  const int ci0 = blockIdx.y * 32, b = blockIdx.z;
  const float* sp = src + (size_t)b * cin_real * isp + p;
  ushort tmp[32];
#pragma unroll
  for (int j = 0; j < 32; j++) {
    const int ci = ci0 + j;
    const float v = (ci < cin_real) ? sp[(size_t)ci * isp] : 0.f;
    tmp[j] = f2bf(v);
  }
  ushort* dp = dst + ((size_t)b * isp + p) * cin_pad + ci0;
#pragma unroll
  for (int k = 0; k < 4; k++) *(bh8*)(dp + k * 8) = *(const bh8*)&tmp[k * 8];
}

// ---------------- weight pack: OIHW fp32 -> [co][t][ci] bf16 (padded) ------
struct WEnt { const float* src; ushort* dst; int cout_real, cin_real, kc32, total; };
struct WArgs { WEnt e[5]; };

__global__ __launch_bounds__(256) void k_wpack(WArgs a) {
  const WEnt en = a.e[blockIdx.y];
  const int tk = 9 * en.kc32;
  for (int i = blockIdx.x * 256 + threadIdx.x; i < en.total; i += gridDim.x * 256) {
    const int co = i / tk, rem = i - co * tk;
    const int t = rem / en.kc32, ci = rem - t * en.kc32;
    float v = 0.f;
    if (co < en.cout_real && ci < en.cin_real)
      v = en.src[((size_t)co * en.cin_real + ci) * 9 + t];
    en.dst[i] = f2bf(v);
  }
}

// ---------------- 3x3 conv as bf16 MFMA implicit GEMM ----------------------
__global__ __launch_bounds__(256)
void k_conv3m(const ushort* __restrict__ xin, long in_bs, int in_cs, int ih, int iw,
              const ushort* __restrict__ wp, int kchunks, int cout_real,
              float* __restrict__ out, long out_bs, int out_coff,
              int oh, int ow, int pad) {
  __shared__ ushort xt[4 * 130 * 32];
  const int tid = threadIdx.x, b = blockIdx.z;
  const int y0 = blockIdx.x * 2, co0 = blockIdx.y * 64;
  const int wv = tid >> 6, lane = tid & 63;
  const int row_sel = wv >> 1, col0 = (wv & 1) * 64;
  const int q = lane >> 4, n = lane & 15, q8 = q * 8;
  const int kc32 = kchunks * 32;
  const ushort* xb = xin + (size_t)b * in_bs;

  f32x4 acc[4][4];
#pragma unroll
  for (int mt = 0; mt < 4; mt++)
#pragma unroll
    for (int nb = 0; nb < 4; nb++) acc[mt][nb] = (f32x4){0.f, 0.f, 0.f, 0.f};

  for (int cc = 0; cc < kchunks; cc++) {
    __syncthreads();
    for (int i = tid; i < 2080; i += 256) {
      const int qq = i & 3, rc = i >> 2;
      const int r = rc / 130, c = rc - r * 130;
      const int yy = y0 - pad + r, xx = c - pad;
      bh8 v = {0, 0, 0, 0, 0, 0, 0, 0};
      if (yy >= 0 && yy < ih && xx >= 0 && xx < iw)
        v = *(const bh8*)(xb + ((size_t)yy * iw + xx) * in_cs + cc * 32 + qq * 8);
      *(bh8*)&xt[rc * 32 + qq * 8] = v;
    }
    __syncthreads();
#pragma unroll
    for (int t = 0; t < 9; t++) {
      const int dy = t / 3, dx = t - dy * 3;
      bh8 a[4], bb[4];
#pragma unroll
      for (int mt = 0; mt < 4; mt++)
        a[mt] = *(const bh8*)(wp + (size_t)((co0 + mt * 16 + n) * 9 + t) * kc32 + cc * 32 + q8);
#pragma unroll
      for (int nb = 0; nb < 4; nb++)
        bb[nb] = *(const bh8*)&xt[((row_sel + dy) * 130 + col0 + nb * 16 + n + dx) * 32 + q8];
#pragma unroll
      for (int mt = 0; mt < 4; mt++)
#pragma unroll
        for (int nb = 0; nb < 4; nb++)
          acc[mt][nb] = __builtin_amdgcn_mfma_f32_16x16x32_bf16(a[mt], bb[nb], acc[mt][nb], 0, 0, 0);
    }
  }

  const int oy = y0 + row_sel;
  const size_t osp = (size_t)oh * ow;
  float* ob = out + (size_t)b * out_bs + (size_t)out_coff * osp + (size_t)oy * ow;
#pragma unroll
  for (int mt = 0; mt < 4; mt++)
#pragma unroll
    for (int r = 0; r < 4; r++) {
      const int co = co0 + mt * 16 + q * 4 + r;
      if (co < cout_real) {
#pragma unroll
        for (int nb = 0; nb < 4; nb++) {
          const int px = col0 + nb * 16 + n;
          if (px < ow) ob[(size_t)co * osp + px] = acc[mt][nb][r];
        }
      }
    }
}

// ---------------- generic 1x1 conv (4 couts/thread) ------------------------
__global__ __launch_bounds__(256)
void k_conv1x1(const float* __restrict__ in, long in_bs, int cin,
               const float* __restrict__ wts, const float* __restrict__ bias,
               const float* __restrict__ resid, long res_bs,
               float* __restrict__ out, long out_bs, int out_coff) {
  const int n = blockIdx.x * 256 + threadIdx.x;
  const int co0 = blockIdx.y * 4, b = blockIdx.z;
  const float* ip = in + (size_t)b * in_bs + n;
  const float* w = wts + (size_t)co0 * cin;
  float a0 = 0, a1 = 0, a2 = 0, a3 = 0;
  for (int ci = 0; ci < cin; ci++) {
    float xv = ip[(size_t)ci * N];
    a0 += xv * w[ci]; a1 += xv * w[cin + ci];
    a2 += xv * w[2 * cin + ci]; a3 += xv * w[3 * cin + ci];
  }
  float acc[4] = {a0, a1, a2, a3};
#pragma unroll
  for (int o = 0; o < 4; o++) {
    const int co = co0 + o;
    float r = acc[o];
    if (bias) r += bias[co];
    if (resid) r += resid[(size_t)b * res_bs + (size_t)co * N + n];
    out[(size_t)b * out_bs + (size_t)(out_coff + co) * N + n] = r;
  }
}

// ---------------- grouped 3x3 conv (groups=32, 3 in / 3 out per group) -----
__global__ __launch_bounds__(256) void k_dwconv(const float* __restrict__ in,
                                                const float* __restrict__ wts,
                                                float* __restrict__ out) {
  const int n = blockIdx.x * 256 + threadIdx.x;
  const int g = blockIdx.y, b = blockIdx.z;
  const int h0 = n >> 7, w0 = n & 127;
  float acc[3] = {0.f, 0.f, 0.f};
  for (int ci = 0; ci < 3; ci++) {
    const float* ip = in + ((size_t)b * 96 + g * 3 + ci) * N;
#pragma unroll
    for (int ky = 0; ky < 3; ky++) {
      const int iy = h0 - 1 + ky;
      if (iy < 0 || iy >= H) continue;
#pragma unroll
      for (int kx = 0; kx < 3; kx++) {
        const int ix = w0 - 1 + kx;
        if (ix < 0 || ix >= W) continue;
        const float v = ip[(size_t)iy * W + ix];
#pragma unroll
        for (int o = 0; o < 3; o++)
          acc[o] += v * wts[((size_t)(g * 3 + o) * 3 + ci) * 9 + ky * 3 + kx];
      }
    }
  }
#pragma unroll
  for (int o = 0; o < 3; o++)
    out[((size_t)b * 96 + g * 3 + o) * N + n] = acc[o];
}

// ---------------- channel-attn phase 1: partial sums over N chunk ----------
template <int DQ>
__global__ __launch_bounds__(256)
void k_attn_part(const float* __restrict__ q1, long q1_bs,
                 const float* __restrict__ q2, long q2_bs,
                 const float* __restrict__ k, long k_bs,
                 float* __restrict__ partial) {
  const int h = blockIdx.x, b = blockIdx.y, ch = blockIdx.z, tid = threadIdx.x;
  const float* qp[DQ];
#pragma unroll
  for (int d = 0; d < DQ; d++) {
    const int qc = h * DQ + d;
    qp[d] = (qc < 32) ? (q1 + (size_t)b * q1_bs + (size_t)qc * N)
                      : (q2 + (size_t)b * q2_bs + (size_t)(qc - 32) * N);
  }
  const float* kp[4];
#pragma unroll
  for (int e = 0; e < 4; e++) kp[e] = k + (size_t)b * k_bs + (size_t)(h * 4 + e) * N;

  constexpr int NV = DQ + 4 + DQ * 4;
  float ssq[DQ] = {}, ssk[4] = {}, gr[DQ][4] = {};
  const int n1 = (ch + 1) * (N / 8);
  for (int n = ch * (N / 8) + tid; n < n1; n += 256) {
    float qv[DQ], kv[4];
#pragma unroll
    for (int d = 0; d < DQ; d++) { qv[d] = qp[d][n]; ssq[d] += qv[d] * qv[d]; }
#pragma unroll
    for (int e = 0; e < 4; e++) { kv[e] = kp[e][n]; ssk[e] += kv[e] * kv[e]; }
#pragma unroll
    for (int d = 0; d < DQ; d++)
#pragma unroll
      for (int e = 0; e < 4; e++) gr[d][e] += qv[d] * kv[e];
  }
  float vals[NV];
#pragma unroll
  for (int d = 0; d < DQ; d++) vals[d] = ssq[d];
#pragma unroll
  for (int e = 0; e < 4; e++) vals[DQ + e] = ssk[e];
#pragma unroll
  for (int d = 0; d < DQ; d++)
#pragma unroll
    for (int e = 0; e < 4; e++) vals[DQ + 4 + d * 4 + e] = gr[d][e];
#pragma unroll
  for (int j = 0; j < NV; j++) {
    float v = vals[j];
    for (int m = 32; m > 0; m >>= 1) v += __shfl_xor(v, m, 64);
    vals[j] = v;
  }
  __shared__ float red[4][NV];
  const int wid = tid >> 6, lane = tid & 63;
  if (lane == 0)
#pragma unroll
    for (int j = 0; j < NV; j++) red[wid][j] = vals[j];
  __syncthreads();
  if (tid < NV)
    partial[(size_t)(((b * 8 + h) * 8) + ch) * NV + tid] =
        red[0][tid] + red[1][tid] + red[2][tid] + red[3][tid];
}

// ---------------- channel-attn phase 2: reduce + softmax -------------------
template <int DQ>
__global__ __launch_bounds__(128)
void k_attn_soft(const float* __restrict__ partial,
                 const float* __restrict__ temp, float* __restrict__ stats) {
  constexpr int NV = DQ + 4 + DQ * 4;
  const int h = blockIdx.x, b = blockIdx.y, tid = threadIdx.x;
  __shared__ float tot[NV];
  if (tid < NV) {
    float s = 0.f;
#pragma unroll
    for (int ch = 0; ch < 8; ch++)
      s += partial[(size_t)(((b * 8 + h) * 8) + ch) * NV + tid];
    tot[tid] = s;
  }
  __syncthreads();
  if (tid == 0) {
    float invq[DQ], invk[4];
#pragma unroll
    for (int d = 0; d < DQ; d++) invq[d] = 1.f / fmaxf(sqrtf(tot[d]), 1e-12f);
#pragma unroll
    for (int e = 0; e < 4; e++) invk[e] = 1.f / fmaxf(sqrtf(tot[DQ + e]), 1e-12f);
    const float t = temp[h];
    float* sp = stats + (size_t)(b * 8 + h) * DQ * 4;
    for (int d = 0; d < DQ; d++) {
      float s[4], mx = -1e30f;
#pragma unroll
      for (int e = 0; e < 4; e++) {
        s[e] = tot[DQ + 4 + d * 4 + e] * invq[d] * invk[e] * t;
        mx = fmaxf(mx, s[e]);
      }
      float sum = 0.f;
#pragma unroll
      for (int e = 0; e < 4; e++) { s[e] = expf(s[e] - mx); sum += s[e]; }
#pragma unroll
      for (int e = 0; e < 4; e++) sp[d * 4 + e] = s[e] / sum;
    }
  }
}

// ---------------- fused inner attn-apply + mproj + residual ----------------
__global__ __launch_bounds__(256)
void k_attn_mproj(const float* __restrict__ qkv2, const float* __restrict__ stats,
                  const float* __restrict__ wm, const float* __restrict__ x,
                  float* __restrict__ cat1) {
  __shared__ float als[128], wls[1024];
  const int tid = threadIdx.x, b = blockIdx.y;
  const int n = blockIdx.x * 256 + tid;
  if (tid < 128) als[tid] = stats[(size_t)b * 128 + tid];
  for (int i = tid; i < 1024; i += 256) wls[i] = wm[i];
  __syncthreads();
  const float* vi = qkv2 + (size_t)b * (96L * N) + 64L * N;
  float t[32];
#pragma unroll
  for (int h = 0; h < 8; h++) {
    float vv[4];
#pragma unroll
    for (int e = 0; e < 4; e++) vv[e] = vi[(size_t)(h * 4 + e) * N + n];
#pragma unroll
    for (int d = 0; d < 4; d++) {
      const float* A = &als[h * 16 + d * 4];
      t[h * 4 + d] = A[0] * vv[0] + A[1] * vv[1] + A[2] * vv[2] + A[3] * vv[3];
    }
  }
  for (int co = 0; co < 32; co++) {
    const float* w = &wls[co * 32];
    float r = 0.f;
#pragma unroll
    for (int ci = 0; ci < 32; ci++) r += w[ci] * t[ci];
    r += x[(size_t)(b * 64 + co) * N + n];
    cat1[((size_t)b * 96 + 64 + co) * N + n] = r;
  }
}

// ---------------- fused final attn-apply + po -> d_out ---------------------
__global__ __launch_bounds__(256)
void k_attn_po(const float* __restrict__ cat2, const float* __restrict__ stats,
               const float* __restrict__ wpo, float* __restrict__ outp) {
  __shared__ float als[256], wls[2048];
  const int tid = threadIdx.x, b = blockIdx.y;
  const int n = blockIdx.x * 256 + tid;
  if (tid < 256) als[tid] = stats[(size_t)b * 256 + tid];
  for (int i = tid; i < 2048; i += 256) wls[i] = wpo[i];
  __syncthreads();
  const float* v = cat2 + (size_t)b * (64L * N);
  float t[64];
#pragma unroll
  for (int h = 0; h < 8; h++) {
    float vv[4];
#pragma unroll
    for (int e = 0; e < 4; e++) vv[e] = v[(size_t)(h * 4 + e) * N + n];
#pragma unroll
    for (int d = 0; d < 8; d++) {
      const float* A = &als[h * 32 + d * 4];
      t[h * 8 + d] = A[0] * vv[0] + A[1] * vv[1] + A[2] * vv[2] + A[3] * vv[3];
    }
  }
  for (int co = 0; co < 32; co++) {
    const float* w = &wls[co * 64];
    float r = 0.f;
#pragma unroll
    for (int ci = 0; ci < 64; ci++) r += w[ci] * t[ci];
    outp[(size_t)(b * 32 + co) * N + n] = r;
  }
}

// ---------------- avgpool 2x2 -> NHWC bf16 directly ------------------------
__global__ __launch_bounds__(256) void k_avgpoolb(const float* __restrict__ in,
                                                  ushort* __restrict__ outb) {
  const int opx = blockIdx.x * 256 + threadIdx.x;  // 4096 per b
  const int b = blockIdx.y;
  const int ox = opx & 63, oy = opx >> 6;
  const float* p0 = in + (size_t)b * 64 * N + (size_t)(oy * 2) * W + ox * 2;
  ushort tmp[64];
#pragma unroll
  for (int c = 0; c < 64; c++) {
    const float* p = p0 + (size_t)c * N;
    tmp[c] = f2bf(0.25f * (p[0] + p[1] + p[W] + p[W + 1]));
  }
  ushort* dp = outb + ((size_t)b * 4096 + opx) * 64;
#pragma unroll
  for (int k = 0; k < 8; k++) *(bh8*)(dp + k * 8) = *(const bh8*)&tmp[k * 8];
}

// ---------------- fused T3 * sigmoid(resize(asmall)) -> NHWC bf16 ----------
__global__ __launch_bounds__(256)
void k_sigcast(const float* __restrict__ t3, const float* __restrict__ asmall,
               ushort* __restrict__ t3b) {
  const int n = blockIdx.x * 256 + threadIdx.x;
  const int cy = blockIdx.y, b = blockIdx.z;
  const int x = n & 127, yv = n >> 7;
  const int iy = (yv * 62) >> 7, ix = (x * 62) >> 7;
  ushort tmp[32];
#pragma unroll
  for (int j = 0; j < 32; j++) {
    const int c = cy * 32 + j;
    float v = 0.f;
    if (c < 166) {
      const float a = asmall[((size_t)b * 166 + c) * 3844 + iy * 62 + ix];
      v = t3[((size_t)b * 166 + c) * N + n] * (1.f / (1.f + expf(-a)));
    }
    tmp[j] = f2bf(v);
  }
  ushort* dp = t3b + ((size_t)b * N + n) * 192 + cy * 32;
#pragma unroll
  for (int k = 0; k < 4; k++) *(bh8*)(dp + k * 8) = *(const bh8*)&tmp[k * 8];
}

// ---------------- deformable conv v4 ---------------------------------------
// Phase A: per-(pixel,tap) bilinear weights + clamped addrs -> LDS.
// Phase B: lane=channel, 2 px/thread (2x gather ILP); bf16 corners (64B rows
//          -> x0/x1 share a cache line); quad DPP broadcast contraction.
template <int K>
__global__ __launch_bounds__(256)
void k_deform4(const ushort* __restrict__ xtb, const float* __restrict__ offs, int off_c0,
               const float* __restrict__ wd, const float* __restrict__ bd,
               float* __restrict__ out, int out_c0) {
  constexpr int K2 = K * K, PAD = K / 2;
  __shared__ float wlds[K2 * 128];   // [t][cout(32)][j(4)]
  __shared__ float wbl[16][K2][4];   // bilinear weights per (px,tap)
  __shared__ int   abl[16][K2][4];   // clamped row addrs (elements) per (px,tap)
  const int tid = threadIdx.x, b = blockIdx.y;
  const int px0 = blockIdx.x * 16;
  for (int i = tid; i < K2 * 128; i += 256) {
    const int t = i >> 7, r = i & 127, o = r >> 2, j = r & 3;
    wlds[i] = wd[(size_t)(o * 4 + j) * K2 + t];
  }
  const float* obb = offs + (size_t)b * (166 * N) + (size_t)off_c0 * N;
  for (int i = tid; i < 16 * K2; i += 256) {
    const int p = i / K2, t = i - p * K2;
    const int px = px0 + p;
    const int hy = px >> 7, wx = px & 127;
    const int ky = t / K, kx = t - ky * K;
    const float dy = obb[(size_t)(2 * t) * N + px];
    const float dx = obb[(size_t)(2 * t + 1) * N + px];
    const float py = (float)(hy - PAD + ky) + dy;
    const float pxf = (float)(wx - PAD + kx) + dx;
    const float y0f = floorf(py), x0f = floorf(pxf);
    const float fy = py - y0f, fx = pxf - x0f;
    const int y0 = (int)y0f, x0 = (int)x0f;
    const int y1 = y0 + 1, x1 = x0 + 1;
    float w00 = (1.f - fy) * (1.f - fx), w01 = (1.f - fy) * fx;
    float w10 = fy * (1.f - fx), w11 = fy * fx;
    const bool vy0 = (y0 >= 0) & (y0 < H), vy1 = (y1 >= 0) & (y1 < H);
    const bool vx0 = (x0 >= 0) & (x0 < W), vx1 = (x1 >= 0) & (x1 < W);
    w00 = (vy0 & vx0) ? w00 : 0.f;
    w01 = (vy0 & vx1) ? w01 : 0.f;
    w10 = (vy1 & vx0) ? w10 : 0.f;
    w11 = (vy1 & vx1) ? w11 : 0.f;
    const int cy0 = min(max(y0, 0), H - 1), cy1 = min(max(y1, 0), H - 1);
    const int cx0 = min(max(x0, 0), W - 1), cx1 = min(max(x1, 0), W - 1);
    wbl[p][t][0] = w00; wbl[p][t][1] = w01; wbl[p][t][2] = w10; wbl[p][t][3] = w11;
    abl[p][t][0] = (cy0 * W + cx0) * 32;
    abl[p][t][1] = (cy0 * W + cx1) * 32;
    abl[p][t][2] = (cy1 * W + cx0) * 32;
    abl[p][t][3] = (cy1 * W + cx1) * 32;
  }
  __syncthreads();
  const int pxl = tid >> 5, c = tid & 31;
  const ushort* xb = xtb + (size_t)b * N * 32 + c;
  float accA = 0.f, accB = 0.f;
  for (int t = 0; t < K2; t++) {
    const float4 wA = *(const float4*)&wbl[pxl][t][0];
    const int4  aA = *(const int4*)&abl[pxl][t][0];
    const float4 wB = *(const float4*)&wbl[pxl + 8][t][0];
    const int4  aB = *(const int4*)&abl[pxl + 8][t][0];
    const float sA = wA.x * bf2f(xb[aA.x]) + wA.y * bf2f(xb[aA.y])
                   + wA.z * bf2f(xb[aA.z]) + wA.w * bf2f(xb[aA.w]);
    const float sB = wB.x * bf2f(xb[aB.x]) + wB.y * bf2f(xb[aB.y])
                   + wB.z * bf2f(xb[aB.z]) + wB.w * bf2f(xb[aB.w]);
    const int siA = __float_as_int(sA), siB = __float_as_int(sB);
    const float4 wc = *(const float4*)&wlds[t * 128 + c * 4];
    accA += __int_as_float(__builtin_amdgcn_mov_dpp(siA, 0x00, 0xf, 0xf, false)) * wc.x
          + __int_as_float(__builtin_amdgcn_mov_dpp(siA, 0x55, 0xf, 0xf, false)) * wc.y
          + __int_as_float(__builtin_amdgcn_mov_dpp(siA, 0xAA, 0xf, 0xf, false)) * wc.z
          + __int_as_float(__builtin_amdgcn_mov_dpp(siA, 0xFF, 0xf, 0xf, false)) * wc.w;
    accB += __int_as_float(__builtin_amdgcn_mov_dpp(siB, 0x00, 0xf, 0xf, false)) * wc.x
          + __int_as_float(__builtin_amdgcn_mov_dpp(siB, 0x55, 0xf, 0xf, false)) * wc.y
          + __int_as_float(__builtin_amdgcn_mov_dpp(siB, 0xAA, 0xf, 0xf, false)) * wc.z
          + __int_as_float(__builtin_amdgcn_mov_dpp(siB, 0xFF, 0xf, 0xf, false)) * wc.w;
  }
  const float bia = bd[c];
  float* op = out + ((size_t)b * 96 + out_c0 + c) * N + px0 + pxl;
  op[0] = fmaxf(accA + bia, 0.f);
  op[8] = fmaxf(accB + bia, 0.f);
}

// ---------------------------------------------------------------------------
extern "C" void kernel_launch(void* const* d_in, const int* in_sizes, int n_in,
                              void* d_out, int out_size, void* d_ws, size_t ws_size,
                              hipStream_t stream) {
  const float* fx       = (const float*)d_in[0];
  const float* fy       = (const float*)d_in[1];
  const float* w_temp   = (const float*)d_in[2];
  const float* w_po     = (const float*)d_in[3];
  const float* w_lp1    = (const float*)d_in[4];
  const float* w_lp2    = (const float*)d_in[5];
  const float* ln_g     = (const float*)d_in[6];
  const float* ln_b     = (const float*)d_in[7];
  const float* w_tempin = (const float*)d_in[8];
  const float* w_qkv    = (const float*)d_in[9];
  const float* w_qkvd   = (const float*)d_in[10];
  const float* w_mproj  = (const float*)d_in[11];
  const float* w_c3     = (const float*)d_in[12];
  const float* w_k2     = (const float*)d_in[13];
  const float* w_k3     = (const float*)d_in[14];
  const float* w_k4     = (const float*)d_in[15];
  const float* w_d3     = (const float*)d_in[16];
  const float* b_d3     = (const float*)d_in[17];
  const float* w_d5     = (const float*)d_in[18];
  const float* b_d5     = (const float*)d_in[19];
  const float* w_d7     = (const float*)d_in[20];
  const float* b_d7     = (const float*)d_in[21];
  const float* w_pw     = (const float*)d_in[22];
  const float* b_pw     = (const float*)d_in[23];
  float* ws = (float*)d_ws;

  size_t off = 0;
  auto buf = [&](size_t nelem) { float* p = ws + off; off += nelem; return p; };
  float* CAT2   = buf(2097152);
  float* XTBf   = buf(1048576);   // XTb bf16 [B,N,32] (uses first half)
  float* R1     = buf(1048576);
  float* R2     = buf(3145728);
  float* R3     = buf(3145728);
  float* PROMPT = buf(1048576);
  float* R4     = buf(5439488);
  float* OFFS   = buf(5439488);
  float* STATS  = buf(32768);
  float* CAT2Bf = buf(524288);
  float* WPf    = buf(327680);
  (void)ws_size; (void)out_size; (void)n_in; (void)in_sizes;

  float* XN = R1;
  float* QKV1 = R2;   float* CAT1 = R2;
  float* QKV2 = R3;   float* ASMALL = R3 + 524288;
  float* T3 = R4;     float* CAT3 = R4;   float* KFEAT = R4 + 3145728;
  float* ST_IN = STATS;
  float* ST_FI = STATS + 256;
  float* P_IN  = STATS + 1024;
  float* P_FI  = STATS + 8192;

  ushort* XTb   = (ushort*)XTBf;
  ushort* CAT2b = (ushort*)CAT2Bf;
  ushort* POOLb = (ushort*)R3;
  ushort* CAT1b = (ushort*)OFFS;
  ushort* T3b   = (ushort*)R2;

  ushort* WPu = (ushort*)WPf;
  ushort* wp_lp2 = WPu;
  ushort* wp_c3  = wp_lp2 + 18432;
  ushort* wp_k2  = wp_c3 + 55296;
  ushort* wp_k3  = wp_k2 + 110592;
  ushort* wp_k4  = wp_k3 + 110592;

  const long bs64 = 64L * N, bs32 = 32L * N, bs96 = 96L * N, bs166 = 166L * N;

  WArgs wa;
  wa.e[0] = { w_lp2, wp_lp2, 32, 32, 32, 64 * 9 * 32 };
  wa.e[1] = { w_c3,  wp_c3,  32, 96, 96, 64 * 9 * 96 };
  wa.e[2] = { w_k2,  wp_k2, 166, 64, 64, 192 * 9 * 64 };
  wa.e[3] = { w_k3,  wp_k3, 166, 64, 64, 192 * 9 * 64 };
  wa.e[4] = { w_k4,  wp_k4, 166, 166, 192, 192 * 9 * 192 };
  k_wpack<<<dim3(64, 5), 256, 0, stream>>>(wa);
  k_prep<<<dim3(N / 256, B), 256, 0, stream>>>(fx, fy, ln_g, ln_b, CAT2, XTb, CAT2b, XN);
  k_conv1x1<<<dim3(N / 256, 24, B), 256, 0, stream>>>(
      XN, bs32, 32, w_qkv, nullptr, nullptr, 0, QKV1, bs96, 0);
  k_dwconv<<<dim3(N / 256, 32, B), 256, 0, stream>>>(QKV1, w_qkvd, QKV2);
  k_attn_part<4><<<dim3(8, B, 8), 256, 0, stream>>>(
      QKV2, bs96, nullptr, 0, QKV2 + bs32, bs96, P_IN);
  k_attn_soft<4><<<dim3(8, B), 128, 0, stream>>>(P_IN, w_tempin, ST_IN);
  k_attn_mproj<<<dim3(N / 256, B), 256, 0, stream>>>(QKV2, ST_IN, w_mproj, CAT2, CAT1);
  k_conv1x1<<<dim3(N / 256, 8, B), 256, 0, stream>>>(
      CAT2, bs64, 32, w_lp1, nullptr, nullptr, 0, CAT1, bs96, 0);
  k_conv3m<<<dim3(64, 1, B), 256, 0, stream>>>(
      CAT2b, (long)N * 64, 64, H, W, wp_lp2, 1, 32, CAT1, bs96, 32, H, W, 1);
  k_castn<<<dim3(64, 3, B), 256, 0, stream>>>(CAT1, CAT1b, N, 96, 96);
  k_conv3m<<<dim3(64, 1, B), 256, 0, stream>>>(
      CAT1b, (long)N * 96, 96, H, W, wp_c3, 3, 32, PROMPT, bs32, 0, H, W, 1);
  k_avgpoolb<<<dim3(16, B), 256, 0, stream>>>(CAT2, POOLb);
  k_conv3m<<<dim3(31, 3, B), 256, 0, stream>>>(
      POOLb, 4096L * 64, 64, 64, 64, wp_k2, 2, 166, ASMALL, 166L * 3844, 0, 62, 62, 0);
  k_conv3m<<<dim3(64, 3, B), 256, 0, stream>>>(
      CAT2b, (long)N * 64, 64, H, W, wp_k3, 2, 166, T3, bs166, 0, H, W, 1);
  k_sigcast<<<dim3(64, 6, B), 256, 0, stream>>>(T3, ASMALL, T3b);
  k_conv3m<<<dim3(64, 3, B), 256, 0, stream>>>(
      T3b, (long)N * 192, 192, H, W, wp_k4, 6, 166, OFFS, bs166, 0, H, W, 1);
  k_deform4<3><<<dim3(N / 16, B), 256, 0, stream>>>(XTb, OFFS, 0, w_d3, b_d3, CAT3, 0);
  k_deform4<5><<<dim3(N / 16, B), 256, 0, stream>>>(XTb, OFFS, 18, w_d5, b_d5, CAT3, 32);
  k_deform4<7><<<dim3(N / 16, B), 256, 0, stream>>>(XTb, OFFS, 68, w_d7, b_d7, CAT3, 64);
  k_conv1x1<<<dim3(N / 256, 8, B), 256, 0, stream>>>(
      CAT3, bs96, 96, w_pw, b_pw, nullptr, 0, KFEAT, bs32, 0);
  k_attn_part<8><<<dim3(8, B, 8), 256, 0, stream>>>(
      CAT2, bs64, PROMPT, bs32, KFEAT, bs32, P_FI);
  k_attn_soft<8><<<dim3(8, B), 128, 0, stream>>>(P_FI, w_temp, ST_FI);
  k_attn_po<<<dim3(N / 256, B), 256, 0, stream>>>(CAT2, ST_FI, w_po, (float*)d_out);
}

// Round 9
// 563.449 us; speedup vs baseline: 3.4864x; 1.0016x over previous
//
#include <hip/hip_runtime.h>
#include <hip/hip_bf16.h>
#include <hip/hip_fp16.h>

// ---------------------------------------------------------------------------
// MDTA_FOR_VIDEO_Prompted — full-graph HIP implementation.
// B=2, C=32, H=W=128. fp32 in/out; 3x3 convs via bf16 MFMA implicit GEMM.
// R9: deform v5 = packed LDS (ushort row addrs, fp16 bilinear + conv weights):
//     K=7 LDS 50->24.5 KB, 3->6 blocks/CU. Rest as R8.
// ---------------------------------------------------------------------------

constexpr int B = 2, C = 32, H = 128, W = 128, N = H * W;

using bh8   = __attribute__((ext_vector_type(8))) short;  // 8 bf16 = 4 VGPRs
using f32x4 = __attribute__((ext_vector_type(4))) float;

__device__ __forceinline__ ushort f2bf(float v) {
  __hip_bfloat16 h = __float2bfloat16(v);
  return *(ushort*)&h;
}
__device__ __forceinline__ float bf2f(ushort u) {
  union { unsigned int i; float f; } w; w.i = ((unsigned int)u) << 16; return w.f;
}

// ---------------- prep: CAT2=[x;y] NCHW fp32, XTb = x NHWC bf16,
//                  CAT2b = [x;y] NHWC bf16, XN = layernorm(x) NCHW ----------
__global__ __launch_bounds__(256) void k_prep(const float* __restrict__ x,
                                              const float* __restrict__ y,
                                              const float* __restrict__ ln_g,
                                              const float* __restrict__ ln_b,
                                              float* __restrict__ cat2,
                                              ushort* __restrict__ xtb,
                                              ushort* __restrict__ cat2b,
                                              float* __restrict__ xn) {
  __shared__ float tile[C][257];
  const int b = blockIdx.y, n0 = blockIdx.x * 256, tid = threadIdx.x;
  const int n = n0 + tid;
  for (int c = 0; c < C; c++) {
    float v = x[(size_t)(b * C + c) * N + n];
    tile[c][tid] = v;
    cat2[(size_t)(b * 64 + c) * N + n] = v;
  }
  __syncthreads();
  {
    float s = 0.f, ss = 0.f;
#pragma unroll
    for (int c = 0; c < C; c++) { const float v = tile[c][tid]; s += v; ss += v * v; }
    const float mu = s * (1.f / C);
    const float var = ss * (1.f / C) - mu * mu;
    const float inv = rsqrtf(var + 1e-5f);
#pragma unroll
    for (int c = 0; c < C; c++)
      xn[(size_t)(b * C + c) * N + n] = (tile[c][tid] - mu) * inv * ln_g[c] + ln_b[c];
  }
  for (int i = tid; i < C * 256; i += 256) {
    int c = i & 31, nl = i >> 5;
    const ushort bv = f2bf(tile[c][nl]);
    xtb[((size_t)b * N + n0 + nl) * 32 + c] = bv;
    cat2b[((size_t)b * N + n0 + nl) * 64 + c] = bv;
  }
  __syncthreads();
  for (int c = 0; c < C; c++) {
    float v = y[(size_t)(b * C + c) * N + n];
    tile[c][tid] = v;
    cat2[(size_t)(b * 64 + 32 + c) * N + n] = v;
  }
  __syncthreads();
  for (int i = tid; i < C * 256; i += 256) {
    int c = i & 31, nl = i >> 5;
    cat2b[((size_t)b * N + n0 + nl) * 64 + 32 + c] = f2bf(tile[c][nl]);
  }
}

// ---------------- NCHW fp32 -> NHWC bf16 cast (32-ch chunk per block) ------
__global__ __launch_bounds__(256)
void k_castn(const float* __restrict__ src, ushort* __restrict__ dst,
             int isp, int cin_real, int cin_pad) {
  const int p = blockIdx.x * 256 + threadIdx.x;
  const int ci0 = blockIdx.y * 32, b = blockIdx.z;
  const float* sp = src + (size_t)b * cin_real * isp + p;
  ushort tmp[32];
#pragma unroll
  for (int j = 0; j < 32; j++) {
    const int ci = ci0 + j;
    const float v = (ci < cin_real) ? sp[(size_t)ci * isp] : 0.f;
    tmp[j] = f2bf(v);
  }
  ushort* dp = dst + ((size_t)b * isp + p) * cin_pad + ci0;
#pragma unroll
  for (int k = 0; k < 4; k++) *(bh8*)(dp + k * 8) = *(const bh8*)&tmp[k * 8];
}

// ---------------- weight pack: OIHW fp32 -> [co][t][ci] bf16 (padded) ------
struct WEnt { const float* src; ushort* dst; int cout_real, cin_real, kc32, total; };
struct WArgs { WEnt e[5]; };

__global__ __launch_bounds__(256) void k_wpack(WArgs a) {
  const WEnt en = a.e[blockIdx.y];
  const int tk = 9 * en.kc32;
  for (int i = blockIdx.x * 256 + threadIdx.x; i < en.total; i += gridDim.x * 256) {
    const int co = i / tk, rem = i - co * tk;
    const int t = rem / en.kc32, ci = rem - t * en.kc32;
    float v = 0.f;
    if (co < en.cout_real && ci < en.cin_real)
      v = en.src[((size_t)co * en.cin_real + ci) * 9 + t];
    en.dst[i] = f2bf(v);
  }
}

// ---------------- 3x3 conv as bf16 MFMA implicit GEMM ----------------------
__global__ __launch_bounds__(256)
void k_conv3m(const ushort* __restrict__ xin, long in_bs, int in_cs, int ih, int iw,
              const ushort* __restrict__ wp, int kchunks, int cout_real,
              float* __restrict__ out, long out_bs, int out_coff,
              int oh, int ow, int pad) {
  __shared__ ushort xt[4 * 130 * 32];
  const int tid = threadIdx.x, b = blockIdx.z;
  const int y0 = blockIdx.x * 2, co0 = blockIdx.y * 64;
  const int wv = tid >> 6, lane = tid & 63;
  const int row_sel = wv >> 1, col0 = (wv & 1) * 64;
  const int q = lane >> 4, n = lane & 15, q8 = q * 8;
  const int kc32 = kchunks * 32;
  const ushort* xb = xin + (size_t)b * in_bs;

  f32x4 acc[4][4];
#pragma unroll
  for (int mt = 0; mt < 4; mt++)
#pragma unroll
    for (int nb = 0; nb < 4; nb++) acc[mt][nb] = (f32x4){0.f, 0.f, 0.f, 0.f};

  for (int cc = 0; cc < kchunks; cc++) {
    __syncthreads();
    for (int i = tid; i < 2080; i += 256) {
      const int qq = i & 3, rc = i >> 2;
      const int r = rc / 130, c = rc - r * 130;
      const int yy = y0 - pad + r, xx = c - pad;
      bh8 v = {0, 0, 0, 0, 0, 0, 0, 0};
      if (yy >= 0 && yy < ih && xx >= 0 && xx < iw)
        v = *(const bh8*)(xb + ((size_t)yy * iw + xx) * in_cs + cc * 32 + qq * 8);
      *(bh8*)&xt[rc * 32 + qq * 8] = v;
    }
    __syncthreads();
#pragma unroll
    for (int t = 0; t < 9; t++) {
      const int dy = t / 3, dx = t - dy * 3;
      bh8 a[4], bb[4];
#pragma unroll
      for (int mt = 0; mt < 4; mt++)
        a[mt] = *(const bh8*)(wp + (size_t)((co0 + mt * 16 + n) * 9 + t) * kc32 + cc * 32 + q8);
#pragma unroll
      for (int nb = 0; nb < 4; nb++)
        bb[nb] = *(const bh8*)&xt[((row_sel + dy) * 130 + col0 + nb * 16 + n + dx) * 32 + q8];
#pragma unroll
      for (int mt = 0; mt < 4; mt++)
#pragma unroll
        for (int nb = 0; nb < 4; nb++)
          acc[mt][nb] = __builtin_amdgcn_mfma_f32_16x16x32_bf16(a[mt], bb[nb], acc[mt][nb], 0, 0, 0);
    }
  }

  const int oy = y0 + row_sel;
  const size_t osp = (size_t)oh * ow;
  float* ob = out + (size_t)b * out_bs + (size_t)out_coff * osp + (size_t)oy * ow;
#pragma unroll
  for (int mt = 0; mt < 4; mt++)
#pragma unroll
    for (int r = 0; r < 4; r++) {
      const int co = co0 + mt * 16 + q * 4 + r;
      if (co < cout_real) {
#pragma unroll
        for (int nb = 0; nb < 4; nb++) {
          const int px = col0 + nb * 16 + n;
          if (px < ow) ob[(size_t)co * osp + px] = acc[mt][nb][r];
        }
      }
    }
}

// ---------------- generic 1x1 conv (4 couts/thread) ------------------------
__global__ __launch_bounds__(256)
void k_conv1x1(const float* __restrict__ in, long in_bs, int cin,
               const float* __restrict__ wts, const float* __restrict__ bias,
               const float* __restrict__ resid, long res_bs,
               float* __restrict__ out, long out_bs, int out_coff) {
  const int n = blockIdx.x * 256 + threadIdx.x;
  const int co0 = blockIdx.y * 4, b = blockIdx.z;
  const float* ip = in + (size_t)b * in_bs + n;
  const float* w = wts + (size_t)co0 * cin;
  float a0 = 0, a1 = 0, a2 = 0, a3 = 0;
  for (int ci = 0; ci < cin; ci++) {
    float xv = ip[(size_t)ci * N];
    a0 += xv * w[ci]; a1 += xv * w[cin + ci];
    a2 += xv * w[2 * cin + ci]; a3 += xv * w[3 * cin + ci];
  }
  float acc[4] = {a0, a1, a2, a3};
#pragma unroll
  for (int o = 0; o < 4; o++) {
    const int co = co0 + o;
    float r = acc[o];
    if (bias) r += bias[co];
    if (resid) r += resid[(size_t)b * res_bs + (size_t)co * N + n];
    out[(size_t)b * out_bs + (size_t)(out_coff + co) * N + n] = r;
  }
}

// ---------------- grouped 3x3 conv (groups=32, 3 in / 3 out per group) -----
__global__ __launch_bounds__(256) void k_dwconv(const float* __restrict__ in,
                                                const float* __restrict__ wts,
                                                float* __restrict__ out) {
  const int n = blockIdx.x * 256 + threadIdx.x;
  const int g = blockIdx.y, b = blockIdx.z;
  const int h0 = n >> 7, w0 = n & 127;
  float acc[3] = {0.f, 0.f, 0.f};
  for (int ci = 0; ci < 3; ci++) {
    const float* ip = in + ((size_t)b * 96 + g * 3 + ci) * N;
#pragma unroll
    for (int ky = 0; ky < 3; ky++) {
      const int iy = h0 - 1 + ky;
      if (iy < 0 || iy >= H) continue;
#pragma unroll
      for (int kx = 0; kx < 3; kx++) {
        const int ix = w0 - 1 + kx;
        if (ix < 0 || ix >= W) continue;
        const float v = ip[(size_t)iy * W + ix];
#pragma unroll
        for (int o = 0; o < 3; o++)
          acc[o] += v * wts[((size_t)(g * 3 + o) * 3 + ci) * 9 + ky * 3 + kx];
      }
    }
  }
#pragma unroll
  for (int o = 0; o < 3; o++)
    out[((size_t)b * 96 + g * 3 + o) * N + n] = acc[o];
}

// ---------------- channel-attn phase 1: partial sums over N chunk ----------
template <int DQ>
__global__ __launch_bounds__(256)
void k_attn_part(const float* __restrict__ q1, long q1_bs,
                 const float* __restrict__ q2, long q2_bs,
                 const float* __restrict__ k, long k_bs,
                 float* __restrict__ partial) {
  const int h = blockIdx.x, b = blockIdx.y, ch = blockIdx.z, tid = threadIdx.x;
  const float* qp[DQ];
#pragma unroll
  for (int d = 0; d < DQ; d++) {
    const int qc = h * DQ + d;
    qp[d] = (qc < 32) ? (q1 + (size_t)b * q1_bs + (size_t)qc * N)
                      : (q2 + (size_t)b * q2_bs + (size_t)(qc - 32) * N);
  }
  const float* kp[4];
#pragma unroll
  for (int e = 0; e < 4; e++) kp[e] = k + (size_t)b * k_bs + (size_t)(h * 4 + e) * N;

  constexpr int NV = DQ + 4 + DQ * 4;
  float ssq[DQ] = {}, ssk[4] = {}, gr[DQ][4] = {};
  const int n1 = (ch + 1) * (N / 8);
  for (int n = ch * (N / 8) + tid; n < n1; n += 256) {
    float qv[DQ], kv[4];
#pragma unroll
    for (int d = 0; d < DQ; d++) { qv[d] = qp[d][n]; ssq[d] += qv[d] * qv[d]; }
#pragma unroll
    for (int e = 0; e < 4; e++) { kv[e] = kp[e][n]; ssk[e] += kv[e] * kv[e]; }
#pragma unroll
    for (int d = 0; d < DQ; d++)
#pragma unroll
      for (int e = 0; e < 4; e++) gr[d][e] += qv[d] * kv[e];
  }
  float vals[NV];
#pragma unroll
  for (int d = 0; d < DQ; d++) vals[d] = ssq[d];
#pragma unroll
  for (int e = 0; e < 4; e++) vals[DQ + e] = ssk[e];
#pragma unroll
  for (int d = 0; d < DQ; d++)
#pragma unroll
    for (int e = 0; e < 4; e++) vals[DQ + 4 + d * 4 + e] = gr[d][e];
#pragma unroll
  for (int j = 0; j < NV; j++) {
    float v = vals[j];
    for (int m = 32; m > 0; m >>= 1) v += __shfl_xor(v, m, 64);
    vals[j] = v;
  }
  __shared__ float red[4][NV];
  const int wid = tid >> 6, lane = tid & 63;
  if (lane == 0)
#pragma unroll
    for (int j = 0; j < NV; j++) red[wid][j] = vals[j];
  __syncthreads();
  if (tid < NV)
    partial[(size_t)(((b * 8 + h) * 8) + ch) * NV + tid] =
        red[0][tid] + red[1][tid] + red[2][tid] + red[3][tid];
}

// ---------------- channel-attn phase 2: reduce + softmax -------------------
template <int DQ>
__global__ __launch_bounds__(128)
void k_attn_soft(const float* __restrict__ partial,
                 const float* __restrict__ temp, float* __restrict__ stats) {
  constexpr int NV = DQ + 4 + DQ * 4;
  const int h = blockIdx.x, b = blockIdx.y, tid = threadIdx.x;
  __shared__ float tot[NV];
  if (tid < NV) {
    float s = 0.f;
#pragma unroll
    for (int ch = 0; ch < 8; ch++)
      s += partial[(size_t)(((b * 8 + h) * 8) + ch) * NV + tid];
    tot[tid] = s;
  }
  __syncthreads();
  if (tid == 0) {
    float invq[DQ], invk[4];
#pragma unroll
    for (int d = 0; d < DQ; d++) invq[d] = 1.f / fmaxf(sqrtf(tot[d]), 1e-12f);
#pragma unroll
    for (int e = 0; e < 4; e++) invk[e] = 1.f / fmaxf(sqrtf(tot[DQ + e]), 1e-12f);
    const float t = temp[h];
    float* sp = stats + (size_t)(b * 8 + h) * DQ * 4;
    for (int d = 0; d < DQ; d++) {
      float s[4], mx = -1e30f;
#pragma unroll
      for (int e = 0; e < 4; e++) {
        s[e] = tot[DQ + 4 + d * 4 + e] * invq[d] * invk[e] * t;
        mx = fmaxf(mx, s[e]);
      }
      float sum = 0.f;
#pragma unroll
      for (int e = 0; e < 4; e++) { s[e] = expf(s[e] - mx); sum += s[e]; }
#pragma unroll
      for (int e = 0; e < 4; e++) sp[d * 4 + e] = s[e] / sum;
    }
  }
}

// ---------------- fused inner attn-apply + mproj + residual ----------------
__global__ __launch_bounds__(256)
void k_attn_mproj(const float* __restrict__ qkv2, const float* __restrict__ stats,
                  const float* __restrict__ wm, const float* __restrict__ x,
                  float* __restrict__ cat1) {
  __shared__ float als[128], wls[1024];
  const int tid = threadIdx.x, b = blockIdx.y;
  const int n = blockIdx.x * 256 + tid;
  if (tid < 128) als[tid] = stats[(size_t)b * 128 + tid];
  for (int i = tid; i < 1024; i += 256) wls[i] = wm[i];
  __syncthreads();
  const float* vi = qkv2 + (size_t)b * (96L * N) + 64L * N;
  float t[32];
#pragma unroll
  for (int h = 0; h < 8; h++) {
    float vv[4];
#pragma unroll
    for (int e = 0; e < 4; e++) vv[e] = vi[(size_t)(h * 4 + e) * N + n];
#pragma unroll
    for (int d = 0; d < 4; d++) {
      const float* A = &als[h * 16 + d * 4];
      t[h * 4 + d] = A[0] * vv[0] + A[1] * vv[1] + A[2] * vv[2] + A[3] * vv[3];
    }
  }
  for (int co = 0; co < 32; co++) {
    const float* w = &wls[co * 32];
    float r = 0.f;
#pragma unroll
    for (int ci = 0; ci < 32; ci++) r += w[ci] * t[ci];
    r += x[(size_t)(b * 64 + co) * N + n];
    cat1[((size_t)b * 96 + 64 + co) * N + n] = r;
  }
}

// ---------------- fused final attn-apply + po -> d_out ---------------------
__global__ __launch_bounds__(256)
void k_attn_po(const float* __restrict__ cat2, const float* __restrict__ stats,
               const float* __restrict__ wpo, float* __restrict__ outp) {
  __shared__ float als[256], wls[2048];
  const int tid = threadIdx.x, b = blockIdx.y;
  const int n = blockIdx.x * 256 + tid;
  if (tid < 256) als[tid] = stats[(size_t)b * 256 + tid];
  for (int i = tid; i < 2048; i += 256) wls[i] = wpo[i];
  __syncthreads();
  const float* v = cat2 + (size_t)b * (64L * N);
  float t[64];
#pragma unroll
  for (int h = 0; h < 8; h++) {
    float vv[4];
#pragma unroll
    for (int e = 0; e < 4; e++) vv[e] = v[(size_t)(h * 4 + e) * N + n];
#pragma unroll
    for (int d = 0; d < 8; d++) {
      const float* A = &als[h * 32 + d * 4];
      t[h * 8 + d] = A[0] * vv[0] + A[1] * vv[1] + A[2] * vv[2] + A[3] * vv[3];
    }
  }
  for (int co = 0; co < 32; co++) {
    const float* w = &wls[co * 64];
    float r = 0.f;
#pragma unroll
    for (int ci = 0; ci < 64; ci++) r += w[ci] * t[ci];
    outp[(size_t)(b * 32 + co) * N + n] = r;
  }
}

// ---------------- avgpool 2x2 -> NHWC bf16 directly ------------------------
__global__ __launch_bounds__(256) void k_avgpoolb(const float* __restrict__ in,
                                                  ushort* __restrict__ outb) {
  const int opx = blockIdx.x * 256 + threadIdx.x;  // 4096 per b
  const int b = blockIdx.y;
  const int ox = opx & 63, oy = opx >> 6;
  const float* p0 = in + (size_t)b * 64 * N + (size_t)(oy * 2) * W + ox * 2;
  ushort tmp[64];
#pragma unroll
  for (int c = 0; c < 64; c++) {
    const float* p = p0 + (size_t)c * N;
    tmp[c] = f2bf(0.25f * (p[0] + p[1] + p[W] + p[W + 1]));
  }
  ushort* dp = outb + ((size_t)b * 4096 + opx) * 64;
#pragma unroll
  for (int k = 0; k < 8; k++) *(bh8*)(dp + k * 8) = *(const bh8*)&tmp[k * 8];
}

// ---------------- fused T3 * sigmoid(resize(asmall)) -> NHWC bf16 ----------
__global__ __launch_bounds__(256)
void k_sigcast(const float* __restrict__ t3, const float* __restrict__ asmall,
               ushort* __restrict__ t3b) {
  const int n = blockIdx.x * 256 + threadIdx.x;
  const int cy = blockIdx.y, b = blockIdx.z;
  const int x = n & 127, yv = n >> 7;
  const int iy = (yv * 62) >> 7, ix = (x * 62) >> 7;
  ushort tmp[32];
#pragma unroll
  for (int j = 0; j < 32; j++) {
    const int c = cy * 32 + j;
    float v = 0.f;
    if (c < 166) {
      const float a = asmall[((size_t)b * 166 + c) * 3844 + iy * 62 + ix];
      v = t3[((size_t)b * 166 + c) * N + n] * (1.f / (1.f + expf(-a)));
    }
    tmp[j] = f2bf(v);
  }
  ushort* dp = t3b + ((size_t)b * N + n) * 192 + cy * 32;
#pragma unroll
  for (int k = 0; k < 4; k++) *(bh8*)(dp + k * 8) = *(const bh8*)&tmp[k * 8];
}

// ---------------- deformable conv v5 ---------------------------------------
// Phase A: per-(px,tap) fp16 bilinear weights + ushort row addrs -> LDS.
// Phase B: lane=channel, 2 px/thread; bf16 corner gathers; quad DPP
//          contraction with fp16 conv weights. K=7 LDS = 24.5 KB (6 blk/CU).
template <int K>
__global__ __launch_bounds__(256)
void k_deform5(const ushort* __restrict__ xtb, const float* __restrict__ offs, int off_c0,
               const float* __restrict__ wd, const float* __restrict__ bd,
               float* __restrict__ out, int out_c0) {
  constexpr int K2 = K * K, PAD = K / 2;
  __shared__ __align__(16) __half  wlds[K2 * 128];   // [t][cout(32)][j(4)] fp16
  __shared__ __align__(16) __half  wbl[16][K2][4];   // bilinear weights fp16
  __shared__ __align__(16) ushort  abl[16][K2][4];   // clamped row idx (cy*W+cx)
  const int tid = threadIdx.x, b = blockIdx.y;
  const int px0 = blockIdx.x * 16;
  for (int i = tid; i < K2 * 128; i += 256) {
    const int t = i >> 7, r = i & 127, o = r >> 2, j = r & 3;
    wlds[i] = __float2half(wd[(size_t)(o * 4 + j) * K2 + t]);
  }
  const float* obb = offs + (size_t)b * (166 * N) + (size_t)off_c0 * N;
  for (int i = tid; i < 16 * K2; i += 256) {
    const int p = i / K2, t = i - p * K2;
    const int px = px0 + p;
    const int hy = px >> 7, wx = px & 127;
    const int ky = t / K, kx = t - ky * K;
    const float dy = obb[(size_t)(2 * t) * N + px];
    const float dx = obb[(size_t)(2 * t + 1) * N + px];
    const float py = (float)(hy - PAD + ky) + dy;
    const float pxf = (float)(wx - PAD + kx) + dx;
    const float y0f = floorf(py), x0f = floorf(pxf);
    const float fy = py - y0f, fx = pxf - x0f;
    const int y0 = (int)y0f, x0 = (int)x0f;
    const int y1 = y0 + 1, x1 = x0 + 1;
    float w00 = (1.f - fy) * (1.f - fx), w01 = (1.f - fy) * fx;
    float w10 = fy * (1.f - fx), w11 = fy * fx;
    const bool vy0 = (y0 >= 0) & (y0 < H), vy1 = (y1 >= 0) & (y1 < H);
    const bool vx0 = (x0 >= 0) & (x0 < W), vx1 = (x1 >= 0) & (x1 < W);
    w00 = (vy0 & vx0) ? w00 : 0.f;
    w01 = (vy0 & vx1) ? w01 : 0.f;
    w10 = (vy1 & vx0) ? w10 : 0.f;
    w11 = (vy1 & vx1) ? w11 : 0.f;
    const int cy0 = min(max(y0, 0), H - 1), cy1 = min(max(y1, 0), H - 1);
    const int cx0 = min(max(x0, 0), W - 1), cx1 = min(max(x1, 0), W - 1);
    wbl[p][t][0] = __float2half(w00); wbl[p][t][1] = __float2half(w01);
    wbl[p][t][2] = __float2half(w10); wbl[p][t][3] = __float2half(w11);
    abl[p][t][0] = (ushort)(cy0 * W + cx0);
    abl[p][t][1] = (ushort)(cy0 * W + cx1);
    abl[p][t][2] = (ushort)(cy1 * W + cx0);
    abl[p][t][3] = (ushort)(cy1 * W + cx1);
  }
  __syncthreads();
  const int pxl = tid >> 5, c = tid & 31;
  const ushort* xb = xtb + (size_t)b * N * 32 + c;
  float accA = 0.f, accB = 0.f;
  for (int t = 0; t < K2; t++) {
    const ushort4 rA = *(const ushort4*)&abl[pxl][t][0];
    const ushort4 rB = *(const ushort4*)&abl[pxl + 8][t][0];
    const float2 wA01 = __half22float2(*(const __half2*)&wbl[pxl][t][0]);
    const float2 wA23 = __half22float2(*(const __half2*)&wbl[pxl][t][2]);
    const float2 wB01 = __half22float2(*(const __half2*)&wbl[pxl + 8][t][0]);
    const float2 wB23 = __half22float2(*(const __half2*)&wbl[pxl + 8][t][2]);
    const float sA = wA01.x * bf2f(xb[(int)rA.x * 32]) + wA01.y * bf2f(xb[(int)rA.y * 32])
                   + wA23.x * bf2f(xb[(int)rA.z * 32]) + wA23.y * bf2f(xb[(int)rA.w * 32]);
    const float sB = wB01.x * bf2f(xb[(int)rB.x * 32]) + wB01.y * bf2f(xb[(int)rB.y * 32])
                   + wB23.x * bf2f(xb[(int)rB.z * 32]) + wB23.y * bf2f(xb[(int)rB.w * 32]);
    const int siA = __float_as_int(sA), siB = __float_as_int(sB);
    const float2 c01 = __half22float2(*(const __half2*)&wlds[t * 128 + c * 4]);
    const float2 c23 = __half22float2(*(const __half2*)&wlds[t * 128 + c * 4 + 2]);
    accA += __int_as_float(__builtin_amdgcn_mov_dpp(siA, 0x00, 0xf, 0xf, false)) * c01.x
          + __int_as_float(__builtin_amdgcn_mov_dpp(siA, 0x55, 0xf, 0xf, false)) * c01.y
          + __int_as_float(__builtin_amdgcn_mov_dpp(siA, 0xAA, 0xf, 0xf, false)) * c23.x
          + __int_as_float(__builtin_amdgcn_mov_dpp(siA, 0xFF, 0xf, 0xf, false)) * c23.y;
    accB += __int_as_float(__builtin_amdgcn_mov_dpp(siB, 0x00, 0xf, 0xf, false)) * c01.x
          + __int_as_float(__builtin_amdgcn_mov_dpp(siB, 0x55, 0xf, 0xf, false)) * c01.y
          + __int_as_float(__builtin_amdgcn_mov_dpp(siB, 0xAA, 0xf, 0xf, false)) * c23.x
          + __int_as_float(__builtin_amdgcn_mov_dpp(siB, 0xFF, 0xf, 0xf, false)) * c23.y;
  }
  const float bia = bd[c];
  float* op = out + ((size_t)b * 96 + out_c0 + c) * N + px0 + pxl;
  op[0] = fmaxf(accA + bia, 0.f);
  op[8] = fmaxf(accB + bia, 0.f);
}

// ---------------------------------------------------------------------------
extern "C" void kernel_launch(void* const* d_in, const int* in_sizes, int n_in,
                              void* d_out, int out_size, void* d_ws, size_t ws_size,
                              hipStream_t stream) {
  const float* fx       = (const float*)d_in[0];
  const float* fy       = (const float*)d_in[1];
  const float* w_temp   = (const float*)d_in[2];
  const float* w_po     = (const float*)d_in[3];
  const float* w_lp1    = (const float*)d_in[4];
  const float* w_lp2    = (const float*)d_in[5];
  const float* ln_g     = (const float*)d_in[6];
  const float* ln_b     = (const float*)d_in[7];
  const float* w_tempin = (const float*)d_in[8];
  const float* w_qkv    = (const float*)d_in[9];
  const float* w_qkvd   = (const float*)d_in[10];
  const float* w_mproj  = (const float*)d_in[11];
  const float* w_c3     = (const float*)d_in[12];
  const float* w_k2     = (const float*)d_in[13];
  const float* w_k3     = (const float*)d_in[14];
  const float* w_k4     = (const float*)d_in[15];
  const float* w_d3     = (const float*)d_in[16];
  const float* b_d3     = (const float*)d_in[17];
  const float* w_d5     = (const float*)d_in[18];
  const float* b_d5     = (const float*)d_in[19];
  const float* w_d7     = (const float*)d_in[20];
  const float* b_d7     = (const float*)d_in[21];
  const float* w_pw     = (const float*)d_in[22];
  const float* b_pw     = (const float*)d_in[23];
  float* ws = (float*)d_ws;

  size_t off = 0;
  auto buf = [&](size_t nelem) { float* p = ws + off; off += nelem; return p; };
  float* CAT2   = buf(2097152);
  float* XTBf   = buf(1048576);   // XTb bf16 [B,N,32] (uses first half)
  float* R1     = buf(1048576);
  float* R2     = buf(3145728);
  float* R3     = buf(3145728);
  float* PROMPT = buf(1048576);
  float* R4     = buf(5439488);
  float* OFFS   = buf(5439488);
  float* STATS  = buf(32768);
  float* CAT2Bf = buf(524288);
  float* WPf    = buf(327680);
  (void)ws_size; (void)out_size; (void)n_in; (void)in_sizes;

  float* XN = R1;
  float* QKV1 = R2;   float* CAT1 = R2;
  float* QKV2 = R3;   float* ASMALL = R3 + 524288;
  float* T3 = R4;     float* CAT3 = R4;   float* KFEAT = R4 + 3145728;
  float* ST_IN = STATS;
  float* ST_FI = STATS + 256;
  float* P_IN  = STATS + 1024;
  float* P_FI  = STATS + 8192;

  ushort* XTb   = (ushort*)XTBf;
  ushort* CAT2b = (ushort*)CAT2Bf;
  ushort* POOLb = (ushort*)R3;
  ushort* CAT1b = (ushort*)OFFS;
  ushort* T3b   = (ushort*)R2;

  ushort* WPu = (ushort*)WPf;
  ushort* wp_lp2 = WPu;
  ushort* wp_c3  = wp_lp2 + 18432;
  ushort* wp_k2  = wp_c3 + 55296;
  ushort* wp_k3  = wp_k2 + 110592;
  ushort* wp_k4  = wp_k3 + 110592;

  const long bs64 = 64L * N, bs32 = 32L * N, bs96 = 96L * N, bs166 = 166L * N;

  WArgs wa;
  wa.e[0] = { w_lp2, wp_lp2, 32, 32, 32, 64 * 9 * 32 };
  wa.e[1] = { w_c3,  wp_c3,  32, 96, 96, 64 * 9 * 96 };
  wa.e[2] = { w_k2,  wp_k2, 166, 64, 64, 192 * 9 * 64 };
  wa.e[3] = { w_k3,  wp_k3, 166, 64, 64, 192 * 9 * 64 };
  wa.e[4] = { w_k4,  wp_k4, 166, 166, 192, 192 * 9 * 192 };
  k_wpack<<<dim3(64, 5), 256, 0, stream>>>(wa);
  k_prep<<<dim3(N / 256, B), 256, 0, stream>>>(fx, fy, ln_g, ln_b, CAT2, XTb, CAT2b, XN);
  k_conv1x1<<<dim3(N / 256, 24, B), 256, 0, stream>>>(
      XN, bs32, 32, w_qkv, nullptr, nullptr, 0, QKV1, bs96, 0);
  k_dwconv<<<dim3(N / 256, 32, B), 256, 0, stream>>>(QKV1, w_qkvd, QKV2);
  k_attn_part<4><<<dim3(8, B, 8), 256, 0, stream>>>(
      QKV2, bs96, nullptr, 0, QKV2 + bs32, bs96, P_IN);
  k_attn_soft<4><<<dim3(8, B), 128, 0, stream>>>(P_IN, w_tempin, ST_IN);
  k_attn_mproj<<<dim3(N / 256, B), 256, 0, stream>>>(QKV2, ST_IN, w_mproj, CAT2, CAT1);
  k_conv1x1<<<dim3(N / 256, 8, B), 256, 0, stream>>>(
      CAT2, bs64, 32, w_lp1, nullptr, nullptr, 0, CAT1, bs96, 0);
  k_conv3m<<<dim3(64, 1, B), 256, 0, stream>>>(
      CAT2b, (long)N * 64, 64, H, W, wp_lp2, 1, 32, CAT1, bs96, 32, H, W, 1);
  k_castn<<<dim3(64, 3, B), 256, 0, stream>>>(CAT1, CAT1b, N, 96, 96);
  k_conv3m<<<dim3(64, 1, B), 256, 0, stream>>>(
      CAT1b, (long)N * 96, 96, H, W, wp_c3, 3, 32, PROMPT, bs32, 0, H, W, 1);
  k_avgpoolb<<<dim3(16, B), 256, 0, stream>>>(CAT2, POOLb);
  k_conv3m<<<dim3(31, 3, B), 256, 0, stream>>>(
      POOLb, 4096L * 64, 64, 64, 64, wp_k2, 2, 166, ASMALL, 166L * 3844, 0, 62, 62, 0);
  k_conv3m<<<dim3(64, 3, B), 256, 0, stream>>>(
      CAT2b, (long)N * 64, 64, H, W, wp_k3, 2, 166, T3, bs166, 0, H, W, 1);
  k_sigcast<<<dim3(64, 6, B), 256, 0, stream>>>(T3, ASMALL, T3b);
  k_conv3m<<<dim3(64, 3, B), 256, 0, stream>>>(
      T3b, (long)N * 192, 192, H, W, wp_k4, 6, 166, OFFS, bs166, 0, H, W, 1);
  k_deform5<3><<<dim3(N / 16, B), 256, 0, stream>>>(XTb, OFFS, 0, w_d3, b_d3, CAT3, 0);
  k_deform5<5><<<dim3(N / 16, B), 256, 0, stream>>>(XTb, OFFS, 18, w_d5, b_d5, CAT3, 32);
  k_deform5<7><<<dim3(N / 16, B), 256, 0, stream>>>(XTb, OFFS, 68, w_d7, b_d7, CAT3, 64);
  k_conv1x1<<<dim3(N / 256, 8, B), 256, 0, stream>>>(
      CAT3, bs96, 96, w_pw, b_pw, nullptr, 0, KFEAT, bs32, 0);
  k_attn_part<8><<<dim3(8, B, 8), 256, 0, stream>>>(
      CAT2, bs64, PROMPT, bs32, KFEAT, bs32, P_FI);
  k_attn_soft<8><<<dim3(8, B), 128, 0, stream>>>(P_FI, w_temp, ST_FI);
  k_attn_po<<<dim3(N / 256, B), 256, 0, stream>>>(CAT2, ST_FI, w_po, (float*)d_out);
}

// Round 10
// 543.897 us; speedup vs baseline: 3.6117x; 1.0359x over previous
//
#include <hip/hip_runtime.h>
#include <hip/hip_bf16.h>
#include <hip/hip_fp16.h>

// ---------------------------------------------------------------------------
// MDTA_FOR_VIDEO_Prompted — full-graph HIP implementation.
// B=2, C=32, H=W=128. fp32 in/out; 3x3 convs via bf16 MFMA implicit GEMM.
// R10: deform v6 = single runtime-K dispatch (zones for K=3/5/7) + epilogue
//      quad butterfly reduction (no per-tap DPP). Rest as R9.
// ---------------------------------------------------------------------------

constexpr int B = 2, C = 32, H = 128, W = 128, N = H * W;

using bh8   = __attribute__((ext_vector_type(8))) short;  // 8 bf16 = 4 VGPRs
using f32x4 = __attribute__((ext_vector_type(4))) float;

__device__ __forceinline__ ushort f2bf(float v) {
  __hip_bfloat16 h = __float2bfloat16(v);
  return *(ushort*)&h;
}
__device__ __forceinline__ float bf2f(ushort u) {
  union { unsigned int i; float f; } w; w.i = ((unsigned int)u) << 16; return w.f;
}

// ---------------- prep: CAT2=[x;y] NCHW fp32, XTb = x NHWC bf16,
//                  CAT2b = [x;y] NHWC bf16, XN = layernorm(x) NCHW ----------
__global__ __launch_bounds__(256) void k_prep(const float* __restrict__ x,
                                              const float* __restrict__ y,
                                              const float* __restrict__ ln_g,
                                              const float* __restrict__ ln_b,
                                              float* __restrict__ cat2,
                                              ushort* __restrict__ xtb,
                                              ushort* __restrict__ cat2b,
                                              float* __restrict__ xn) {
  __shared__ float tile[C][257];
  const int b = blockIdx.y, n0 = blockIdx.x * 256, tid = threadIdx.x;
  const int n = n0 + tid;
  for (int c = 0; c < C; c++) {
    float v = x[(size_t)(b * C + c) * N + n];
    tile[c][tid] = v;
    cat2[(size_t)(b * 64 + c) * N + n] = v;
  }
  __syncthreads();
  {
    float s = 0.f, ss = 0.f;
#pragma unroll
    for (int c = 0; c < C; c++) { const float v = tile[c][tid]; s += v; ss += v * v; }
    const float mu = s * (1.f / C);
    const float var = ss * (1.f / C) - mu * mu;
    const float inv = rsqrtf(var + 1e-5f);
#pragma unroll
    for (int c = 0; c < C; c++)
      xn[(size_t)(b * C + c) * N + n] = (tile[c][tid] - mu) * inv * ln_g[c] + ln_b[c];
  }
  for (int i = tid; i < C * 256; i += 256) {
    int c = i & 31, nl = i >> 5;
    const ushort bv = f2bf(tile[c][nl]);
    xtb[((size_t)b * N + n0 + nl) * 32 + c] = bv;
    cat2b[((size_t)b * N + n0 + nl) * 64 + c] = bv;
  }
  __syncthreads();
  for (int c = 0; c < C; c++) {
    float v = y[(size_t)(b * C + c) * N + n];
    tile[c][tid] = v;
    cat2[(size_t)(b * 64 + 32 + c) * N + n] = v;
  }
  __syncthreads();
  for (int i = tid; i < C * 256; i += 256) {
    int c = i & 31, nl = i >> 5;
    cat2b[((size_t)b * N + n0 + nl) * 64 + 32 + c] = f2bf(tile[c][nl]);
  }
}

// ---------------- NCHW fp32 -> NHWC bf16 cast (32-ch chunk per block) ------
__global__ __launch_bounds__(256)
void k_castn(const float* __restrict__ src, ushort* __restrict__ dst,
             int isp, int cin_real, int cin_pad) {
  const int p = blockIdx.x * 256 + threadIdx.x;
  const int ci0 = blockIdx.y * 32, b = blockIdx.z;
  const float* sp = src + (size_t)b * cin_real * isp + p;
  ushort tmp[32];
#pragma unroll
  for (int j = 0; j < 32; j++) {
    const int ci = ci0 + j;
    const float v = (ci < cin_real) ? sp[(size_t)ci * isp] : 0.f;
    tmp[j] = f2bf(v);
  }
  ushort* dp = dst + ((size_t)b * isp + p) * cin_pad + ci0;
#pragma unroll
  for (int k = 0; k < 4; k++) *(bh8*)(dp + k * 8) = *(const bh8*)&tmp[k * 8];
}

// ---------------- weight pack: OIHW fp32 -> [co][t][ci] bf16 (padded) ------
struct WEnt { const float* src; ushort* dst; int cout_real, cin_real, kc32, total; };
struct WArgs { WEnt e[5]; };

__global__ __launch_bounds__(256) void k_wpack(WArgs a) {
  const WEnt en = a.e[blockIdx.y];
  const int tk = 9 * en.kc32;
  for (int i = blockIdx.x * 256 + threadIdx.x; i < en.total; i += gridDim.x * 256) {
    const int co = i / tk, rem = i - co * tk;
    const int t = rem / en.kc32, ci = rem - t * en.kc32;
    float v = 0.f;
    if (co < en.cout_real && ci < en.cin_real)
      v = en.src[((size_t)co * en.cin_real + ci) * 9 + t];
    en.dst[i] = f2bf(v);
  }
}

// ---------------- 3x3 conv as bf16 MFMA implicit GEMM ----------------------
__global__ __launch_bounds__(256)
void k_conv3m(const ushort* __restrict__ xin, long in_bs, int in_cs, int ih, int iw,
              const ushort* __restrict__ wp, int kchunks, int cout_real,
              float* __restrict__ out, long out_bs, int out_coff,
              int oh, int ow, int pad) {
  __shared__ ushort xt[4 * 130 * 32];
  const int tid = threadIdx.x, b = blockIdx.z;
  const int y0 = blockIdx.x * 2, co0 = blockIdx.y * 64;
  const int wv = tid >> 6, lane = tid & 63;
  const int row_sel = wv >> 1, col0 = (wv & 1) * 64;
  const int q = lane >> 4, n = lane & 15, q8 = q * 8;
  const int kc32 = kchunks * 32;
  const ushort* xb = xin + (size_t)b * in_bs;

  f32x4 acc[4][4];
#pragma unroll
  for (int mt = 0; mt < 4; mt++)
#pragma unroll
    for (int nb = 0; nb < 4; nb++) acc[mt][nb] = (f32x4){0.f, 0.f, 0.f, 0.f};

  for (int cc = 0; cc < kchunks; cc++) {
    __syncthreads();
    for (int i = tid; i < 2080; i += 256) {
      const int qq = i & 3, rc = i >> 2;
      const int r = rc / 130, c = rc - r * 130;
      const int yy = y0 - pad + r, xx = c - pad;
      bh8 v = {0, 0, 0, 0, 0, 0, 0, 0};
      if (yy >= 0 && yy < ih && xx >= 0 && xx < iw)
        v = *(const bh8*)(xb + ((size_t)yy * iw + xx) * in_cs + cc * 32 + qq * 8);
      *(bh8*)&xt[rc * 32 + qq * 8] = v;
    }
    __syncthreads();
#pragma unroll
    for (int t = 0; t < 9; t++) {
      const int dy = t / 3, dx = t - dy * 3;
      bh8 a[4], bb[4];
#pragma unroll
      for (int mt = 0; mt < 4; mt++)
        a[mt] = *(const bh8*)(wp + (size_t)((co0 + mt * 16 + n) * 9 + t) * kc32 + cc * 32 + q8);
#pragma unroll
      for (int nb = 0; nb < 4; nb++)
        bb[nb] = *(const bh8*)&xt[((row_sel + dy) * 130 + col0 + nb * 16 + n + dx) * 32 + q8];
#pragma unroll
      for (int mt = 0; mt < 4; mt++)
#pragma unroll
        for (int nb = 0; nb < 4; nb++)
          acc[mt][nb] = __builtin_amdgcn_mfma_f32_16x16x32_bf16(a[mt], bb[nb], acc[mt][nb], 0, 0, 0);
    }
  }

  const int oy = y0 + row_sel;
  const size_t osp = (size_t)oh * ow;
  float* ob = out + (size_t)b * out_bs + (size_t)out_coff * osp + (size_t)oy * ow;
#pragma unroll
  for (int mt = 0; mt < 4; mt++)
#pragma unroll
    for (int r = 0; r < 4; r++) {
      const int co = co0 + mt * 16 + q * 4 + r;
      if (co < cout_real) {
#pragma unroll
        for (int nb = 0; nb < 4; nb++) {
          const int px = col0 + nb * 16 + n;
          if (px < ow) ob[(size_t)co * osp + px] = acc[mt][nb][r];
        }
      }
    }
}

// ---------------- generic 1x1 conv (4 couts/thread) ------------------------
__global__ __launch_bounds__(256)
void k_conv1x1(const float* __restrict__ in, long in_bs, int cin,
               const float* __restrict__ wts, const float* __restrict__ bias,
               const float* __restrict__ resid, long res_bs,
               float* __restrict__ out, long out_bs, int out_coff) {
  const int n = blockIdx.x * 256 + threadIdx.x;
  const int co0 = blockIdx.y * 4, b = blockIdx.z;
  const float* ip = in + (size_t)b * in_bs + n;
  const float* w = wts + (size_t)co0 * cin;
  float a0 = 0, a1 = 0, a2 = 0, a3 = 0;
  for (int ci = 0; ci < cin; ci++) {
    float xv = ip[(size_t)ci * N];
    a0 += xv * w[ci]; a1 += xv * w[cin + ci];
    a2 += xv * w[2 * cin + ci]; a3 += xv * w[3 * cin + ci];
  }
  float acc[4] = {a0, a1, a2, a3};
#pragma unroll
  for (int o = 0; o < 4; o++) {
    const int co = co0 + o;
    float r = acc[o];
    if (bias) r += bias[co];
    if (resid) r += resid[(size_t)b * res_bs + (size_t)co * N + n];
    out[(size_t)b * out_bs + (size_t)(out_coff + co) * N + n] = r;
  }
}

// ---------------- grouped 3x3 conv (groups=32, 3 in / 3 out per group) -----
__global__ __launch_bounds__(256) void k_dwconv(const float* __restrict__ in,
                                                const float* __restrict__ wts,
                                                float* __restrict__ out) {
  const int n = blockIdx.x * 256 + threadIdx.x;
  const int g = blockIdx.y, b = blockIdx.z;
  const int h0 = n >> 7, w0 = n & 127;
  float acc[3] = {0.f, 0.f, 0.f};
  for (int ci = 0; ci < 3; ci++) {
    const float* ip = in + ((size_t)b * 96 + g * 3 + ci) * N;
#pragma unroll
    for (int ky = 0; ky < 3; ky++) {
      const int iy = h0 - 1 + ky;
      if (iy < 0 || iy >= H) continue;
#pragma unroll
      for (int kx = 0; kx < 3; kx++) {
        const int ix = w0 - 1 + kx;
        if (ix < 0 || ix >= W) continue;
        const float v = ip[(size_t)iy * W + ix];
#pragma unroll
        for (int o = 0; o < 3; o++)
          acc[o] += v * wts[((size_t)(g * 3 + o) * 3 + ci) * 9 + ky * 3 + kx];
      }
    }
  }
#pragma unroll
  for (int o = 0; o < 3; o++)
    out[((size_t)b * 96 + g * 3 + o) * N + n] = acc[o];
}

// ---------------- channel-attn phase 1: partial sums over N chunk ----------
template <int DQ>
__global__ __launch_bounds__(256)
void k_attn_part(const float* __restrict__ q1, long q1_bs,
                 const float* __restrict__ q2, long q2_bs,
                 const float* __restrict__ k, long k_bs,
                 float* __restrict__ partial) {
  const int h = blockIdx.x, b = blockIdx.y, ch = blockIdx.z, tid = threadIdx.x;
  const float* qp[DQ];
#pragma unroll
  for (int d = 0; d < DQ; d++) {
    const int qc = h * DQ + d;
    qp[d] = (qc < 32) ? (q1 + (size_t)b * q1_bs + (size_t)qc * N)
                      : (q2 + (size_t)b * q2_bs + (size_t)(qc - 32) * N);
  }
  const float* kp[4];
#pragma unroll
  for (int e = 0; e < 4; e++) kp[e] = k + (size_t)b * k_bs + (size_t)(h * 4 + e) * N;

  constexpr int NV = DQ + 4 + DQ * 4;
  float ssq[DQ] = {}, ssk[4] = {}, gr[DQ][4] = {};
  const int n1 = (ch + 1) * (N / 8);
  for (int n = ch * (N / 8) + tid; n < n1; n += 256) {
    float qv[DQ], kv[4];
#pragma unroll
    for (int d = 0; d < DQ; d++) { qv[d] = qp[d][n]; ssq[d] += qv[d] * qv[d]; }
#pragma unroll
    for (int e = 0; e < 4; e++) { kv[e] = kp[e][n]; ssk[e] += kv[e] * kv[e]; }
#pragma unroll
    for (int d = 0; d < DQ; d++)
#pragma unroll
      for (int e = 0; e < 4; e++) gr[d][e] += qv[d] * kv[e];
  }
  float vals[NV];
#pragma unroll
  for (int d = 0; d < DQ; d++) vals[d] = ssq[d];
#pragma unroll
  for (int e = 0; e < 4; e++) vals[DQ + e] = ssk[e];
#pragma unroll
  for (int d = 0; d < DQ; d++)
#pragma unroll
    for (int e = 0; e < 4; e++) vals[DQ + 4 + d * 4 + e] = gr[d][e];
#pragma unroll
  for (int j = 0; j < NV; j++) {
    float v = vals[j];
    for (int m = 32; m > 0; m >>= 1) v += __shfl_xor(v, m, 64);
    vals[j] = v;
  }
  __shared__ float red[4][NV];
  const int wid = tid >> 6, lane = tid & 63;
  if (lane == 0)
#pragma unroll
    for (int j = 0; j < NV; j++) red[wid][j] = vals[j];
  __syncthreads();
  if (tid < NV)
    partial[(size_t)(((b * 8 + h) * 8) + ch) * NV + tid] =
        red[0][tid] + red[1][tid] + red[2][tid] + red[3][tid];
}

// ---------------- channel-attn phase 2: reduce + softmax -------------------
template <int DQ>
__global__ __launch_bounds__(128)
void k_attn_soft(const float* __restrict__ partial,
                 const float* __restrict__ temp, float* __restrict__ stats) {
  constexpr int NV = DQ + 4 + DQ * 4;
  const int h = blockIdx.x, b = blockIdx.y, tid = threadIdx.x;
  __shared__ float tot[NV];
  if (tid < NV) {
    float s = 0.f;
#pragma unroll
    for (int ch = 0; ch < 8; ch++)
      s += partial[(size_t)(((b * 8 + h) * 8) + ch) * NV + tid];
    tot[tid] = s;
  }
  __syncthreads();
  if (tid == 0) {
    float invq[DQ], invk[4];
#pragma unroll
    for (int d = 0; d < DQ; d++) invq[d] = 1.f / fmaxf(sqrtf(tot[d]), 1e-12f);
#pragma unroll
    for (int e = 0; e < 4; e++) invk[e] = 1.f / fmaxf(sqrtf(tot[DQ + e]), 1e-12f);
    const float t = temp[h];
    float* sp = stats + (size_t)(b * 8 + h) * DQ * 4;
    for (int d = 0; d < DQ; d++) {
      float s[4], mx = -1e30f;
#pragma unroll
      for (int e = 0; e < 4; e++) {
        s[e] = tot[DQ + 4 + d * 4 + e] * invq[d] * invk[e] * t;
        mx = fmaxf(mx, s[e]);
      }
      float sum = 0.f;
#pragma unroll
      for (int e = 0; e < 4; e++) { s[e] = expf(s[e] - mx); sum += s[e]; }
#pragma unroll
      for (int e = 0; e < 4; e++) sp[d * 4 + e] = s[e] / sum;
    }
  }
}

// ---------------- fused inner attn-apply + mproj + residual ----------------
__global__ __launch_bounds__(256)
void k_attn_mproj(const float* __restrict__ qkv2, const float* __restrict__ stats,
                  const float* __restrict__ wm, const float* __restrict__ x,
                  float* __restrict__ cat1) {
  __shared__ float als[128], wls[1024];
  const int tid = threadIdx.x, b = blockIdx.y;
  const int n = blockIdx.x * 256 + tid;
  if (tid < 128) als[tid] = stats[(size_t)b * 128 + tid];
  for (int i = tid; i < 1024; i += 256) wls[i] = wm[i];
  __syncthreads();
  const float* vi = qkv2 + (size_t)b * (96L * N) + 64L * N;
  float t[32];
#pragma unroll
  for (int h = 0; h < 8; h++) {
    float vv[4];
#pragma unroll
    for (int e = 0; e < 4; e++) vv[e] = vi[(size_t)(h * 4 + e) * N + n];
#pragma unroll
    for (int d = 0; d < 4; d++) {
      const float* A = &als[h * 16 + d * 4];
      t[h * 4 + d] = A[0] * vv[0] + A[1] * vv[1] + A[2] * vv[2] + A[3] * vv[3];
    }
  }
  for (int co = 0; co < 32; co++) {
    const float* w = &wls[co * 32];
    float r = 0.f;
#pragma unroll
    for (int ci = 0; ci < 32; ci++) r += w[ci] * t[ci];
    r += x[(size_t)(b * 64 + co) * N + n];
    cat1[((size_t)b * 96 + 64 + co) * N + n] = r;
  }
}

// ---------------- fused final attn-apply + po -> d_out ---------------------
__global__ __launch_bounds__(256)
void k_attn_po(const float* __restrict__ cat2, const float* __restrict__ stats,
               const float* __restrict__ wpo, float* __restrict__ outp) {
  __shared__ float als[256], wls[2048];
  const int tid = threadIdx.x, b = blockIdx.y;
  const int n = blockIdx.x * 256 + tid;
  if (tid < 256) als[tid] = stats[(size_t)b * 256 + tid];
  for (int i = tid; i < 2048; i += 256) wls[i] = wpo[i];
  __syncthreads();
  const float* v = cat2 + (size_t)b * (64L * N);
  float t[64];
#pragma unroll
  for (int h = 0; h < 8; h++) {
    float vv[4];
#pragma unroll
    for (int e = 0; e < 4; e++) vv[e] = v[(size_t)(h * 4 + e) * N + n];
#pragma unroll
    for (int d = 0; d < 8; d++) {
      const float* A = &als[h * 32 + d * 4];
      t[h * 8 + d] = A[0] * vv[0] + A[1] * vv[1] + A[2] * vv[2] + A[3] * vv[3];
    }
  }
  for (int co = 0; co < 32; co++) {
    const float* w = &wls[co * 64];
    float r = 0.f;
#pragma unroll
    for (int ci = 0; ci < 64; ci++) r += w[ci] * t[ci];
    outp[(size_t)(b * 32 + co) * N + n] = r;
  }
}

// ---------------- avgpool 2x2 -> NHWC bf16 directly ------------------------
__global__ __launch_bounds__(256) void k_avgpoolb(const float* __restrict__ in,
                                                  ushort* __restrict__ outb) {
  const int opx = blockIdx.x * 256 + threadIdx.x;  // 4096 per b
  const int b = blockIdx.y;
  const int ox = opx & 63, oy = opx >> 6;
  const float* p0 = in + (size_t)b * 64 * N + (size_t)(oy * 2) * W + ox * 2;
  ushort tmp[64];
#pragma unroll
  for (int c = 0; c < 64; c++) {
    const float* p = p0 + (size_t)c * N;
    tmp[c] = f2bf(0.25f * (p[0] + p[1] + p[W] + p[W + 1]));
  }
  ushort* dp = outb + ((size_t)b * 4096 + opx) * 64;
#pragma unroll
  for (int k = 0; k < 8; k++) *(bh8*)(dp + k * 8) = *(const bh8*)&tmp[k * 8];
}

// ---------------- fused T3 * sigmoid(resize(asmall)) -> NHWC bf16 ----------
__global__ __launch_bounds__(256)
void k_sigcast(const float* __restrict__ t3, const float* __restrict__ asmall,
               ushort* __restrict__ t3b) {
  const int n = blockIdx.x * 256 + threadIdx.x;
  const int cy = blockIdx.y, b = blockIdx.z;
  const int x = n & 127, yv = n >> 7;
  const int iy = (yv * 62) >> 7, ix = (x * 62) >> 7;
  ushort tmp[32];
#pragma unroll
  for (int j = 0; j < 32; j++) {
    const int c = cy * 32 + j;
    float v = 0.f;
    if (c < 166) {
      const float a = asmall[((size_t)b * 166 + c) * 3844 + iy * 62 + ix];
      v = t3[((size_t)b * 166 + c) * N + n] * (1.f / (1.f + expf(-a)));
    }
    tmp[j] = f2bf(v);
  }
  ushort* dp = t3b + ((size_t)b * N + n) * 192 + cy * 32;
#pragma unroll
  for (int k = 0; k < 4; k++) *(bh8*)(dp + k * 8) = *(const bh8*)&tmp[k * 8];
}

// ---------------- deformable conv v6 ---------------------------------------
// One dispatch for K=3/5/7 (zone by blockIdx.x). Phase A: per-(px,tap) fp16
// bilinear weights + ushort row addrs in dynamic LDS. Phase B: lane=channel,
// 2 px/thread, bf16 gathers; per-lane 4 partial couts (no per-tap DPP);
// epilogue 2-stage quad butterfly + select.
__global__ __launch_bounds__(256)
void k_deform6(const ushort* __restrict__ xtb, const float* __restrict__ offs,
               const float* __restrict__ wd3, const float* __restrict__ bd3,
               const float* __restrict__ wd5, const float* __restrict__ bd5,
               const float* __restrict__ wd7, const float* __restrict__ bd7,
               float* __restrict__ out) {
  const int tid = threadIdx.x, b = blockIdx.y;
  const int zone = blockIdx.x >> 10;           // N/16 = 1024 blocks per zone
  const int blk = blockIdx.x & 1023;
  int K, off_c0, out_c0;
  const float *wd, *bd;
  if (zone == 0)      { K = 3; off_c0 = 0;  out_c0 = 0;  wd = wd3; bd = bd3; }
  else if (zone == 1) { K = 5; off_c0 = 18; out_c0 = 32; wd = wd5; bd = bd5; }
  else                { K = 7; off_c0 = 68; out_c0 = 64; wd = wd7; bd = bd7; }
  const int K2 = K * K, PAD = K / 2;

  extern __shared__ __align__(16) char smem[];
  __half*  wlds = (__half*)smem;               // [t][c(32)][oo(4)]  K2*128
  __half*  wbl  = wlds + K2 * 128;             // [p(16)][t][4]
  ushort*  abl  = (ushort*)(wbl + 16 * K2 * 4);// [p(16)][t][4]

  // conv weights, re-laid for per-lane partial couts:
  // wlds[(t*32+c)*4+oo] = wd[(((c&~3)|oo)*4 + (c&3))*K2 + t]
  for (int i = tid; i < K2 * 128; i += 256) {
    const int t = i >> 7, r = i & 127, c = r >> 2, oo = r & 3;
    wlds[i] = __float2half(wd[(size_t)((((c & ~3) | oo) * 4) + (c & 3)) * K2 + t]);
  }
  const int px0 = blk * 16;
  const float* obb = offs + (size_t)b * (166 * N) + (size_t)off_c0 * N;
  for (int i = tid; i < 16 * K2; i += 256) {
    const int p = i / K2, t = i - p * K2;
    const int px = px0 + p;
    const int hy = px >> 7, wx = px & 127;
    const int ky = t / K, kx = t - ky * K;
    const float dy = obb[(size_t)(2 * t) * N + px];
    const float dx = obb[(size_t)(2 * t + 1) * N + px];
    const float py = (float)(hy - PAD + ky) + dy;
    const float pxf = (float)(wx - PAD + kx) + dx;
    const float y0f = floorf(py), x0f = floorf(pxf);
    const float fy = py - y0f, fx = pxf - x0f;
    const int y0 = (int)y0f, x0 = (int)x0f;
    const int y1 = y0 + 1, x1 = x0 + 1;
    float w00 = (1.f - fy) * (1.f - fx), w01 = (1.f - fy) * fx;
    float w10 = fy * (1.f - fx), w11 = fy * fx;
    const bool vy0 = (y0 >= 0) & (y0 < H), vy1 = (y1 >= 0) & (y1 < H);
    const bool vx0 = (x0 >= 0) & (x0 < W), vx1 = (x1 >= 0) & (x1 < W);
    w00 = (vy0 & vx0) ? w00 : 0.f;
    w01 = (vy0 & vx1) ? w01 : 0.f;
    w10 = (vy1 & vx0) ? w10 : 0.f;
    w11 = (vy1 & vx1) ? w11 : 0.f;
    const int cy0 = min(max(y0, 0), H - 1), cy1 = min(max(y1, 0), H - 1);
    const int cx0 = min(max(x0, 0), W - 1), cx1 = min(max(x1, 0), W - 1);
    const int base = (p * K2 + t) * 4;
    wbl[base + 0] = __float2half(w00); wbl[base + 1] = __float2half(w01);
    wbl[base + 2] = __float2half(w10); wbl[base + 3] = __float2half(w11);
    abl[base + 0] = (ushort)(cy0 * W + cx0);
    abl[base + 1] = (ushort)(cy0 * W + cx1);
    abl[base + 2] = (ushort)(cy1 * W + cx0);
    abl[base + 3] = (ushort)(cy1 * W + cx1);
  }
  __syncthreads();

  const int pxl = tid >> 5, c = tid & 31;
  const ushort* xb = xtb + (size_t)b * N * 32 + c;
  float pA[4] = {0.f, 0.f, 0.f, 0.f}, pB[4] = {0.f, 0.f, 0.f, 0.f};
  for (int t = 0; t < K2; t++) {
    const int baseA = (pxl * K2 + t) * 4, baseB = ((pxl + 8) * K2 + t) * 4;
    const ushort4 rA = *(const ushort4*)&abl[baseA];
    const ushort4 rB = *(const ushort4*)&abl[baseB];
    const float2 wA01 = __half22float2(*(const __half2*)&wbl[baseA]);
    const float2 wA23 = __half22float2(*(const __half2*)&wbl[baseA + 2]);
    const float2 wB01 = __half22float2(*(const __half2*)&wbl[baseB]);
    const float2 wB23 = __half22float2(*(const __half2*)&wbl[baseB + 2]);
    const float sA = wA01.x * bf2f(xb[(int)rA.x * 32]) + wA01.y * bf2f(xb[(int)rA.y * 32])
                   + wA23.x * bf2f(xb[(int)rA.z * 32]) + wA23.y * bf2f(xb[(int)rA.w * 32]);
    const float sB = wB01.x * bf2f(xb[(int)rB.x * 32]) + wB01.y * bf2f(xb[(int)rB.y * 32])
                   + wB23.x * bf2f(xb[(int)rB.z * 32]) + wB23.y * bf2f(xb[(int)rB.w * 32]);
    const float2 c01 = __half22float2(*(const __half2*)&wlds[(t * 32 + c) * 4]);
    const float2 c23 = __half22float2(*(const __half2*)&wlds[(t * 32 + c) * 4 + 2]);
    pA[0] += sA * c01.x; pA[1] += sA * c01.y; pA[2] += sA * c23.x; pA[3] += sA * c23.y;
    pB[0] += sB * c01.x; pB[1] += sB * c01.y; pB[2] += sB * c23.x; pB[3] += sB * c23.y;
  }
  // quad butterfly: sum partial[oo] across the 4 cin lanes of the quad
#pragma unroll
  for (int oo = 0; oo < 4; oo++) {
    int v = __float_as_int(pA[oo]);
    pA[oo] += __int_as_float(__builtin_amdgcn_mov_dpp(v, 0xB1, 0xf, 0xf, false));
    v = __float_as_int(pA[oo]);
    pA[oo] += __int_as_float(__builtin_amdgcn_mov_dpp(v, 0x4E, 0xf, 0xf, false));
    v = __float_as_int(pB[oo]);
    pB[oo] += __int_as_float(__builtin_amdgcn_mov_dpp(v, 0xB1, 0xf, 0xf, false));
    v = __float_as_int(pB[oo]);
    pB[oo] += __int_as_float(__builtin_amdgcn_mov_dpp(v, 0x4E, 0xf, 0xf, false));
  }
  const int j = c & 3;
  float accA = pA[0], accB = pB[0];
  if (j == 1) { accA = pA[1]; accB = pB[1]; }
  else if (j == 2) { accA = pA[2]; accB = pB[2]; }
  else if (j == 3) { accA = pA[3]; accB = pB[3]; }
  const float bia = bd[c];
  float* op = out + ((size_t)b * 96 + out_c0 + c) * N + px0 + pxl;
  op[0] = fmaxf(accA + bia, 0.f);
  op[8] = fmaxf(accB + bia, 0.f);
}

// ---------------------------------------------------------------------------
extern "C" void kernel_launch(void* const* d_in, const int* in_sizes, int n_in,
                              void* d_out, int out_size, void* d_ws, size_t ws_size,
                              hipStream_t stream) {
  const float* fx       = (const float*)d_in[0];
  const float* fy       = (const float*)d_in[1];
  const float* w_temp   = (const float*)d_in[2];
  const float* w_po     = (const float*)d_in[3];
  const float* w_lp1    = (const float*)d_in[4];
  const float* w_lp2    = (const float*)d_in[5];
  const float* ln_g     = (const float*)d_in[6];
  const float* ln_b     = (const float*)d_in[7];
  const float* w_tempin = (const float*)d_in[8];
  const float* w_qkv    = (const float*)d_in[9];
  const float* w_qkvd   = (const float*)d_in[10];
  const float* w_mproj  = (const float*)d_in[11];
  const float* w_c3     = (const float*)d_in[12];
  const float* w_k2     = (const float*)d_in[13];
  const float* w_k3     = (const float*)d_in[14];
  const float* w_k4     = (const float*)d_in[15];
  const float* w_d3     = (const float*)d_in[16];
  const float* b_d3     = (const float*)d_in[17];
  const float* w_d5     = (const float*)d_in[18];
  const float* b_d5     = (const float*)d_in[19];
  const float* w_d7     = (const float*)d_in[20];
  const float* b_d7     = (const float*)d_in[21];
  const float* w_pw     = (const float*)d_in[22];
  const float* b_pw     = (const float*)d_in[23];
  float* ws = (float*)d_ws;

  size_t off = 0;
  auto buf = [&](size_t nelem) { float* p = ws + off; off += nelem; return p; };
  float* CAT2   = buf(2097152);
  float* XTBf   = buf(1048576);   // XTb bf16 [B,N,32] (uses first half)
  float* R1     = buf(1048576);
  float* R2     = buf(3145728);
  float* R3     = buf(3145728);
  float* PROMPT = buf(1048576);
  float* R4     = buf(5439488);
  float* OFFS   = buf(5439488);
  float* STATS  = buf(32768);
  float* CAT2Bf = buf(524288);
  float* WPf    = buf(327680);
  (void)ws_size; (void)out_size; (void)n_in; (void)in_sizes;

  float* XN = R1;
  float* QKV1 = R2;   float* CAT1 = R2;
  float* QKV2 = R3;   float* ASMALL = R3 + 524288;
  float* T3 = R4;     float* CAT3 = R4;   float* KFEAT = R4 + 3145728;
  float* ST_IN = STATS;
  float* ST_FI = STATS + 256;
  float* P_IN  = STATS + 1024;
  float* P_FI  = STATS + 8192;

  ushort* XTb   = (ushort*)XTBf;
  ushort* CAT2b = (ushort*)CAT2Bf;
  ushort* POOLb = (ushort*)R3;
  ushort* CAT1b = (ushort*)OFFS;
  ushort* T3b   = (ushort*)R2;

  ushort* WPu = (ushort*)WPf;
  ushort* wp_lp2 = WPu;
  ushort* wp_c3  = wp_lp2 + 18432;
  ushort* wp_k2  = wp_c3 + 55296;
  ushort* wp_k3  = wp_k2 + 110592;
  ushort* wp_k4  = wp_k3 + 110592;

  const long bs64 = 64L * N, bs32 = 32L * N, bs96 = 96L * N, bs166 = 166L * N;

  WArgs wa;
  wa.e[0] = { w_lp2, wp_lp2, 32, 32, 32, 64 * 9 * 32 };
  wa.e[1] = { w_c3,  wp_c3,  32, 96, 96, 64 * 9 * 96 };
  wa.e[2] = { w_k2,  wp_k2, 166, 64, 64, 192 * 9 * 64 };
  wa.e[3] = { w_k3,  wp_k3, 166, 64, 64, 192 * 9 * 64 };
  wa.e[4] = { w_k4,  wp_k4, 166, 166, 192, 192 * 9 * 192 };
  k_wpack<<<dim3(64, 5), 256, 0, stream>>>(wa);
  k_prep<<<dim3(N / 256, B), 256, 0, stream>>>(fx, fy, ln_g, ln_b, CAT2, XTb, CAT2b, XN);
  k_conv1x1<<<dim3(N / 256, 24, B), 256, 0, stream>>>(
      XN, bs32, 32, w_qkv, nullptr, nullptr, 0, QKV1, bs96, 0);
  k_dwconv<<<dim3(N / 256, 32, B), 256, 0, stream>>>(QKV1, w_qkvd, QKV2);
  k_attn_part<4><<<dim3(8, B, 8), 256, 0, stream>>>(
      QKV2, bs96, nullptr, 0, QKV2 + bs32, bs96, P_IN);
  k_attn_soft<4><<<dim3(8, B), 128, 0, stream>>>(P_IN, w_tempin, ST_IN);
  k_attn_mproj<<<dim3(N / 256, B), 256, 0, stream>>>(QKV2, ST_IN, w_mproj, CAT2, CAT1);
  k_conv1x1<<<dim3(N / 256, 8, B), 256, 0, stream>>>(
      CAT2, bs64, 32, w_lp1, nullptr, nullptr, 0, CAT1, bs96, 0);
  k_conv3m<<<dim3(64, 1, B), 256, 0, stream>>>(
      CAT2b, (long)N * 64, 64, H, W, wp_lp2, 1, 32, CAT1, bs96, 32, H, W, 1);
  k_castn<<<dim3(64, 3, B), 256, 0, stream>>>(CAT1, CAT1b, N, 96, 96);
  k_conv3m<<<dim3(64, 1, B), 256, 0, stream>>>(
      CAT1b, (long)N * 96, 96, H, W, wp_c3, 3, 32, PROMPT, bs32, 0, H, W, 1);
  k_avgpoolb<<<dim3(16, B), 256, 0, stream>>>(CAT2, POOLb);
  k_conv3m<<<dim3(31, 3, B), 256, 0, stream>>>(
      POOLb, 4096L * 64, 64, 64, 64, wp_k2, 2, 166, ASMALL, 166L * 3844, 0, 62, 62, 0);
  k_conv3m<<<dim3(64, 3, B), 256, 0, stream>>>(
      CAT2b, (long)N * 64, 64, H, W, wp_k3, 2, 166, T3, bs166, 0, H, W, 1);
  k_sigcast<<<dim3(64, 6, B), 256, 0, stream>>>(T3, ASMALL, T3b);
  k_conv3m<<<dim3(64, 3, B), 256, 0, stream>>>(
      T3b, (long)N * 192, 192, H, W, wp_k4, 6, 166, OFFS, bs166, 0, H, W, 1);
  // merged deformable conv: zones K=3 / K=5 / K=7; dynamic LDS sized for K=7
  {
    const int K2m = 49;
    const size_t smem = (size_t)K2m * 128 * 2 + (size_t)16 * K2m * 4 * 2 * 2;  // 25088
    k_deform6<<<dim3(3 * (N / 16), B), 256, smem, stream>>>(
        XTb, OFFS, w_d3, b_d3, w_d5, b_d5, w_d7, b_d7, CAT3);
  }
  k_conv1x1<<<dim3(N / 256, 8, B), 256, 0, stream>>>(
      CAT3, bs96, 96, w_pw, b_pw, nullptr, 0, KFEAT, bs32, 0);
  k_attn_part<8><<<dim3(8, B, 8), 256, 0, stream>>>(
      CAT2, bs64, PROMPT, bs32, KFEAT, bs32, P_FI);
  k_attn_soft<8><<<dim3(8, B), 128, 0, stream>>>(P_FI, w_temp, ST_FI);
  k_attn_po<<<dim3(N / 256, B), 256, 0, stream>>>(CAT2, ST_FI, w_po, (float*)d_out);
}